// Round 6
// baseline (1783.632 us; speedup 1.0000x reference)
//
#include <hip/hip_runtime.h>
#include <hip/hip_bf16.h>
#include <cstddef>

__device__ __forceinline__ unsigned short f2bf(float f) {
    union { float f; unsigned int u; } v; v.f = f;
    unsigned int r = (v.u + 0x7fffu + ((v.u >> 16) & 1u)) >> 16;   // RNE
    return (unsigned short)r;
}

typedef __bf16    bf16x8 __attribute__((ext_vector_type(8)));
typedef float     f32x4  __attribute__((ext_vector_type(4)));
typedef _Float16  f16x8  __attribute__((ext_vector_type(8)));
typedef _Float16  f16x4  __attribute__((ext_vector_type(4)));

// fp32 -> fp16 (hi, lo*4096) split: hi + 2^-12*lo == v to ~2^-22 relative.
__device__ __forceinline__ void fsplit(float v, _Float16& hi, _Float16& lo) {
    hi = (_Float16)v;
    lo = (_Float16)((v - (float)hi) * 4096.0f);
}

// ---------------------------------------------------------------------------
// Split-fp16 MFMA GEMM v3 (encoder): C = relu(A @ Bt^T + bias).
// 2-phase pipelined: double-buffered LDS for B (one barrier per K-step);
// next-tile global loads (B->regs, A->regs) issued BEFORE the MFMA cluster,
// regs written to LDS[p^1] AFTER it (issue-early / write-late, T14).
// AF32: A is fp32 (X input), split to (hi, lo*2^12) in-register.
// 3 MFMA passes: acc0 = Ah*Bh; acc1 = Ah*Bl + Al*Bh; C = acc0 + 2^-12*acc1.
// ---------------------------------------------------------------------------
template<int K, bool AF32>
__global__ __launch_bounds__(256, 2)
void gemm_split3(const void* __restrict__ Asrc, const _Float16* __restrict__ Alo_,
                 const _Float16* __restrict__ Bhi, const _Float16* __restrict__ Blo,
                 const float* __restrict__ bias,
                 _Float16* __restrict__ Chi, _Float16* __restrict__ Clo,
                 int M, int N)
{
    constexpr int BK  = 32;
    constexpr int LDP = 40;                      // 80B row stride
    constexpr int NS  = K / BK;

    __shared__ alignas(16) _Float16 Bh[2][128][LDP];
    __shared__ alignas(16) _Float16 Bl[2][128][LDP];

    const int tid  = threadIdx.x;
    const int lane = tid & 63;
    const int w    = tid >> 6;
    const int wr   = (w >> 1) * 64;
    const int wc   = (w & 1) * 64;
    const int bm   = blockIdx.y * 128;
    const int bn   = blockIdx.x * 128;

    f32x4 acc0[4][4], acc1[4][4];
#pragma unroll
    for (int m = 0; m < 4; ++m)
#pragma unroll
        for (int n = 0; n < 4; ++n) {
            acc0[m][n] = (f32x4){0.f, 0.f, 0.f, 0.f};
            acc1[m][n] = (f32x4){0.f, 0.f, 0.f, 0.f};
        }

    const int arow = bm + wr + (lane & 15);      // A-frag row (m=0)
    const int kgrp = (lane >> 4) * 8;            // k sub-offset
    const int brow = tid >> 1;                   // B staging: 2 thr/row
    const int bcol = (tid & 1) * 16;             // 16 f16 (32B) each

    const _Float16* Ahi_ = (const _Float16*)Asrc;
    const float*    Af_  = (const float*)Asrc;

    f16x8 ah[4], al[4], ahn[4], aln[4];
    float4 rbh0, rbh1, rbl0, rbl1;               // staged B regs

    auto loadB = [&](int k0) {
        const size_t gb = (size_t)(bn + brow) * K + k0 + bcol;
        rbh0 = *reinterpret_cast<const float4*>(Bhi + gb);
        rbh1 = *reinterpret_cast<const float4*>(Bhi + gb + 8);
        rbl0 = *reinterpret_cast<const float4*>(Blo + gb);
        rbl1 = *reinterpret_cast<const float4*>(Blo + gb + 8);
    };
    auto storeB = [&](int p) {
        *reinterpret_cast<float4*>(&Bh[p][brow][bcol])     = rbh0;
        *reinterpret_cast<float4*>(&Bh[p][brow][bcol + 8]) = rbh1;
        *reinterpret_cast<float4*>(&Bl[p][brow][bcol])     = rbl0;
        *reinterpret_cast<float4*>(&Bl[p][brow][bcol + 8]) = rbl1;
    };
    auto loadA = [&](int k0, f16x8* h, f16x8* l) {
#pragma unroll
        for (int m = 0; m < 4; ++m) {
            const size_t ga = (size_t)(arow + m * 16) * K + k0 + kgrp;
            if constexpr (AF32) {
                float4 v0 = *reinterpret_cast<const float4*>(Af_ + ga);
                float4 v1 = *reinterpret_cast<const float4*>(Af_ + ga + 4);
                float vv[8] = {v0.x, v0.y, v0.z, v0.w, v1.x, v1.y, v1.z, v1.w};
                f16x8 hh, ll;
#pragma unroll
                for (int j = 0; j < 8; ++j) {
                    _Float16 hi, lo; fsplit(vv[j], hi, lo);
                    hh[j] = hi; ll[j] = lo;
                }
                h[m] = hh; l[m] = ll;
            } else {
                h[m] = *reinterpret_cast<const f16x8*>(Ahi_ + ga);
                l[m] = *reinterpret_cast<const f16x8*>(Alo_ + ga);
            }
        }
    };

    // prologue: tile 0 into buf 0 + A frags
    loadB(0);
    loadA(0, ah, al);
    storeB(0);
    __syncthreads();

#pragma unroll
    for (int s = 0; s < NS; ++s) {
        const int p = s & 1;
        if (s + 1 < NS) {                        // issue next-tile loads EARLY
            loadB((s + 1) * BK);
            loadA((s + 1) * BK, ahn, aln);
        }
        // MFMA cluster on buf p
#pragma unroll
        for (int n = 0; n < 4; ++n) {
            const f16x8 bh = *reinterpret_cast<const f16x8*>(
                &Bh[p][wc + n * 16 + (lane & 15)][kgrp]);
            const f16x8 bl = *reinterpret_cast<const f16x8*>(
                &Bl[p][wc + n * 16 + (lane & 15)][kgrp]);
#pragma unroll
            for (int m = 0; m < 4; ++m)
                acc0[m][n] = __builtin_amdgcn_mfma_f32_16x16x32_f16(
                    ah[m], bh, acc0[m][n], 0, 0, 0);
#pragma unroll
            for (int m = 0; m < 4; ++m)
                acc1[m][n] = __builtin_amdgcn_mfma_f32_16x16x32_f16(
                    ah[m], bl, acc1[m][n], 0, 0, 0);
#pragma unroll
            for (int m = 0; m < 4; ++m)
                acc1[m][n] = __builtin_amdgcn_mfma_f32_16x16x32_f16(
                    al[m], bh, acc1[m][n], 0, 0, 0);
        }
        if (s + 1 < NS) {                        // write-late into other buffer
            storeB(p ^ 1);
#pragma unroll
            for (int m = 0; m < 4; ++m) { ah[m] = ahn[m]; al[m] = aln[m]; }
        }
        __syncthreads();
    }

    // epilogue: combine, bias, relu, write fp16 pair planes
#pragma unroll
    for (int m = 0; m < 4; ++m)
#pragma unroll
        for (int n = 0; n < 4; ++n) {
            const int col = bn + wc + n * 16 + (lane & 15);
            const float bv = bias[col];
#pragma unroll
            for (int q = 0; q < 4; ++q) {
                const int row = bm + wr + m * 16 + (lane >> 4) * 4 + q;
                float v = acc0[m][n][q] + 2.44140625e-4f * acc1[m][n][q] + bv;
                v = fmaxf(v, 0.f);
                _Float16 hi, lo; fsplit(v, hi, lo);
                Chi[(size_t)row * N + col] = hi;
                Clo[(size_t)row * N + col] = lo;
            }
        }
}

// ---------------------------------------------------------------------------
// z_e GEMM: fp64 accumulation (exact-at-fp32 -> safe VQ argmin + tight
// output-1 check). A consumed from fp16 pair planes, W2 fp32. 64x64 tile.
// ---------------------------------------------------------------------------
__global__ __launch_bounds__(256)
void gemm_ze(const _Float16* __restrict__ Ahi, const _Float16* __restrict__ Alo,
             const float* __restrict__ W, const float* __restrict__ bias,
             float* __restrict__ C, int M, int N, int K)
{
    __shared__ alignas(16) float As[16][64];
    __shared__ alignas(16) float Bs[16][64];

    const int tid = threadIdx.x;
    const int tx  = tid % 16;
    const int ty  = tid / 16;
    const int bm  = blockIdx.y * 64;
    const int bn  = blockIdx.x * 64;

    double acc[4][4];
#pragma unroll
    for (int i = 0; i < 4; ++i)
#pragma unroll
        for (int j = 0; j < 4; ++j) acc[i][j] = 0.0;

    for (int k0 = 0; k0 < K; k0 += 16) {
        {
            int idx = tid * 4;
            int r = idx >> 4, c = idx & 15;
            f16x4 h = *reinterpret_cast<const f16x4*>(&Ahi[(size_t)(bm + r) * K + k0 + c]);
            f16x4 l = *reinterpret_cast<const f16x4*>(&Alo[(size_t)(bm + r) * K + k0 + c]);
#pragma unroll
            for (int i = 0; i < 4; ++i)
                As[c + i][r] = (float)h[i] + 2.44140625e-4f * (float)l[i];
        }
        {
            int idx = tid * 4;
            int r = idx / 64, c = idx % 64;
            *reinterpret_cast<float4*>(&Bs[r][c]) =
                *reinterpret_cast<const float4*>(&W[(size_t)(k0 + r) * N + bn + c]);
        }
        __syncthreads();

#pragma unroll
        for (int kk = 0; kk < 16; ++kk) {
            float a[4], b[4];
#pragma unroll
            for (int i = 0; i < 4; ++i) a[i] = As[kk][ty * 4 + i];
#pragma unroll
            for (int j = 0; j < 4; ++j) b[j] = Bs[kk][tx * 4 + j];
#pragma unroll
            for (int i = 0; i < 4; ++i)
#pragma unroll
                for (int j = 0; j < 4; ++j)
                    acc[i][j] = fma((double)a[i], (double)b[j], acc[i][j]);
        }
        __syncthreads();
    }

#pragma unroll
    for (int ii = 0; ii < 4; ++ii) {
        const size_t r = (size_t)bm + ty * 4 + ii;
        const int c = bn + tx * 4;
        float4 bv = *reinterpret_cast<const float4*>(&bias[c]);
        float4 o;
        o.x = (float)acc[ii][0] + bv.x; o.y = (float)acc[ii][1] + bv.y;
        o.z = (float)acc[ii][2] + bv.z; o.w = (float)acc[ii][3] + bv.w;
        *reinterpret_cast<float4*>(&C[r * N + c]) = o;
    }
}

// ---------------------------------------------------------------------------
// bf16 MFMA GEMM (decoder), 2-phase pipelined like gemm_split3:
// double-buffered LDS, next-tile loads issued before the MFMA cluster,
// LDS writes after, one barrier per K-step.
// ---------------------------------------------------------------------------
template<bool RELU, bool OUT_BF16>
__global__ __launch_bounds__(256, 2)
void gemm_mfma_bt(const unsigned short* __restrict__ A,
                  const unsigned short* __restrict__ Bt,
                  const float* __restrict__ bias,
                  void* __restrict__ Cv, int M, int N, int K)
{
    constexpr int BK  = 64;
    constexpr int LDP = 72;

    __shared__ alignas(16) unsigned short Asl[2][128][LDP];
    __shared__ alignas(16) unsigned short Bsl[2][128][LDP];

    const int tid  = threadIdx.x;
    const int lane = tid & 63;
    const int w    = tid >> 6;
    const int wr   = (w >> 1) * 64;
    const int wc   = (w & 1) * 64;
    const int bm   = blockIdx.y * 128;
    const int bn   = blockIdx.x * 128;

    f32x4 acc[4][4];
#pragma unroll
    for (int m = 0; m < 4; ++m)
#pragma unroll
        for (int n = 0; n < 4; ++n) acc[m][n] = (f32x4){0.f, 0.f, 0.f, 0.f};

    const int sr = tid >> 1;
    const int sc = (tid & 1) * 32;

    float4 ra[4], rb[4];
    auto loadAB = [&](int k0) {
        const float4* ga = reinterpret_cast<const float4*>(
            &A[(size_t)(bm + sr) * K + k0 + sc]);
        const float4* gb = reinterpret_cast<const float4*>(
            &Bt[(size_t)(bn + sr) * K + k0 + sc]);
#pragma unroll
        for (int i = 0; i < 4; ++i) { ra[i] = ga[i]; rb[i] = gb[i]; }
    };
    auto storeAB = [&](int p) {
        float4* da = reinterpret_cast<float4*>(&Asl[p][sr][sc]);
        float4* db = reinterpret_cast<float4*>(&Bsl[p][sr][sc]);
#pragma unroll
        for (int i = 0; i < 4; ++i) { da[i] = ra[i]; db[i] = rb[i]; }
    };

    loadAB(0);
    storeAB(0);
    __syncthreads();

    const int NS = K / BK;
    for (int s = 0; s < NS; ++s) {
        const int p = s & 1;
        if (s + 1 < NS) loadAB((s + 1) * BK);

#pragma unroll
        for (int ks = 0; ks < 2; ++ks) {
            bf16x8 af[4], bf[4];
            const int kc = ks * 32 + (lane >> 4) * 8;
#pragma unroll
            for (int m = 0; m < 4; ++m)
                af[m] = *reinterpret_cast<const bf16x8*>(
                    &Asl[p][wr + m * 16 + (lane & 15)][kc]);
#pragma unroll
            for (int n = 0; n < 4; ++n)
                bf[n] = *reinterpret_cast<const bf16x8*>(
                    &Bsl[p][wc + n * 16 + (lane & 15)][kc]);
#pragma unroll
            for (int m = 0; m < 4; ++m)
#pragma unroll
                for (int n = 0; n < 4; ++n)
                    acc[m][n] = __builtin_amdgcn_mfma_f32_16x16x32_bf16(
                        af[m], bf[n], acc[m][n], 0, 0, 0);
        }
        if (s + 1 < NS) storeAB(p ^ 1);
        __syncthreads();
    }

#pragma unroll
    for (int m = 0; m < 4; ++m)
#pragma unroll
        for (int n = 0; n < 4; ++n) {
            const int col = bn + wc + n * 16 + (lane & 15);
            const float bv = bias[col];
#pragma unroll
            for (int q = 0; q < 4; ++q) {
                const int row = bm + wr + m * 16 + (lane >> 4) * 4 + q;
                float v = acc[m][n][q] + bv;
                if (RELU) v = fmaxf(v, 0.f);
                if (OUT_BF16)
                    reinterpret_cast<unsigned short*>(Cv)[(size_t)row * N + col] = f2bf(v);
                else
                    reinterpret_cast<float*>(Cv)[(size_t)row * N + col] = v;
            }
        }
}

// ---------------------------------------------------------------------------
// small prep kernels
// ---------------------------------------------------------------------------
__global__ __launch_bounds__(256)
void transpose_bf16(const float* __restrict__ W, unsigned short* __restrict__ Wt,
                    int K, int N)
{
    int idx = blockIdx.x * 256 + threadIdx.x;
    if (idx >= K * N) return;
    int n = idx / K, k = idx % K;
    Wt[idx] = f2bf(W[(size_t)k * N + n]);
}

__global__ __launch_bounds__(256)
void transpose_split_f16(const float* __restrict__ W,
                         _Float16* __restrict__ Whi, _Float16* __restrict__ Wlo,
                         int K, int N)
{
    int idx = blockIdx.x * 256 + threadIdx.x;
    if (idx >= K * N) return;
    int n = idx / K, k = idx % K;
    _Float16 hi, lo; fsplit(W[(size_t)k * N + n], hi, lo);
    Whi[idx] = hi; Wlo[idx] = lo;
}

// ---------------------------------------------------------------------------
// VQ: exact (fp64) nearest-codebook + gather; also emits bf16 z_q copy.
// ---------------------------------------------------------------------------
__global__ __launch_bounds__(256)
void vq_gather(const float* __restrict__ Z, const float* __restrict__ CB,
               float* __restrict__ OUT, unsigned short* __restrict__ ZQB, int M)
{
    __shared__ alignas(16) float cb[256 * 64];
    __shared__ double ccs[256];

    const int tid = threadIdx.x;
    const int row = blockIdx.x * 256 + tid;

#pragma unroll
    for (int v = 0; v < 16; ++v) {
        int idx = (tid + v * 256) * 4;
        *reinterpret_cast<float4*>(&cb[idx]) =
            *reinterpret_cast<const float4*>(&CB[idx]);
    }
    __syncthreads();

    {
        double cc = 0.0;
        const float* c = &cb[tid * 64];
#pragma unroll
        for (int d = 0; d < 64; ++d) { double cd = (double)c[d]; cc = fma(cd, cd, cc); }
        ccs[tid] = cc;
    }

    float z[64];
#pragma unroll
    for (int v = 0; v < 16; ++v) {
        float4 f = *reinterpret_cast<const float4*>(&Z[(size_t)row * 64 + v * 4]);
        z[v * 4 + 0] = f.x; z[v * 4 + 1] = f.y; z[v * 4 + 2] = f.z; z[v * 4 + 3] = f.w;
    }
    double xx = 0.0;
#pragma unroll
    for (int d = 0; d < 64; ++d) { double zd = (double)z[d]; xx = fma(zd, zd, xx); }
    __syncthreads();

    double best = 1.0e300;
    int    bi   = 0;
    for (int e = 0; e < 256; ++e) {
        const float4* c4 = reinterpret_cast<const float4*>(&cb[e * 64]);
        double dot = 0.0;
#pragma unroll
        for (int v = 0; v < 16; ++v) {
            float4 f = c4[v];
            dot = fma((double)z[v * 4 + 0], (double)f.x, dot);
            dot = fma((double)z[v * 4 + 1], (double)f.y, dot);
            dot = fma((double)z[v * 4 + 2], (double)f.z, dot);
            dot = fma((double)z[v * 4 + 3], (double)f.w, dot);
        }
        double d2 = (xx - 2.0 * dot) + ccs[e];
        if (d2 < best) { best = d2; bi = e; }
    }

    {
        const float* src = &cb[bi * 64];
        float* dst = &OUT[(size_t)row * 64];
        unsigned short* dq = &ZQB[(size_t)row * 64];
#pragma unroll
        for (int v = 0; v < 16; ++v) {
            float4 f = *reinterpret_cast<const float4*>(src + v * 4);
            *reinterpret_cast<float4*>(dst + v * 4) = f;
            ushort4 qb = { f2bf(f.x), f2bf(f.y), f2bf(f.z), f2bf(f.w) };
            *reinterpret_cast<ushort4*>(dq + v * 4) = qb;
        }
    }
}

// ---------------------------------------------------------------------------
extern "C" void kernel_launch(void* const* d_in, const int* in_sizes, int n_in,
                              void* d_out, int out_size, void* d_ws, size_t ws_size,
                              hipStream_t stream)
{
    const float* X  = (const float*)d_in[0];
    const float* W0 = (const float*)d_in[1];
    const float* b0 = (const float*)d_in[2];
    const float* W1 = (const float*)d_in[3];
    const float* b1 = (const float*)d_in[4];
    const float* W2 = (const float*)d_in[5];
    const float* b2 = (const float*)d_in[6];
    const float* CB = (const float*)d_in[7];
    const float* W3 = (const float*)d_in[8];
    const float* b3 = (const float*)d_in[9];
    const float* W4 = (const float*)d_in[10];
    const float* b4 = (const float*)d_in[11];
    const float* W5 = (const float*)d_in[12];
    const float* b5 = (const float*)d_in[13];

    const int D_in = 256, H = 512, R = 64, S = 512, NA = 8;
    const int Mtot = in_sizes[0] / D_in;          // 131072

    float* recon = (float*)d_out;
    float* ze    = recon + (size_t)(Mtot / NA) * S;
    float* remb  = ze + (size_t)Mtot * R;

    // ---- workspace: fixed weight planes ----
    char* p = (char*)d_ws;
    _Float16* W0hi = (_Float16*)p;  p += (size_t)H * D_in * 2;
    _Float16* W0lo = (_Float16*)p;  p += (size_t)H * D_in * 2;
    _Float16* W1hi = (_Float16*)p;  p += (size_t)H * H * 2;
    _Float16* W1lo = (_Float16*)p;  p += (size_t)H * H * 2;
    unsigned short* W3t = (unsigned short*)p;  p += (size_t)H * R * 2;
    unsigned short* W4t = (unsigned short*)p;  p += (size_t)H * (NA * H) * 2;
    unsigned short* W5t = (unsigned short*)p;  p += (size_t)S * H * 2;
    size_t fixed = (size_t)(p - (char*)d_ws);
    fixed = (fixed + 255) & ~(size_t)255;

    // per-row chunk bytes: h0 pair 2048 + h1 pair 2048 + zqb 128
    int nc = 2;
    while (nc < 128) {
        size_t rpcT = (size_t)Mtot / nc;
        if (fixed + rpcT * 4224 + 1024 <= ws_size) break;
        nc *= 2;
    }
    const int rpc = Mtot / nc;
    char* q = (char*)d_ws + fixed;
    _Float16* h0hi = (_Float16*)q;                 q += (size_t)rpc * H * 2;
    _Float16* h0lo = (_Float16*)q;                 q += (size_t)rpc * H * 2;
    _Float16* h1hi = (_Float16*)q;                 q += (size_t)rpc * H * 2;
    _Float16* h1lo = (_Float16*)q;                 q += (size_t)rpc * H * 2;
    unsigned short* zqb = (unsigned short*)q;      q += (size_t)rpc * R * 2;
    unsigned short* rec1b = (unsigned short*)h0hi;     // alias (h0 dead after h1)
    unsigned short* rec2b = (unsigned short*)h1hi;     // alias (h1 dead after z_e)

    // ---- one-time weight prep ----
    transpose_split_f16<<<(H * D_in + 255) / 256, 256, 0, stream>>>(W0, W0hi, W0lo, D_in, H);
    transpose_split_f16<<<(H * H + 255) / 256, 256, 0, stream>>>(W1, W1hi, W1lo, H, H);
    transpose_bf16<<<(H * R + 255) / 256, 256, 0, stream>>>(W3, W3t, R, H);
    transpose_bf16<<<(H * NA * H + 255) / 256, 256, 0, stream>>>(W4, W4t, NA * H, H);
    transpose_bf16<<<(S * H + 255) / 256, 256, 0, stream>>>(W5, W5t, H, S);

    for (int r0 = 0; r0 < Mtot; r0 += rpc) {
        const int M6 = rpc / NA;
        // encoder: split-fp16 MFMA, pipelined; h0 splits fp32 X in-register
        gemm_split3<256, true><<<dim3(H / 128, rpc / 128), 256, 0, stream>>>(
            X + (size_t)r0 * D_in, nullptr, W0hi, W0lo, b0, h0hi, h0lo, rpc, H);
        gemm_split3<512, false><<<dim3(H / 128, rpc / 128), 256, 0, stream>>>(
            h0hi, h0lo, W1hi, W1lo, b1, h1hi, h1lo, rpc, H);
        // z_e: fp64 accumulation -> output zone 1
        gemm_ze<<<dim3(1, rpc / 64), 256, 0, stream>>>(
            h1hi, h1lo, W2, b2, ze + (size_t)r0 * R, rpc, R, H);
        // exact VQ -> role_emb + bf16 z_q
        vq_gather<<<rpc / 256, 256, 0, stream>>>(
            ze + (size_t)r0 * R, CB, remb + (size_t)r0 * R, zqb, rpc);
        // decoder: bf16 MFMA, pipelined
        gemm_mfma_bt<true, true><<<dim3(H / 128, rpc / 128), 256, 0, stream>>>(
            zqb, W3t, b3, rec1b, rpc, H, R);
        gemm_mfma_bt<true, true><<<dim3(H / 128, M6 / 128), 256, 0, stream>>>(
            rec1b, W4t, b4, rec2b, M6, H, NA * H);
        gemm_mfma_bt<false, false><<<dim3(S / 128, M6 / 128), 256, 0, stream>>>(
            rec2b, W5t, b5, recon + (size_t)(r0 / NA) * S, M6, S, H);
    }
}

// Round 7
// 1755.272 us; speedup vs baseline: 1.0162x; 1.0162x over previous
//
#include <hip/hip_runtime.h>
#include <hip/hip_bf16.h>
#include <cstddef>

__device__ __forceinline__ unsigned short f2bf(float f) {
    union { float f; unsigned int u; } v; v.f = f;
    unsigned int r = (v.u + 0x7fffu + ((v.u >> 16) & 1u)) >> 16;   // RNE
    return (unsigned short)r;
}

typedef __bf16    bf16x8 __attribute__((ext_vector_type(8)));
typedef float     f32x4  __attribute__((ext_vector_type(4)));
typedef _Float16  f16x8  __attribute__((ext_vector_type(8)));
typedef _Float16  f16x4  __attribute__((ext_vector_type(4)));

// fp32 -> fp16 (hi, lo*4096) split: hi + 2^-12*lo == v to ~2^-22 relative.
__device__ __forceinline__ void fsplit(float v, _Float16& hi, _Float16& lo) {
    hi = (_Float16)v;
    lo = (_Float16)((v - (float)hi) * 4096.0f);
}

// ---------------------------------------------------------------------------
// Split-fp16 MFMA GEMM v4 (encoder): C = relu(A @ Bt^T + bias).
// 512 threads, 128x256 tile (8 waves of 64x64: 2 in M x 4 in N) -> grid.x
// halves to 2, cutting direct-A global re-reads; the 128-row A panel slice
// (16KB/step) is L1-resident so the 4 waves sharing rows hit L1.
// B hi/lo double-buffered in LDS (80KB, 2 blocks/CU); next-tile loads issued
// before the MFMA cluster, LDS writes after (issue-early / write-late).
// 3 MFMA passes: acc0 = Ah*Bh; acc1 = Ah*Bl + Al*Bh; C = acc0 + 2^-12*acc1.
// ---------------------------------------------------------------------------
template<int K, bool AF32>
__global__ __launch_bounds__(512, 2)
void gemm_split4(const void* __restrict__ Asrc,
                 const _Float16* __restrict__ Bhi, const _Float16* __restrict__ Blo,
                 const float* __restrict__ bias,
                 _Float16* __restrict__ Chi, _Float16* __restrict__ Clo,
                 int M, int N)
{
    constexpr int BK  = 32;
    constexpr int LDP = 40;                      // 80B row stride, 16B-aligned
    constexpr int NS  = K / BK;

    __shared__ alignas(16) _Float16 Bh[2][256][LDP];   // 40960 B
    __shared__ alignas(16) _Float16 Bl[2][256][LDP];   // 40960 B

    const int tid  = threadIdx.x;
    const int lane = tid & 63;
    const int w    = tid >> 6;                   // 0..7
    const int wr   = (w >> 2) * 64;              // 2 waves in M
    const int wc   = (w & 3) * 64;               // 4 waves in N
    const int bm   = blockIdx.y * 128;
    const int bn   = blockIdx.x * 256;

    f32x4 acc0[4][4], acc1[4][4];
#pragma unroll
    for (int m = 0; m < 4; ++m)
#pragma unroll
        for (int n = 0; n < 4; ++n) {
            acc0[m][n] = (f32x4){0.f, 0.f, 0.f, 0.f};
            acc1[m][n] = (f32x4){0.f, 0.f, 0.f, 0.f};
        }

    const int arow = bm + wr + (lane & 15);      // A-frag row (m=0)
    const int kgrp = (lane >> 4) * 8;            // k sub-offset
    const int brow = tid >> 1;                   // B staging: 2 thr/row (0..255)
    const int bcol = (tid & 1) * 16;             // 16 f16 (32B) each

    const _Float16* Ahi_ = (const _Float16*)Asrc;
    const float*    Af_  = (const float*)Asrc;

    f16x8 ah[4], al[4], ahn[4], aln[4];
    float4 rbh0, rbh1, rbl0, rbl1;

    auto loadB = [&](int k0) {
        const size_t gb = (size_t)(bn + brow) * K + k0 + bcol;
        rbh0 = *reinterpret_cast<const float4*>(Bhi + gb);
        rbh1 = *reinterpret_cast<const float4*>(Bhi + gb + 8);
        rbl0 = *reinterpret_cast<const float4*>(Blo + gb);
        rbl1 = *reinterpret_cast<const float4*>(Blo + gb + 8);
    };
    auto storeB = [&](int p) {
        *reinterpret_cast<float4*>(&Bh[p][brow][bcol])     = rbh0;
        *reinterpret_cast<float4*>(&Bh[p][brow][bcol + 8]) = rbh1;
        *reinterpret_cast<float4*>(&Bl[p][brow][bcol])     = rbl0;
        *reinterpret_cast<float4*>(&Bl[p][brow][bcol + 8]) = rbl1;
    };
    auto loadA = [&](int k0, f16x8* h, f16x8* l) {
#pragma unroll
        for (int m = 0; m < 4; ++m) {
            const size_t ga = (size_t)(arow + m * 16) * K + k0 + kgrp;
            if constexpr (AF32) {
                float4 v0 = *reinterpret_cast<const float4*>(Af_ + ga);
                float4 v1 = *reinterpret_cast<const float4*>(Af_ + ga + 4);
                float vv[8] = {v0.x, v0.y, v0.z, v0.w, v1.x, v1.y, v1.z, v1.w};
                f16x8 hh, ll;
#pragma unroll
                for (int j = 0; j < 8; ++j) {
                    _Float16 hi, lo; fsplit(vv[j], hi, lo);
                    hh[j] = hi; ll[j] = lo;
                }
                h[m] = hh; l[m] = ll;
            } else {
                h[m] = *reinterpret_cast<const f16x8*>(Ahi_ + ga);
                l[m] = *reinterpret_cast<const f16x8*>(Ahi_ + (size_t)M * K + ga);
            }
        }
    };

    loadB(0);
    loadA(0, ah, al);
    storeB(0);
    __syncthreads();

#pragma unroll
    for (int s = 0; s < NS; ++s) {
        const int p = s & 1;
        if (s + 1 < NS) {                        // issue next-tile loads EARLY
            loadB((s + 1) * BK);
            loadA((s + 1) * BK, ahn, aln);
        }
#pragma unroll
        for (int n = 0; n < 4; ++n) {
            const f16x8 bh = *reinterpret_cast<const f16x8*>(
                &Bh[p][wc + n * 16 + (lane & 15)][kgrp]);
            const f16x8 bl = *reinterpret_cast<const f16x8*>(
                &Bl[p][wc + n * 16 + (lane & 15)][kgrp]);
#pragma unroll
            for (int m = 0; m < 4; ++m)
                acc0[m][n] = __builtin_amdgcn_mfma_f32_16x16x32_f16(
                    ah[m], bh, acc0[m][n], 0, 0, 0);
#pragma unroll
            for (int m = 0; m < 4; ++m)
                acc1[m][n] = __builtin_amdgcn_mfma_f32_16x16x32_f16(
                    ah[m], bl, acc1[m][n], 0, 0, 0);
#pragma unroll
            for (int m = 0; m < 4; ++m)
                acc1[m][n] = __builtin_amdgcn_mfma_f32_16x16x32_f16(
                    al[m], bh, acc1[m][n], 0, 0, 0);
        }
        if (s + 1 < NS) {                        // write-late into other buffer
            storeB(p ^ 1);
#pragma unroll
            for (int m = 0; m < 4; ++m) { ah[m] = ahn[m]; al[m] = aln[m]; }
        }
        __syncthreads();
    }

#pragma unroll
    for (int m = 0; m < 4; ++m)
#pragma unroll
        for (int n = 0; n < 4; ++n) {
            const int col = bn + wc + n * 16 + (lane & 15);
            const float bv = bias[col];
#pragma unroll
            for (int q = 0; q < 4; ++q) {
                const int row = bm + wr + m * 16 + (lane >> 4) * 4 + q;
                float v = acc0[m][n][q] + 2.44140625e-4f * acc1[m][n][q] + bv;
                v = fmaxf(v, 0.f);
                _Float16 hi, lo; fsplit(v, hi, lo);
                Chi[(size_t)row * N + col] = hi;
                Clo[(size_t)row * N + col] = lo;
            }
        }
}

// ---------------------------------------------------------------------------
// z_e GEMM: fp64 accumulation (exact-at-fp32 -> safe VQ argmin + tight
// output-1 check). A consumed from fp16 pair planes, W2 fp32. 64x64 tile.
// ---------------------------------------------------------------------------
__global__ __launch_bounds__(256)
void gemm_ze(const _Float16* __restrict__ Ahi, const _Float16* __restrict__ Alo,
             const float* __restrict__ W, const float* __restrict__ bias,
             float* __restrict__ C, int M, int N, int K)
{
    __shared__ alignas(16) float As[16][64];
    __shared__ alignas(16) float Bs[16][64];

    const int tid = threadIdx.x;
    const int tx  = tid % 16;
    const int ty  = tid / 16;
    const int bm  = blockIdx.y * 64;
    const int bn  = blockIdx.x * 64;

    double acc[4][4];
#pragma unroll
    for (int i = 0; i < 4; ++i)
#pragma unroll
        for (int j = 0; j < 4; ++j) acc[i][j] = 0.0;

    for (int k0 = 0; k0 < K; k0 += 16) {
        {
            int idx = tid * 4;
            int r = idx >> 4, c = idx & 15;
            f16x4 h = *reinterpret_cast<const f16x4*>(&Ahi[(size_t)(bm + r) * K + k0 + c]);
            f16x4 l = *reinterpret_cast<const f16x4*>(&Alo[(size_t)(bm + r) * K + k0 + c]);
#pragma unroll
            for (int i = 0; i < 4; ++i)
                As[c + i][r] = (float)h[i] + 2.44140625e-4f * (float)l[i];
        }
        {
            int idx = tid * 4;
            int r = idx / 64, c = idx % 64;
            *reinterpret_cast<float4*>(&Bs[r][c]) =
                *reinterpret_cast<const float4*>(&W[(size_t)(k0 + r) * N + bn + c]);
        }
        __syncthreads();

#pragma unroll
        for (int kk = 0; kk < 16; ++kk) {
            float a[4], b[4];
#pragma unroll
            for (int i = 0; i < 4; ++i) a[i] = As[kk][ty * 4 + i];
#pragma unroll
            for (int j = 0; j < 4; ++j) b[j] = Bs[kk][tx * 4 + j];
#pragma unroll
            for (int i = 0; i < 4; ++i)
#pragma unroll
                for (int j = 0; j < 4; ++j)
                    acc[i][j] = fma((double)a[i], (double)b[j], acc[i][j]);
        }
        __syncthreads();
    }

#pragma unroll
    for (int ii = 0; ii < 4; ++ii) {
        const size_t r = (size_t)bm + ty * 4 + ii;
        const int c = bn + tx * 4;
        float4 bv = *reinterpret_cast<const float4*>(&bias[c]);
        float4 o;
        o.x = (float)acc[ii][0] + bv.x; o.y = (float)acc[ii][1] + bv.y;
        o.z = (float)acc[ii][2] + bv.z; o.w = (float)acc[ii][3] + bv.w;
        *reinterpret_cast<float4*>(&C[r * N + c]) = o;
    }
}

// ---------------------------------------------------------------------------
// bf16 MFMA GEMM (decoder) -- round-5 version (single-buffered, 4 blocks/CU).
// ---------------------------------------------------------------------------
template<bool RELU, bool OUT_BF16>
__global__ __launch_bounds__(256)
void gemm_mfma_bt(const unsigned short* __restrict__ A,
                  const unsigned short* __restrict__ Bt,
                  const float* __restrict__ bias,
                  void* __restrict__ Cv, int M, int N, int K)
{
    constexpr int BK  = 64;
    constexpr int LDP = BK + 8;

    __shared__ alignas(16) unsigned short Asl[128][LDP];
    __shared__ alignas(16) unsigned short Bsl[128][LDP];

    const int tid  = threadIdx.x;
    const int lane = tid & 63;
    const int w    = tid >> 6;
    const int wr   = (w >> 1) * 64;
    const int wc   = (w & 1) * 64;
    const int bm   = blockIdx.y * 128;
    const int bn   = blockIdx.x * 128;

    f32x4 acc[4][4];
#pragma unroll
    for (int m = 0; m < 4; ++m)
#pragma unroll
        for (int n = 0; n < 4; ++n) acc[m][n] = (f32x4){0.f, 0.f, 0.f, 0.f};

    const int sr = tid >> 1;
    const int sc = (tid & 1) * 32;

    for (int k0 = 0; k0 < K; k0 += BK) {
        {
            const float4* ga = reinterpret_cast<const float4*>(
                &A[(size_t)(bm + sr) * K + k0 + sc]);
            const float4* gb = reinterpret_cast<const float4*>(
                &Bt[(size_t)(bn + sr) * K + k0 + sc]);
            float4 va0 = ga[0], va1 = ga[1], va2 = ga[2], va3 = ga[3];
            float4 vb0 = gb[0], vb1 = gb[1], vb2 = gb[2], vb3 = gb[3];
            float4* da = reinterpret_cast<float4*>(&Asl[sr][sc]);
            float4* db = reinterpret_cast<float4*>(&Bsl[sr][sc]);
            da[0] = va0; da[1] = va1; da[2] = va2; da[3] = va3;
            db[0] = vb0; db[1] = vb1; db[2] = vb2; db[3] = vb3;
        }
        __syncthreads();

#pragma unroll
        for (int ks = 0; ks < 2; ++ks) {
            bf16x8 af[4], bf[4];
            const int kc = ks * 32 + (lane >> 4) * 8;
#pragma unroll
            for (int m = 0; m < 4; ++m)
                af[m] = *reinterpret_cast<const bf16x8*>(
                    &Asl[wr + m * 16 + (lane & 15)][kc]);
#pragma unroll
            for (int n = 0; n < 4; ++n)
                bf[n] = *reinterpret_cast<const bf16x8*>(
                    &Bsl[wc + n * 16 + (lane & 15)][kc]);
#pragma unroll
            for (int m = 0; m < 4; ++m)
#pragma unroll
                for (int n = 0; n < 4; ++n)
                    acc[m][n] = __builtin_amdgcn_mfma_f32_16x16x32_bf16(
                        af[m], bf[n], acc[m][n], 0, 0, 0);
        }
        __syncthreads();
    }

#pragma unroll
    for (int m = 0; m < 4; ++m)
#pragma unroll
        for (int n = 0; n < 4; ++n) {
            const int col = bn + wc + n * 16 + (lane & 15);
            const float bv = bias[col];
#pragma unroll
            for (int q = 0; q < 4; ++q) {
                const int row = bm + wr + m * 16 + (lane >> 4) * 4 + q;
                float v = acc[m][n][q] + bv;
                if (RELU) v = fmaxf(v, 0.f);
                if (OUT_BF16)
                    reinterpret_cast<unsigned short*>(Cv)[(size_t)row * N + col] = f2bf(v);
                else
                    reinterpret_cast<float*>(Cv)[(size_t)row * N + col] = v;
            }
        }
}

// ---------------------------------------------------------------------------
// small prep kernels
// ---------------------------------------------------------------------------
__global__ __launch_bounds__(256)
void transpose_bf16(const float* __restrict__ W, unsigned short* __restrict__ Wt,
                    int K, int N)
{
    int idx = blockIdx.x * 256 + threadIdx.x;
    if (idx >= K * N) return;
    int n = idx / K, k = idx % K;
    Wt[idx] = f2bf(W[(size_t)k * N + n]);
}

__global__ __launch_bounds__(256)
void transpose_split_f16(const float* __restrict__ W,
                         _Float16* __restrict__ Whi, _Float16* __restrict__ Wlo,
                         int K, int N)
{
    int idx = blockIdx.x * 256 + threadIdx.x;
    if (idx >= K * N) return;
    int n = idx / K, k = idx % K;
    _Float16 hi, lo; fsplit(W[(size_t)k * N + n], hi, lo);
    Whi[idx] = hi; Wlo[idx] = lo;
}

// ---------------------------------------------------------------------------
// VQ v2: fp32 filter + exact-fp64 near-tie rescan. No LDS codebook (reads are
// wave-uniform -> scalar cache). EPS=1e-3 >> 2x fp32-d2 error bound (~2.6e-4):
// winner provably equals the exact first-min unless gap <= EPS, in which case
// the fp64 candidate rescan (ascending index, strict <) decides.
// ---------------------------------------------------------------------------
__global__ __launch_bounds__(256)
void vq_gather2(const float* __restrict__ Z, const float* __restrict__ CB,
                float* __restrict__ OUT, unsigned short* __restrict__ ZQB)
{
    __shared__ float  ccf[256];
    __shared__ double ccd[256];

    const int tid = threadIdx.x;
    const int row = blockIdx.x * 256 + tid;

    {   // per-entry |c|^2, fp64 (thread tid = entry tid)
        const float4* c4 = reinterpret_cast<const float4*>(CB + (size_t)tid * 64);
        double cc = 0.0;
#pragma unroll
        for (int v = 0; v < 16; ++v) {
            float4 f = c4[v];
            cc = fma((double)f.x, (double)f.x, cc);
            cc = fma((double)f.y, (double)f.y, cc);
            cc = fma((double)f.z, (double)f.z, cc);
            cc = fma((double)f.w, (double)f.w, cc);
        }
        ccd[tid] = cc; ccf[tid] = (float)cc;
    }
    __syncthreads();

    float z[64];
#pragma unroll
    for (int v = 0; v < 16; ++v) {
        float4 f = *reinterpret_cast<const float4*>(&Z[(size_t)row * 64 + v * 4]);
        z[v * 4 + 0] = f.x; z[v * 4 + 1] = f.y; z[v * 4 + 2] = f.z; z[v * 4 + 3] = f.w;
    }
    double xx = 0.0;
#pragma unroll
    for (int d = 0; d < 64; ++d) xx = fma((double)z[d], (double)z[d], xx);
    const float xxf = (float)xx;

    // pass 1: fp32 d2 over all entries; track min, runner-up value
    float bv1 = 3.4e38f, bv2 = 3.4e38f;
    int   bi  = 0;
    for (int e = 0; e < 256; ++e) {
        const float4* c4 = reinterpret_cast<const float4*>(CB + (size_t)e * 64);
        float d0 = 0.f, d1 = 0.f, d2a = 0.f, d3 = 0.f;
#pragma unroll
        for (int v = 0; v < 16; v += 4) {
            float4 f0 = c4[v], f1 = c4[v + 1], f2 = c4[v + 2], f3 = c4[v + 3];
            d0 = fmaf(z[v*4+ 0], f0.x, d0); d0 = fmaf(z[v*4+ 1], f0.y, d0);
            d0 = fmaf(z[v*4+ 2], f0.z, d0); d0 = fmaf(z[v*4+ 3], f0.w, d0);
            d1 = fmaf(z[v*4+ 4], f1.x, d1); d1 = fmaf(z[v*4+ 5], f1.y, d1);
            d1 = fmaf(z[v*4+ 6], f1.z, d1); d1 = fmaf(z[v*4+ 7], f1.w, d1);
            d2a= fmaf(z[v*4+ 8], f2.x, d2a); d2a= fmaf(z[v*4+ 9], f2.y, d2a);
            d2a= fmaf(z[v*4+10], f2.z, d2a); d2a= fmaf(z[v*4+11], f2.w, d2a);
            d3 = fmaf(z[v*4+12], f3.x, d3); d3 = fmaf(z[v*4+13], f3.y, d3);
            d3 = fmaf(z[v*4+14], f3.z, d3); d3 = fmaf(z[v*4+15], f3.w, d3);
        }
        float dot = (d0 + d1) + (d2a + d3);
        float d2  = (xxf - 2.0f * dot) + ccf[e];
        if (d2 < bv1)      { bv2 = bv1; bv1 = d2; bi = e; }
        else if (d2 < bv2) { bv2 = d2; }
    }

    // pass 2 (rare): near-tie -> exact fp64 over candidates, ascending index
    if (!(bv2 - bv1 > 1e-3f)) {
        const float thr = bv1 + 1e-3f;
        double bestx = 1.0e300; int bix = 0;
        for (int e = 0; e < 256; ++e) {
            const float4* c4 = reinterpret_cast<const float4*>(CB + (size_t)e * 64);
            float d0 = 0.f, d1 = 0.f, d2a = 0.f, d3 = 0.f;
#pragma unroll
            for (int v = 0; v < 16; v += 4) {
                float4 f0 = c4[v], f1 = c4[v + 1], f2 = c4[v + 2], f3 = c4[v + 3];
                d0 = fmaf(z[v*4+ 0], f0.x, d0); d0 = fmaf(z[v*4+ 1], f0.y, d0);
                d0 = fmaf(z[v*4+ 2], f0.z, d0); d0 = fmaf(z[v*4+ 3], f0.w, d0);
                d1 = fmaf(z[v*4+ 4], f1.x, d1); d1 = fmaf(z[v*4+ 5], f1.y, d1);
                d1 = fmaf(z[v*4+ 6], f1.z, d1); d1 = fmaf(z[v*4+ 7], f1.w, d1);
                d2a= fmaf(z[v*4+ 8], f2.x, d2a); d2a= fmaf(z[v*4+ 9], f2.y, d2a);
                d2a= fmaf(z[v*4+10], f2.z, d2a); d2a= fmaf(z[v*4+11], f2.w, d2a);
                d3 = fmaf(z[v*4+12], f3.x, d3); d3 = fmaf(z[v*4+13], f3.y, d3);
                d3 = fmaf(z[v*4+14], f3.z, d3); d3 = fmaf(z[v*4+15], f3.w, d3);
            }
            float dot = (d0 + d1) + (d2a + d3);
            float d2  = (xxf - 2.0f * dot) + ccf[e];
            if (d2 <= thr) {
                double dx = 0.0;
#pragma unroll
                for (int v = 0; v < 16; ++v) {
                    float4 f = c4[v];
                    dx = fma((double)z[v*4+0], (double)f.x, dx);
                    dx = fma((double)z[v*4+1], (double)f.y, dx);
                    dx = fma((double)z[v*4+2], (double)f.z, dx);
                    dx = fma((double)z[v*4+3], (double)f.w, dx);
                }
                double d2x = (xx - 2.0 * dx) + ccd[e];
                if (d2x < bestx) { bestx = d2x; bix = e; }
            }
        }
        bi = bix;
    }

    // gather codebook[bi] -> OUT row + bf16 z_q
    {
        const float4* src = reinterpret_cast<const float4*>(CB + (size_t)bi * 64);
        float* dst = &OUT[(size_t)row * 64];
        unsigned short* dq = &ZQB[(size_t)row * 64];
#pragma unroll
        for (int v = 0; v < 16; ++v) {
            float4 f = src[v];
            *reinterpret_cast<float4*>(dst + v * 4) = f;
            ushort4 qb = { f2bf(f.x), f2bf(f.y), f2bf(f.z), f2bf(f.w) };
            *reinterpret_cast<ushort4*>(dq + v * 4) = qb;
        }
    }
}

// ---------------------------------------------------------------------------
extern "C" void kernel_launch(void* const* d_in, const int* in_sizes, int n_in,
                              void* d_out, int out_size, void* d_ws, size_t ws_size,
                              hipStream_t stream)
{
    const float* X  = (const float*)d_in[0];
    const float* W0 = (const float*)d_in[1];
    const float* b0 = (const float*)d_in[2];
    const float* W1 = (const float*)d_in[3];
    const float* b1 = (const float*)d_in[4];
    const float* W2 = (const float*)d_in[5];
    const float* b2 = (const float*)d_in[6];
    const float* CB = (const float*)d_in[7];
    const float* W3 = (const float*)d_in[8];
    const float* b3 = (const float*)d_in[9];
    const float* W4 = (const float*)d_in[10];
    const float* b4 = (const float*)d_in[11];
    const float* W5 = (const float*)d_in[12];
    const float* b5 = (const float*)d_in[13];

    const int D_in = 256, H = 512, R = 64, S = 512, NA = 8;
    const int Mtot = in_sizes[0] / D_in;          // 131072

    float* recon = (float*)d_out;
    float* ze    = recon + (size_t)(Mtot / NA) * S;
    float* remb  = ze + (size_t)Mtot * R;

    // ---- workspace: fixed weight planes ----
    char* p = (char*)d_ws;
    _Float16* W0hi = (_Float16*)p;  p += (size_t)H * D_in * 2;
    _Float16* W0lo = (_Float16*)p;  p += (size_t)H * D_in * 2;
    _Float16* W1hi = (_Float16*)p;  p += (size_t)H * H * 2;
    _Float16* W1lo = (_Float16*)p;  p += (size_t)H * H * 2;
    unsigned short* W3t = (unsigned short*)p;  p += (size_t)H * R * 2;
    unsigned short* W4t = (unsigned short*)p;  p += (size_t)H * (NA * H) * 2;
    unsigned short* W5t = (unsigned short*)p;  p += (size_t)S * H * 2;
    size_t fixed = (size_t)(p - (char*)d_ws);
    fixed = (fixed + 255) & ~(size_t)255;

    // per-row chunk bytes: h0 pair 2048 + h1 pair 2048 + zqb 128
    int nc = 2;
    while (nc < 128) {
        size_t rpcT = (size_t)Mtot / nc;
        if (fixed + rpcT * 4224 + 1024 <= ws_size) break;
        nc *= 2;
    }
    const int rpc = Mtot / nc;
    char* q = (char*)d_ws + fixed;
    // NOTE: h0hi and h0lo must be contiguous (gemm_split4 A-pair uses +M*K):
    _Float16* h0hi = (_Float16*)q;                 q += (size_t)rpc * H * 2;
    _Float16* h0lo = (_Float16*)q;                 q += (size_t)rpc * H * 2;
    _Float16* h1hi = (_Float16*)q;                 q += (size_t)rpc * H * 2;
    _Float16* h1lo = (_Float16*)q;                 q += (size_t)rpc * H * 2;
    unsigned short* zqb = (unsigned short*)q;      q += (size_t)rpc * R * 2;
    unsigned short* rec1b = (unsigned short*)h0hi;     // alias (h0 dead after h1)
    unsigned short* rec2b = (unsigned short*)h1hi;     // alias (h1 dead after z_e)

    // ---- one-time weight prep ----
    transpose_split_f16<<<(H * D_in + 255) / 256, 256, 0, stream>>>(W0, W0hi, W0lo, D_in, H);
    transpose_split_f16<<<(H * H + 255) / 256, 256, 0, stream>>>(W1, W1hi, W1lo, H, H);
    transpose_bf16<<<(H * R + 255) / 256, 256, 0, stream>>>(W3, W3t, R, H);
    transpose_bf16<<<(H * NA * H + 255) / 256, 256, 0, stream>>>(W4, W4t, NA * H, H);
    transpose_bf16<<<(S * H + 255) / 256, 256, 0, stream>>>(W5, W5t, H, S);

    for (int r0 = 0; r0 < Mtot; r0 += rpc) {
        const int M6 = rpc / NA;
        // encoder: split-fp16 MFMA, 128x256 tile, A direct from global
        gemm_split4<256, true><<<dim3(H / 256, rpc / 128), 512, 0, stream>>>(
            X + (size_t)r0 * D_in, W0hi, W0lo, b0, h0hi, h0lo, rpc, H);
        gemm_split4<512, false><<<dim3(H / 256, rpc / 128), 512, 0, stream>>>(
            h0hi, W1hi, W1lo, b1, h1hi, h1lo, rpc, H);
        // z_e: fp64 accumulation -> output zone 1
        gemm_ze<<<dim3(1, rpc / 64), 256, 0, stream>>>(
            h1hi, h1lo, W2, b2, ze + (size_t)r0 * R, rpc, R, H);
        // exact VQ -> role_emb + bf16 z_q
        vq_gather2<<<rpc / 256, 256, 0, stream>>>(
            ze + (size_t)r0 * R, CB, remb + (size_t)r0 * R, zqb);
        // decoder: bf16 MFMA (round-5 single-buffered version)
        gemm_mfma_bt<true, true><<<dim3(H / 128, rpc / 128), 256, 0, stream>>>(
            zqb, W3t, b3, rec1b, rpc, H, R);
        gemm_mfma_bt<true, true><<<dim3(H / 128, M6 / 128), 256, 0, stream>>>(
            rec1b, W4t, b4, rec2b, M6, H, NA * H);
        gemm_mfma_bt<false, false><<<dim3(S / 128, M6 / 128), 256, 0, stream>>>(
            rec2b, W5t, b5, recon + (size_t)(r0 / NA) * S, M6, S, H);
    }
}

// Round 8
// 1622.339 us; speedup vs baseline: 1.0994x; 1.0819x over previous
//
#include <hip/hip_runtime.h>
#include <hip/hip_bf16.h>
#include <cstddef>

__device__ __forceinline__ unsigned short f2bf(float f) {
    union { float f; unsigned int u; } v; v.f = f;
    unsigned int r = (v.u + 0x7fffu + ((v.u >> 16) & 1u)) >> 16;   // RNE
    return (unsigned short)r;
}

typedef __bf16    bf16x8 __attribute__((ext_vector_type(8)));
typedef float     f32x4  __attribute__((ext_vector_type(4)));
typedef _Float16  f16x8  __attribute__((ext_vector_type(8)));

#define SPLIT_SCALE 2.44140625e-4f   // 2^-12

// fp32 -> fp16 (hi, lo*4096) split: hi + 2^-12*lo == v to ~2^-22 relative.
__device__ __forceinline__ void fsplit(float v, _Float16& hi, _Float16& lo) {
    hi = (_Float16)v;
    lo = (_Float16)((v - (float)hi) * 4096.0f);
}

// ---------------------------------------------------------------------------
// Split-fp16 MFMA GEMM (encoder): C = relu(A @ Bt^T + bias). 128x256 tile,
// 512 thr, B hi/lo double-buffered LDS, A direct from global, issue-early /
// write-late. + bijective XCD chunk swizzle (nwg%8==0) so the grid.x pair
// sharing an A panel lands on one XCD's L2.
// ---------------------------------------------------------------------------
template<int K, bool AF32>
__global__ __launch_bounds__(512, 2)
void gemm_split4(const void* __restrict__ Asrc,
                 const _Float16* __restrict__ Bhi, const _Float16* __restrict__ Blo,
                 const float* __restrict__ bias,
                 _Float16* __restrict__ Chi, _Float16* __restrict__ Clo,
                 int M, int N)
{
    constexpr int BK  = 32;
    constexpr int LDP = 40;
    constexpr int NS  = K / BK;

    __shared__ alignas(16) _Float16 Bh[2][256][LDP];
    __shared__ alignas(16) _Float16 Bl[2][256][LDP];

    const int tid  = threadIdx.x;
    const int lane = tid & 63;
    const int w    = tid >> 6;
    const int wr   = (w >> 2) * 64;
    const int wc   = (w & 3) * 64;

    // XCD chunk swizzle (dispatch id d -> role L; d%8 == XCD stays fixed,
    // consecutive roles map to same XCD)
    int bx = blockIdx.x, by = blockIdx.y;
    {
        const int gx = gridDim.x, nwg = gx * gridDim.y;
        if ((nwg & 7) == 0) {
            int d = bx + by * gx;
            int L = (d & 7) * (nwg >> 3) + (d >> 3);
            bx = L % gx; by = L / gx;
        }
    }
    const int bm = by * 128;
    const int bn = bx * 256;

    f32x4 acc0[4][4], acc1[4][4];
#pragma unroll
    for (int m = 0; m < 4; ++m)
#pragma unroll
        for (int n = 0; n < 4; ++n) {
            acc0[m][n] = (f32x4){0.f, 0.f, 0.f, 0.f};
            acc1[m][n] = (f32x4){0.f, 0.f, 0.f, 0.f};
        }

    const int arow = bm + wr + (lane & 15);
    const int kgrp = (lane >> 4) * 8;
    const int brow = tid >> 1;
    const int bcol = (tid & 1) * 16;

    const _Float16* Ahi_ = (const _Float16*)Asrc;
    const float*    Af_  = (const float*)Asrc;

    f16x8 ah[4], al[4], ahn[4], aln[4];
    float4 rbh0, rbh1, rbl0, rbl1;

    auto loadB = [&](int k0) {
        const size_t gb = (size_t)(bn + brow) * K + k0 + bcol;
        rbh0 = *reinterpret_cast<const float4*>(Bhi + gb);
        rbh1 = *reinterpret_cast<const float4*>(Bhi + gb + 8);
        rbl0 = *reinterpret_cast<const float4*>(Blo + gb);
        rbl1 = *reinterpret_cast<const float4*>(Blo + gb + 8);
    };
    auto storeB = [&](int p) {
        *reinterpret_cast<float4*>(&Bh[p][brow][bcol])     = rbh0;
        *reinterpret_cast<float4*>(&Bh[p][brow][bcol + 8]) = rbh1;
        *reinterpret_cast<float4*>(&Bl[p][brow][bcol])     = rbl0;
        *reinterpret_cast<float4*>(&Bl[p][brow][bcol + 8]) = rbl1;
    };
    auto loadA = [&](int k0, f16x8* h, f16x8* l) {
#pragma unroll
        for (int m = 0; m < 4; ++m) {
            const size_t ga = (size_t)(arow + m * 16) * K + k0 + kgrp;
            if constexpr (AF32) {
                float4 v0 = *reinterpret_cast<const float4*>(Af_ + ga);
                float4 v1 = *reinterpret_cast<const float4*>(Af_ + ga + 4);
                float vv[8] = {v0.x, v0.y, v0.z, v0.w, v1.x, v1.y, v1.z, v1.w};
                f16x8 hh, ll;
#pragma unroll
                for (int j = 0; j < 8; ++j) {
                    _Float16 hi, lo; fsplit(vv[j], hi, lo);
                    hh[j] = hi; ll[j] = lo;
                }
                h[m] = hh; l[m] = ll;
            } else {
                h[m] = *reinterpret_cast<const f16x8*>(Ahi_ + ga);
                l[m] = *reinterpret_cast<const f16x8*>(Ahi_ + (size_t)M * K + ga);
            }
        }
    };

    loadB(0);
    loadA(0, ah, al);
    storeB(0);
    __syncthreads();

#pragma unroll
    for (int s = 0; s < NS; ++s) {
        const int p = s & 1;
        if (s + 1 < NS) {
            loadB((s + 1) * BK);
            loadA((s + 1) * BK, ahn, aln);
        }
#pragma unroll
        for (int n = 0; n < 4; ++n) {
            const f16x8 bh = *reinterpret_cast<const f16x8*>(
                &Bh[p][wc + n * 16 + (lane & 15)][kgrp]);
            const f16x8 bl = *reinterpret_cast<const f16x8*>(
                &Bl[p][wc + n * 16 + (lane & 15)][kgrp]);
#pragma unroll
            for (int m = 0; m < 4; ++m)
                acc0[m][n] = __builtin_amdgcn_mfma_f32_16x16x32_f16(
                    ah[m], bh, acc0[m][n], 0, 0, 0);
#pragma unroll
            for (int m = 0; m < 4; ++m)
                acc1[m][n] = __builtin_amdgcn_mfma_f32_16x16x32_f16(
                    ah[m], bl, acc1[m][n], 0, 0, 0);
#pragma unroll
            for (int m = 0; m < 4; ++m)
                acc1[m][n] = __builtin_amdgcn_mfma_f32_16x16x32_f16(
                    al[m], bh, acc1[m][n], 0, 0, 0);
        }
        if (s + 1 < NS) {
            storeB(p ^ 1);
#pragma unroll
            for (int m = 0; m < 4; ++m) { ah[m] = ahn[m]; al[m] = aln[m]; }
        }
        __syncthreads();
    }

#pragma unroll
    for (int m = 0; m < 4; ++m)
#pragma unroll
        for (int n = 0; n < 4; ++n) {
            const int col = bn + wc + n * 16 + (lane & 15);
            const float bv = bias[col];
#pragma unroll
            for (int q = 0; q < 4; ++q) {
                const int row = bm + wr + m * 16 + (lane >> 4) * 4 + q;
                float v = acc0[m][n][q] + SPLIT_SCALE * acc1[m][n][q] + bv;
                v = fmaxf(v, 0.f);
                _Float16 hi, lo; fsplit(v, hi, lo);
                Chi[(size_t)row * N + col] = hi;
                Clo[(size_t)row * N + col] = lo;
            }
        }
}

// ---------------------------------------------------------------------------
// z_e GEMM via split-fp16 MFMA: ze[M,64] = h1 @ W2 + b2, fp32 accumulation.
// 128x64 tile, 256 thr (4 waves: 2M x 2N of 64x32). A (h1 pair planes) and
// B (W2t pair planes, [64][512], L1/L2-resident) read direct from global.
// Error class == np's own fp32 GEMM noise (~3e-6) -> output-1 check safe;
// argmin safety unchanged (vq's fp64 near-tie rescan keys off our ze).
// ---------------------------------------------------------------------------
__global__ __launch_bounds__(256)
void gemm_ze_mfma(const _Float16* __restrict__ Ahi, const _Float16* __restrict__ Alo,
                  const _Float16* __restrict__ Bhi, const _Float16* __restrict__ Blo,
                  const float* __restrict__ bias, float* __restrict__ C, int M)
{
    constexpr int K = 512, N = 64;
    const int tid  = threadIdx.x;
    const int lane = tid & 63;
    const int w    = tid >> 6;
    const int wr   = (w >> 1) * 64;
    const int wc   = (w & 1) * 32;
    const int bm   = blockIdx.x * 128;

    f32x4 acc0[4][2], acc1[4][2];
#pragma unroll
    for (int m = 0; m < 4; ++m)
#pragma unroll
        for (int n = 0; n < 2; ++n) {
            acc0[m][n] = (f32x4){0.f, 0.f, 0.f, 0.f};
            acc1[m][n] = (f32x4){0.f, 0.f, 0.f, 0.f};
        }

    const int arow = bm + wr + (lane & 15);
    const int kgrp = (lane >> 4) * 8;

#pragma unroll
    for (int ks = 0; ks < K / 32; ++ks) {
        const int k0 = ks * 32 + kgrp;
        f16x8 ah[4], al[4];
#pragma unroll
        for (int m = 0; m < 4; ++m) {
            const size_t ga = (size_t)(arow + m * 16) * K + k0;
            ah[m] = *reinterpret_cast<const f16x8*>(Ahi + ga);
            al[m] = *reinterpret_cast<const f16x8*>(Alo + ga);
        }
#pragma unroll
        for (int n = 0; n < 2; ++n) {
            const size_t gb = (size_t)(wc + n * 16 + (lane & 15)) * K + k0;
            const f16x8 bh = *reinterpret_cast<const f16x8*>(Bhi + gb);
            const f16x8 bl = *reinterpret_cast<const f16x8*>(Blo + gb);
#pragma unroll
            for (int m = 0; m < 4; ++m)
                acc0[m][n] = __builtin_amdgcn_mfma_f32_16x16x32_f16(
                    ah[m], bh, acc0[m][n], 0, 0, 0);
#pragma unroll
            for (int m = 0; m < 4; ++m)
                acc1[m][n] = __builtin_amdgcn_mfma_f32_16x16x32_f16(
                    ah[m], bl, acc1[m][n], 0, 0, 0);
#pragma unroll
            for (int m = 0; m < 4; ++m)
                acc1[m][n] = __builtin_amdgcn_mfma_f32_16x16x32_f16(
                    al[m], bh, acc1[m][n], 0, 0, 0);
        }
    }

#pragma unroll
    for (int m = 0; m < 4; ++m)
#pragma unroll
        for (int n = 0; n < 2; ++n) {
            const int col = wc + n * 16 + (lane & 15);
            const float bv = bias[col];
#pragma unroll
            for (int q = 0; q < 4; ++q) {
                const int row = bm + wr + m * 16 + (lane >> 4) * 4 + q;
                C[(size_t)row * N + col] = acc0[m][n][q] + SPLIT_SCALE * acc1[m][n][q] + bv;
            }
        }
}

// ---------------------------------------------------------------------------
// VQ via MFMA: one block = 128 rows x all 256 entries (128x256x64 GEMM in
// split-fp16, 8 waves). d2f = xx - 2*dot + cc computed to ~4e-5; fp32
// first-min argmin via in-reg + shfl_xor reduction; rows whose runner-up is
// within EPS=1e-3 get an exact fp64 full rescan (first-min). Then gather
// CB[bi] -> OUT (fp32) and ZQB (bf16).
// ---------------------------------------------------------------------------
#define VQ_EPS 1e-3f
__global__ __launch_bounds__(512)
void vq_mfma(const float* __restrict__ Z, const float* __restrict__ CB,
             const _Float16* __restrict__ Chi, const _Float16* __restrict__ Clo,
             float* __restrict__ OUT, unsigned short* __restrict__ ZQB)
{
    __shared__ float  ccf[256];
    __shared__ double ccd[256];
    __shared__ float  xxf[128];
    __shared__ double xxd[128];
    __shared__ float  redv[4][128];
    __shared__ int    redi[4][128];
    __shared__ float  bv1s[128];
    __shared__ int    bis[128];
    __shared__ int    flags[128];

    const int tid  = threadIdx.x;
    const int lane = tid & 63;
    const int w    = tid >> 6;
    const int wr   = (w >> 2) * 64;              // 2 M-waves
    const int wc   = (w & 3) * 64;               // 4 N-waves
    const int bm   = blockIdx.x * 128;

    // ---- phase A: stats ----
    if (tid < 256) {
        const float4* c4 = reinterpret_cast<const float4*>(CB + (size_t)tid * 64);
        double cc = 0.0;
#pragma unroll
        for (int v = 0; v < 16; ++v) {
            float4 f = c4[v];
            cc = fma((double)f.x, (double)f.x, cc);
            cc = fma((double)f.y, (double)f.y, cc);
            cc = fma((double)f.z, (double)f.z, cc);
            cc = fma((double)f.w, (double)f.w, cc);
        }
        ccd[tid] = cc; ccf[tid] = (float)cc;
    }
    if (tid < 128) {
        const float4* z4 = reinterpret_cast<const float4*>(Z + (size_t)(bm + tid) * 64);
        double xx = 0.0;
#pragma unroll
        for (int v = 0; v < 16; ++v) {
            float4 f = z4[v];
            xx = fma((double)f.x, (double)f.x, xx);
            xx = fma((double)f.y, (double)f.y, xx);
            xx = fma((double)f.z, (double)f.z, xx);
            xx = fma((double)f.w, (double)f.w, xx);
        }
        xxd[tid] = xx; xxf[tid] = (float)xx;
        flags[tid] = 0;
    }
    __syncthreads();

    // ---- phase B: split-fp16 MFMA dot products ----
    f32x4 acc0[4][4], acc1[4][4];
#pragma unroll
    for (int m = 0; m < 4; ++m)
#pragma unroll
        for (int n = 0; n < 4; ++n) {
            acc0[m][n] = (f32x4){0.f, 0.f, 0.f, 0.f};
            acc1[m][n] = (f32x4){0.f, 0.f, 0.f, 0.f};
        }

    const int arow = bm + wr + (lane & 15);
    const int kgrp = (lane >> 4) * 8;

#pragma unroll
    for (int ks = 0; ks < 2; ++ks) {
        const int k0 = ks * 32 + kgrp;
        f16x8 ah[4], al[4];
#pragma unroll
        for (int m = 0; m < 4; ++m) {
            const float* src = Z + (size_t)(arow + m * 16) * 64 + k0;
            float4 v0 = *reinterpret_cast<const float4*>(src);
            float4 v1 = *reinterpret_cast<const float4*>(src + 4);
            float vv[8] = {v0.x, v0.y, v0.z, v0.w, v1.x, v1.y, v1.z, v1.w};
            f16x8 hh, ll;
#pragma unroll
            for (int j = 0; j < 8; ++j) {
                _Float16 hi, lo; fsplit(vv[j], hi, lo);
                hh[j] = hi; ll[j] = lo;
            }
            ah[m] = hh; al[m] = ll;
        }
#pragma unroll
        for (int n = 0; n < 4; ++n) {
            const size_t gb = (size_t)(wc + n * 16 + (lane & 15)) * 64 + k0;
            const f16x8 bh = *reinterpret_cast<const f16x8*>(Chi + gb);
            const f16x8 bl = *reinterpret_cast<const f16x8*>(Clo + gb);
#pragma unroll
            for (int m = 0; m < 4; ++m)
                acc0[m][n] = __builtin_amdgcn_mfma_f32_16x16x32_f16(
                    ah[m], bh, acc0[m][n], 0, 0, 0);
#pragma unroll
            for (int m = 0; m < 4; ++m)
                acc1[m][n] = __builtin_amdgcn_mfma_f32_16x16x32_f16(
                    ah[m], bl, acc1[m][n], 0, 0, 0);
#pragma unroll
            for (int m = 0; m < 4; ++m)
                acc1[m][n] = __builtin_amdgcn_mfma_f32_16x16x32_f16(
                    al[m], bh, acc1[m][n], 0, 0, 0);
        }
    }

    // fold into d2f (store in acc0): d2 = xx - 2*dot + cc
#pragma unroll
    for (int m = 0; m < 4; ++m)
#pragma unroll
        for (int n = 0; n < 4; ++n) {
            const int col = wc + n * 16 + (lane & 15);
            const float cf = ccf[col];
#pragma unroll
            for (int q = 0; q < 4; ++q) {
                const int rl = wr + m * 16 + (lane >> 4) * 4 + q;
                float dot = acc0[m][n][q] + SPLIT_SCALE * acc1[m][n][q];
                acc0[m][n][q] = (xxf[rl] - 2.0f * dot) + cf;
            }
        }

    // ---- phase C: argmin reduction (first-min) ----
    float bvr[4][4]; int bir[4][4];
#pragma unroll
    for (int m = 0; m < 4; ++m)
#pragma unroll
        for (int q = 0; q < 4; ++q) {
            float bv = 3.4e38f; int bi = 0;
#pragma unroll
            for (int n = 0; n < 4; ++n) {
                const int col = wc + n * 16 + (lane & 15);
                const float v = acc0[m][n][q];
                if (v < bv || (v == bv && col < bi)) { bv = v; bi = col; }
            }
            bvr[m][q] = bv; bir[m][q] = bi;
        }
#pragma unroll
    for (int mask = 1; mask < 16; mask <<= 1) {
#pragma unroll
        for (int m = 0; m < 4; ++m)
#pragma unroll
            for (int q = 0; q < 4; ++q) {
                float ov = __shfl_xor(bvr[m][q], mask);
                int   oi = __shfl_xor(bir[m][q], mask);
                if (ov < bvr[m][q] || (ov == bvr[m][q] && oi < bir[m][q])) {
                    bvr[m][q] = ov; bir[m][q] = oi;
                }
            }
    }
    if ((lane & 15) == 0) {
#pragma unroll
        for (int m = 0; m < 4; ++m)
#pragma unroll
            for (int q = 0; q < 4; ++q) {
                const int rl = wr + m * 16 + (lane >> 4) * 4 + q;
                redv[w & 3][rl] = bvr[m][q];
                redi[w & 3][rl] = bir[m][q];
            }
    }
    __syncthreads();

    if (tid < 128) {
        float bv = 3.4e38f; int bi = 0;
#pragma unroll
        for (int nw = 0; nw < 4; ++nw) {        // ascending entry ranges
            float v = redv[nw][tid];
            if (v < bv) { bv = v; bi = redi[nw][tid]; }
        }
        bv1s[tid] = bv; bis[tid] = bi;
    }
    __syncthreads();

    // ---- phase D: near-tie detection ----
#pragma unroll
    for (int m = 0; m < 4; ++m)
#pragma unroll
        for (int q = 0; q < 4; ++q) {
            const int rl = wr + m * 16 + (lane >> 4) * 4 + q;
            const float thr = bv1s[rl] + VQ_EPS;
            const int   win = bis[rl];
#pragma unroll
            for (int n = 0; n < 4; ++n) {
                const int col = wc + n * 16 + (lane & 15);
                if (acc0[m][n][q] <= thr && col != win) flags[rl] = 1;
            }
        }
    __syncthreads();

    // ---- phase E: rare exact rescan (fp64, first-min over all entries) ----
    if (tid < 128 && flags[tid]) {
        const float* zr = Z + (size_t)(bm + tid) * 64;
        double zd[64];
#pragma unroll
        for (int d = 0; d < 64; ++d) zd[d] = (double)zr[d];
        const double xx = xxd[tid];
        double best = 1.0e300; int bi = 0;
        for (int e = 0; e < 256; ++e) {
            const float* c = CB + (size_t)e * 64;
            double dot = 0.0;
#pragma unroll
            for (int d = 0; d < 64; ++d) dot = fma(zd[d], (double)c[d], dot);
            double d2 = (xx - 2.0 * dot) + ccd[e];
            if (d2 < best) { best = d2; bi = e; }
        }
        bis[tid] = bi;
    }
    __syncthreads();

    // ---- phase F: gather ----
    {
        const int row  = tid >> 2;
        const int part = tid & 3;
        const int bi   = bis[row];
        const float4* src = reinterpret_cast<const float4*>(CB + (size_t)bi * 64) + part * 4;
        float* dst = OUT + (size_t)(bm + row) * 64 + part * 16;
        unsigned short* dq = ZQB + (size_t)(bm + row) * 64 + part * 16;
#pragma unroll
        for (int v = 0; v < 4; ++v) {
            float4 f = src[v];
            *reinterpret_cast<float4*>(dst + v * 4) = f;
            ushort4 qb = { f2bf(f.x), f2bf(f.y), f2bf(f.z), f2bf(f.w) };
            *reinterpret_cast<ushort4*>(dq + v * 4) = qb;
        }
    }
}

// ---------------------------------------------------------------------------
// bf16 MFMA GEMM (decoder) -- single-buffered (round-5 known-good).
// ---------------------------------------------------------------------------
template<bool RELU, bool OUT_BF16>
__global__ __launch_bounds__(256)
void gemm_mfma_bt(const unsigned short* __restrict__ A,
                  const unsigned short* __restrict__ Bt,
                  const float* __restrict__ bias,
                  void* __restrict__ Cv, int M, int N, int K)
{
    constexpr int BK  = 64;
    constexpr int LDP = BK + 8;

    __shared__ alignas(16) unsigned short Asl[128][LDP];
    __shared__ alignas(16) unsigned short Bsl[128][LDP];

    const int tid  = threadIdx.x;
    const int lane = tid & 63;
    const int w    = tid >> 6;
    const int wr   = (w >> 1) * 64;
    const int wc   = (w & 1) * 64;
    const int bm   = blockIdx.y * 128;
    const int bn   = blockIdx.x * 128;

    f32x4 acc[4][4];
#pragma unroll
    for (int m = 0; m < 4; ++m)
#pragma unroll
        for (int n = 0; n < 4; ++n) acc[m][n] = (f32x4){0.f, 0.f, 0.f, 0.f};

    const int sr = tid >> 1;
    const int sc = (tid & 1) * 32;

    for (int k0 = 0; k0 < K; k0 += BK) {
        {
            const float4* ga = reinterpret_cast<const float4*>(
                &A[(size_t)(bm + sr) * K + k0 + sc]);
            const float4* gb = reinterpret_cast<const float4*>(
                &Bt[(size_t)(bn + sr) * K + k0 + sc]);
            float4 va0 = ga[0], va1 = ga[1], va2 = ga[2], va3 = ga[3];
            float4 vb0 = gb[0], vb1 = gb[1], vb2 = gb[2], vb3 = gb[3];
            float4* da = reinterpret_cast<float4*>(&Asl[sr][sc]);
            float4* db = reinterpret_cast<float4*>(&Bsl[sr][sc]);
            da[0] = va0; da[1] = va1; da[2] = va2; da[3] = va3;
            db[0] = vb0; db[1] = vb1; db[2] = vb2; db[3] = vb3;
        }
        __syncthreads();

#pragma unroll
        for (int ks = 0; ks < 2; ++ks) {
            bf16x8 af[4], bf[4];
            const int kc = ks * 32 + (lane >> 4) * 8;
#pragma unroll
            for (int m = 0; m < 4; ++m)
                af[m] = *reinterpret_cast<const bf16x8*>(
                    &Asl[wr + m * 16 + (lane & 15)][kc]);
#pragma unroll
            for (int n = 0; n < 4; ++n)
                bf[n] = *reinterpret_cast<const bf16x8*>(
                    &Bsl[wc + n * 16 + (lane & 15)][kc]);
#pragma unroll
            for (int m = 0; m < 4; ++m)
#pragma unroll
                for (int n = 0; n < 4; ++n)
                    acc[m][n] = __builtin_amdgcn_mfma_f32_16x16x32_bf16(
                        af[m], bf[n], acc[m][n], 0, 0, 0);
        }
        __syncthreads();
    }

#pragma unroll
    for (int m = 0; m < 4; ++m)
#pragma unroll
        for (int n = 0; n < 4; ++n) {
            const int col = bn + wc + n * 16 + (lane & 15);
            const float bv = bias[col];
#pragma unroll
            for (int q = 0; q < 4; ++q) {
                const int row = bm + wr + m * 16 + (lane >> 4) * 4 + q;
                float v = acc[m][n][q] + bv;
                if (RELU) v = fmaxf(v, 0.f);
                if (OUT_BF16)
                    reinterpret_cast<unsigned short*>(Cv)[(size_t)row * N + col] = f2bf(v);
                else
                    reinterpret_cast<float*>(Cv)[(size_t)row * N + col] = v;
            }
        }
}

// ---------------------------------------------------------------------------
// small prep kernels
// ---------------------------------------------------------------------------
__global__ __launch_bounds__(256)
void transpose_bf16(const float* __restrict__ W, unsigned short* __restrict__ Wt,
                    int K, int N)
{
    int idx = blockIdx.x * 256 + threadIdx.x;
    if (idx >= K * N) return;
    int n = idx / K, k = idx % K;
    Wt[idx] = f2bf(W[(size_t)k * N + n]);
}

__global__ __launch_bounds__(256)
void transpose_split_f16(const float* __restrict__ W,
                         _Float16* __restrict__ Whi, _Float16* __restrict__ Wlo,
                         int K, int N)
{
    int idx = blockIdx.x * 256 + threadIdx.x;
    if (idx >= K * N) return;
    int n = idx / K, k = idx % K;
    _Float16 hi, lo; fsplit(W[(size_t)k * N + n], hi, lo);
    Whi[idx] = hi; Wlo[idx] = lo;
}

__global__ __launch_bounds__(256)
void split_flat_f16(const float* __restrict__ src,
                    _Float16* __restrict__ hi, _Float16* __restrict__ lo, int n)
{
    int i = blockIdx.x * 256 + threadIdx.x;
    if (i >= n) return;
    _Float16 h, l; fsplit(src[i], h, l);
    hi[i] = h; lo[i] = l;
}

// ---------------------------------------------------------------------------
extern "C" void kernel_launch(void* const* d_in, const int* in_sizes, int n_in,
                              void* d_out, int out_size, void* d_ws, size_t ws_size,
                              hipStream_t stream)
{
    const float* X  = (const float*)d_in[0];
    const float* W0 = (const float*)d_in[1];
    const float* b0 = (const float*)d_in[2];
    const float* W1 = (const float*)d_in[3];
    const float* b1 = (const float*)d_in[4];
    const float* W2 = (const float*)d_in[5];
    const float* b2 = (const float*)d_in[6];
    const float* CB = (const float*)d_in[7];
    const float* W3 = (const float*)d_in[8];
    const float* b3 = (const float*)d_in[9];
    const float* W4 = (const float*)d_in[10];
    const float* b4 = (const float*)d_in[11];
    const float* W5 = (const float*)d_in[12];
    const float* b5 = (const float*)d_in[13];

    const int D_in = 256, H = 512, R = 64, S = 512, NA = 8;
    const int Mtot = in_sizes[0] / D_in;          // 131072

    float* recon = (float*)d_out;
    float* ze    = recon + (size_t)(Mtot / NA) * S;
    float* remb  = ze + (size_t)Mtot * R;

    // ---- workspace: fixed weight planes ----
    char* p = (char*)d_ws;
    _Float16* W0hi = (_Float16*)p;  p += (size_t)H * D_in * 2;
    _Float16* W0lo = (_Float16*)p;  p += (size_t)H * D_in * 2;
    _Float16* W1hi = (_Float16*)p;  p += (size_t)H * H * 2;
    _Float16* W1lo = (_Float16*)p;  p += (size_t)H * H * 2;
    _Float16* W2thi = (_Float16*)p; p += (size_t)R * H * 2;        // [64][512]
    _Float16* W2tlo = (_Float16*)p; p += (size_t)R * H * 2;
    _Float16* CBhi = (_Float16*)p;  p += (size_t)256 * R * 2;      // [256][64]
    _Float16* CBlo = (_Float16*)p;  p += (size_t)256 * R * 2;
    unsigned short* W3t = (unsigned short*)p;  p += (size_t)H * R * 2;
    unsigned short* W4t = (unsigned short*)p;  p += (size_t)H * (NA * H) * 2;
    unsigned short* W5t = (unsigned short*)p;  p += (size_t)S * H * 2;
    size_t fixed = (size_t)(p - (char*)d_ws);
    fixed = (fixed + 255) & ~(size_t)255;

    // per-row chunk bytes: h0 pair 2048 + h1 pair 2048 + zqb 128
    int nc = 2;
    while (nc < 128) {
        size_t rpcT = (size_t)Mtot / nc;
        if (fixed + rpcT * 4224 + 1024 <= ws_size) break;
        nc *= 2;
    }
    const int rpc = Mtot / nc;
    char* q = (char*)d_ws + fixed;
    // h0hi/h0lo and h1hi/h1lo contiguous (split4 AF32=false uses Ahi + M*K)
    _Float16* h0hi = (_Float16*)q;                 q += (size_t)rpc * H * 2;
    _Float16* h0lo = (_Float16*)q;                 q += (size_t)rpc * H * 2;
    _Float16* h1hi = (_Float16*)q;                 q += (size_t)rpc * H * 2;
    _Float16* h1lo = (_Float16*)q;                 q += (size_t)rpc * H * 2;
    unsigned short* zqb = (unsigned short*)q;      q += (size_t)rpc * R * 2;
    unsigned short* rec1b = (unsigned short*)h0hi;     // alias (h0 dead after h1)
    unsigned short* rec2b = (unsigned short*)h1hi;     // alias (h1 dead after ze)

    // ---- one-time weight prep ----
    transpose_split_f16<<<(H * D_in + 255) / 256, 256, 0, stream>>>(W0, W0hi, W0lo, D_in, H);
    transpose_split_f16<<<(H * H + 255) / 256, 256, 0, stream>>>(W1, W1hi, W1lo, H, H);
    transpose_split_f16<<<(H * R + 255) / 256, 256, 0, stream>>>(W2, W2thi, W2tlo, H, R);
    split_flat_f16<<<(256 * R + 255) / 256, 256, 0, stream>>>(CB, CBhi, CBlo, 256 * R);
    transpose_bf16<<<(H * R + 255) / 256, 256, 0, stream>>>(W3, W3t, R, H);
    transpose_bf16<<<(H * NA * H + 255) / 256, 256, 0, stream>>>(W4, W4t, NA * H, H);
    transpose_bf16<<<(S * H + 255) / 256, 256, 0, stream>>>(W5, W5t, H, S);

    for (int r0 = 0; r0 < Mtot; r0 += rpc) {
        const int M6 = rpc / NA;
        // encoder: split-fp16 MFMA (+XCD swizzle)
        gemm_split4<256, true><<<dim3(H / 256, rpc / 128), 512, 0, stream>>>(
            X + (size_t)r0 * D_in, W0hi, W0lo, b0, h0hi, h0lo, rpc, H);
        gemm_split4<512, false><<<dim3(H / 256, rpc / 128), 512, 0, stream>>>(
            h0hi, W1hi, W1lo, b1, h1hi, h1lo, rpc, H);
        // z_e: split-fp16 MFMA, fp32 accum -> output zone 1
        gemm_ze_mfma<<<rpc / 128, 256, 0, stream>>>(
            h1hi, h1lo, W2thi, W2tlo, b2, ze + (size_t)r0 * R, rpc);
        // VQ via MFMA (fp32 filter + fp64 near-tie rescan) -> role_emb + zqb
        vq_mfma<<<rpc / 128, 512, 0, stream>>>(
            ze + (size_t)r0 * R, CB, CBhi, CBlo,
            remb + (size_t)r0 * R, zqb);
        // decoder: bf16 MFMA
        gemm_mfma_bt<true, true><<<dim3(H / 128, rpc / 128), 256, 0, stream>>>(
            zqb, W3t, b3, rec1b, rpc, H, R);
        gemm_mfma_bt<true, true><<<dim3(H / 128, M6 / 128), 256, 0, stream>>>(
            rec1b, W4t, b4, rec2b, M6, H, NA * H);
        gemm_mfma_bt<false, false><<<dim3(S / 128, M6 / 128), 256, 0, stream>>>(
            rec2b, W5t, b5, recon + (size_t)(r0 / NA) * S, M6, S, H);
    }
}

// Round 9
// 1450.769 us; speedup vs baseline: 1.2294x; 1.1183x over previous
//
#include <hip/hip_runtime.h>
#include <hip/hip_bf16.h>
#include <cstddef>

__device__ __forceinline__ unsigned short f2bf(float f) {
    union { float f; unsigned int u; } v; v.f = f;
    unsigned int r = (v.u + 0x7fffu + ((v.u >> 16) & 1u)) >> 16;   // RNE
    return (unsigned short)r;
}

typedef __bf16    bf16x8 __attribute__((ext_vector_type(8)));
typedef float     f32x4  __attribute__((ext_vector_type(4)));
typedef _Float16  f16x8  __attribute__((ext_vector_type(8)));

#define SPLIT_SCALE 2.44140625e-4f   // 2^-12

// fp32 -> fp16 (hi, lo*4096) split: hi + 2^-12*lo == v to ~2^-22 relative.
__device__ __forceinline__ void fsplit(float v, _Float16& hi, _Float16& lo) {
    hi = (_Float16)v;
    lo = (_Float16)((v - (float)hi) * 4096.0f);
}

// ---------------------------------------------------------------------------
// Split-fp16 MFMA GEMM (encoder): C = relu(A @ Bt^T + bias). 128x256 tile,
// 512 thr, B hi/lo double-buffered LDS, A direct from global, issue-early /
// write-late. + bijective XCD chunk swizzle (nwg%8==0).
// ---------------------------------------------------------------------------
template<int K, bool AF32>
__global__ __launch_bounds__(512, 2)
void gemm_split4(const void* __restrict__ Asrc,
                 const _Float16* __restrict__ Bhi, const _Float16* __restrict__ Blo,
                 const float* __restrict__ bias,
                 _Float16* __restrict__ Chi, _Float16* __restrict__ Clo,
                 int M, int N)
{
    constexpr int BK  = 32;
    constexpr int LDP = 40;
    constexpr int NS  = K / BK;

    __shared__ alignas(16) _Float16 Bh[2][256][LDP];
    __shared__ alignas(16) _Float16 Bl[2][256][LDP];

    const int tid  = threadIdx.x;
    const int lane = tid & 63;
    const int w    = tid >> 6;
    const int wr   = (w >> 2) * 64;
    const int wc   = (w & 3) * 64;

    int bx = blockIdx.x, by = blockIdx.y;
    {
        const int gx = gridDim.x, nwg = gx * gridDim.y;
        if ((nwg & 7) == 0) {
            int d = bx + by * gx;
            int L = (d & 7) * (nwg >> 3) + (d >> 3);
            bx = L % gx; by = L / gx;
        }
    }
    const int bm = by * 128;
    const int bn = bx * 256;

    f32x4 acc0[4][4], acc1[4][4];
#pragma unroll
    for (int m = 0; m < 4; ++m)
#pragma unroll
        for (int n = 0; n < 4; ++n) {
            acc0[m][n] = (f32x4){0.f, 0.f, 0.f, 0.f};
            acc1[m][n] = (f32x4){0.f, 0.f, 0.f, 0.f};
        }

    const int arow = bm + wr + (lane & 15);
    const int kgrp = (lane >> 4) * 8;
    const int brow = tid >> 1;
    const int bcol = (tid & 1) * 16;

    const _Float16* Ahi_ = (const _Float16*)Asrc;
    const float*    Af_  = (const float*)Asrc;

    f16x8 ah[4], al[4], ahn[4], aln[4];
    float4 rbh0, rbh1, rbl0, rbl1;

    auto loadB = [&](int k0) {
        const size_t gb = (size_t)(bn + brow) * K + k0 + bcol;
        rbh0 = *reinterpret_cast<const float4*>(Bhi + gb);
        rbh1 = *reinterpret_cast<const float4*>(Bhi + gb + 8);
        rbl0 = *reinterpret_cast<const float4*>(Blo + gb);
        rbl1 = *reinterpret_cast<const float4*>(Blo + gb + 8);
    };
    auto storeB = [&](int p) {
        *reinterpret_cast<float4*>(&Bh[p][brow][bcol])     = rbh0;
        *reinterpret_cast<float4*>(&Bh[p][brow][bcol + 8]) = rbh1;
        *reinterpret_cast<float4*>(&Bl[p][brow][bcol])     = rbl0;
        *reinterpret_cast<float4*>(&Bl[p][brow][bcol + 8]) = rbl1;
    };
    auto loadA = [&](int k0, f16x8* h, f16x8* l) {
#pragma unroll
        for (int m = 0; m < 4; ++m) {
            const size_t ga = (size_t)(arow + m * 16) * K + k0 + kgrp;
            if constexpr (AF32) {
                float4 v0 = *reinterpret_cast<const float4*>(Af_ + ga);
                float4 v1 = *reinterpret_cast<const float4*>(Af_ + ga + 4);
                float vv[8] = {v0.x, v0.y, v0.z, v0.w, v1.x, v1.y, v1.z, v1.w};
                f16x8 hh, ll;
#pragma unroll
                for (int j = 0; j < 8; ++j) {
                    _Float16 hi, lo; fsplit(vv[j], hi, lo);
                    hh[j] = hi; ll[j] = lo;
                }
                h[m] = hh; l[m] = ll;
            } else {
                h[m] = *reinterpret_cast<const f16x8*>(Ahi_ + ga);
                l[m] = *reinterpret_cast<const f16x8*>(Ahi_ + (size_t)M * K + ga);
            }
        }
    };

    loadB(0);
    loadA(0, ah, al);
    storeB(0);
    __syncthreads();

#pragma unroll
    for (int s = 0; s < NS; ++s) {
        const int p = s & 1;
        if (s + 1 < NS) {
            loadB((s + 1) * BK);
            loadA((s + 1) * BK, ahn, aln);
        }
#pragma unroll
        for (int n = 0; n < 4; ++n) {
            const f16x8 bh = *reinterpret_cast<const f16x8*>(
                &Bh[p][wc + n * 16 + (lane & 15)][kgrp]);
            const f16x8 bl = *reinterpret_cast<const f16x8*>(
                &Bl[p][wc + n * 16 + (lane & 15)][kgrp]);
#pragma unroll
            for (int m = 0; m < 4; ++m)
                acc0[m][n] = __builtin_amdgcn_mfma_f32_16x16x32_f16(
                    ah[m], bh, acc0[m][n], 0, 0, 0);
#pragma unroll
            for (int m = 0; m < 4; ++m)
                acc1[m][n] = __builtin_amdgcn_mfma_f32_16x16x32_f16(
                    ah[m], bl, acc1[m][n], 0, 0, 0);
#pragma unroll
            for (int m = 0; m < 4; ++m)
                acc1[m][n] = __builtin_amdgcn_mfma_f32_16x16x32_f16(
                    al[m], bh, acc1[m][n], 0, 0, 0);
        }
        if (s + 1 < NS) {
            storeB(p ^ 1);
#pragma unroll
            for (int m = 0; m < 4; ++m) { ah[m] = ahn[m]; al[m] = aln[m]; }
        }
        __syncthreads();
    }

#pragma unroll
    for (int m = 0; m < 4; ++m)
#pragma unroll
        for (int n = 0; n < 4; ++n) {
            const int col = bn + wc + n * 16 + (lane & 15);
            const float bv = bias[col];
#pragma unroll
            for (int q = 0; q < 4; ++q) {
                const int row = bm + wr + m * 16 + (lane >> 4) * 4 + q;
                float v = acc0[m][n][q] + SPLIT_SCALE * acc1[m][n][q] + bv;
                v = fmaxf(v, 0.f);
                _Float16 hi, lo; fsplit(v, hi, lo);
                Chi[(size_t)row * N + col] = hi;
                Clo[(size_t)row * N + col] = lo;
            }
        }
}

// ---------------------------------------------------------------------------
// z_e GEMM via split-fp16 MFMA: ze[M,64] = h1 @ W2 + b2, fp32 accumulation.
// ---------------------------------------------------------------------------
__global__ __launch_bounds__(256)
void gemm_ze_mfma(const _Float16* __restrict__ Ahi, const _Float16* __restrict__ Alo,
                  const _Float16* __restrict__ Bhi, const _Float16* __restrict__ Blo,
                  const float* __restrict__ bias, float* __restrict__ C, int M)
{
    constexpr int K = 512, N = 64;
    const int tid  = threadIdx.x;
    const int lane = tid & 63;
    const int w    = tid >> 6;
    const int wr   = (w >> 1) * 64;
    const int wc   = (w & 1) * 32;
    const int bm   = blockIdx.x * 128;

    f32x4 acc0[4][2], acc1[4][2];
#pragma unroll
    for (int m = 0; m < 4; ++m)
#pragma unroll
        for (int n = 0; n < 2; ++n) {
            acc0[m][n] = (f32x4){0.f, 0.f, 0.f, 0.f};
            acc1[m][n] = (f32x4){0.f, 0.f, 0.f, 0.f};
        }

    const int arow = bm + wr + (lane & 15);
    const int kgrp = (lane >> 4) * 8;

#pragma unroll
    for (int ks = 0; ks < K / 32; ++ks) {
        const int k0 = ks * 32 + kgrp;
        f16x8 ah[4], al[4];
#pragma unroll
        for (int m = 0; m < 4; ++m) {
            const size_t ga = (size_t)(arow + m * 16) * K + k0;
            ah[m] = *reinterpret_cast<const f16x8*>(Ahi + ga);
            al[m] = *reinterpret_cast<const f16x8*>(Alo + ga);
        }
#pragma unroll
        for (int n = 0; n < 2; ++n) {
            const size_t gb = (size_t)(wc + n * 16 + (lane & 15)) * K + k0;
            const f16x8 bh = *reinterpret_cast<const f16x8*>(Bhi + gb);
            const f16x8 bl = *reinterpret_cast<const f16x8*>(Blo + gb);
#pragma unroll
            for (int m = 0; m < 4; ++m)
                acc0[m][n] = __builtin_amdgcn_mfma_f32_16x16x32_f16(
                    ah[m], bh, acc0[m][n], 0, 0, 0);
#pragma unroll
            for (int m = 0; m < 4; ++m)
                acc1[m][n] = __builtin_amdgcn_mfma_f32_16x16x32_f16(
                    ah[m], bl, acc1[m][n], 0, 0, 0);
#pragma unroll
            for (int m = 0; m < 4; ++m)
                acc1[m][n] = __builtin_amdgcn_mfma_f32_16x16x32_f16(
                    al[m], bh, acc1[m][n], 0, 0, 0);
        }
    }

#pragma unroll
    for (int m = 0; m < 4; ++m)
#pragma unroll
        for (int n = 0; n < 2; ++n) {
            const int col = wc + n * 16 + (lane & 15);
            const float bv = bias[col];
#pragma unroll
            for (int q = 0; q < 4; ++q) {
                const int row = bm + wr + m * 16 + (lane >> 4) * 4 + q;
                C[(size_t)row * N + col] = acc0[m][n][q] + SPLIT_SCALE * acc1[m][n][q] + bv;
            }
        }
}

// ---------------------------------------------------------------------------
// VQ via MFMA: 128 rows x 256 entries split-fp16 GEMM -> fp32 d2 filter ->
// argmin reduce -> near-tie rows rescanned EXACTLY (fp64, first-min) by one
// WAVE per flagged row: lane l handles entries {l, l+64, l+128, l+192} (ILP-4
// chains, no per-thread fp64 arrays -> no scratch), lexicographic shfl reduce.
// ---------------------------------------------------------------------------
#define VQ_EPS 1e-3f
__global__ __launch_bounds__(512)
void vq_mfma(const float* __restrict__ Z, const float* __restrict__ CB,
             const _Float16* __restrict__ Chi, const _Float16* __restrict__ Clo,
             float* __restrict__ OUT, unsigned short* __restrict__ ZQB)
{
    __shared__ float  ccf[256];
    __shared__ double ccd[256];
    __shared__ float  xxf[128];
    __shared__ double xxd[128];
    __shared__ float  redv[4][128];
    __shared__ int    redi[4][128];
    __shared__ float  bv1s[128];
    __shared__ int    bis[128];
    __shared__ int    flags[128];
    __shared__ int    flaglist[128];
    __shared__ int    nflag;

    const int tid  = threadIdx.x;
    const int lane = tid & 63;
    const int w    = tid >> 6;
    const int wr   = (w >> 2) * 64;              // 2 M-waves
    const int wc   = (w & 3) * 64;               // 4 N-waves
    const int bm   = blockIdx.x * 128;

    // ---- phase A: stats ----
    if (tid == 0) nflag = 0;
    if (tid < 256) {
        const float4* c4 = reinterpret_cast<const float4*>(CB + (size_t)tid * 64);
        double cc = 0.0;
#pragma unroll
        for (int v = 0; v < 16; ++v) {
            float4 f = c4[v];
            cc = fma((double)f.x, (double)f.x, cc);
            cc = fma((double)f.y, (double)f.y, cc);
            cc = fma((double)f.z, (double)f.z, cc);
            cc = fma((double)f.w, (double)f.w, cc);
        }
        ccd[tid] = cc; ccf[tid] = (float)cc;
    }
    if (tid < 128) {
        const float4* z4 = reinterpret_cast<const float4*>(Z + (size_t)(bm + tid) * 64);
        double xx = 0.0;
#pragma unroll
        for (int v = 0; v < 16; ++v) {
            float4 f = z4[v];
            xx = fma((double)f.x, (double)f.x, xx);
            xx = fma((double)f.y, (double)f.y, xx);
            xx = fma((double)f.z, (double)f.z, xx);
            xx = fma((double)f.w, (double)f.w, xx);
        }
        xxd[tid] = xx; xxf[tid] = (float)xx;
        flags[tid] = 0;
    }
    __syncthreads();

    // ---- phase B: split-fp16 MFMA dot products ----
    f32x4 acc0[4][4], acc1[4][4];
#pragma unroll
    for (int m = 0; m < 4; ++m)
#pragma unroll
        for (int n = 0; n < 4; ++n) {
            acc0[m][n] = (f32x4){0.f, 0.f, 0.f, 0.f};
            acc1[m][n] = (f32x4){0.f, 0.f, 0.f, 0.f};
        }

    const int arow = bm + wr + (lane & 15);
    const int kgrp = (lane >> 4) * 8;

#pragma unroll
    for (int ks = 0; ks < 2; ++ks) {
        const int k0 = ks * 32 + kgrp;
        f16x8 ah[4], al[4];
#pragma unroll
        for (int m = 0; m < 4; ++m) {
            const float* src = Z + (size_t)(arow + m * 16) * 64 + k0;
            float4 v0 = *reinterpret_cast<const float4*>(src);
            float4 v1 = *reinterpret_cast<const float4*>(src + 4);
            float vv[8] = {v0.x, v0.y, v0.z, v0.w, v1.x, v1.y, v1.z, v1.w};
            f16x8 hh, ll;
#pragma unroll
            for (int j = 0; j < 8; ++j) {
                _Float16 hi, lo; fsplit(vv[j], hi, lo);
                hh[j] = hi; ll[j] = lo;
            }
            ah[m] = hh; al[m] = ll;
        }
#pragma unroll
        for (int n = 0; n < 4; ++n) {
            const size_t gb = (size_t)(wc + n * 16 + (lane & 15)) * 64 + k0;
            const f16x8 bh = *reinterpret_cast<const f16x8*>(Chi + gb);
            const f16x8 bl = *reinterpret_cast<const f16x8*>(Clo + gb);
#pragma unroll
            for (int m = 0; m < 4; ++m)
                acc0[m][n] = __builtin_amdgcn_mfma_f32_16x16x32_f16(
                    ah[m], bh, acc0[m][n], 0, 0, 0);
#pragma unroll
            for (int m = 0; m < 4; ++m)
                acc1[m][n] = __builtin_amdgcn_mfma_f32_16x16x32_f16(
                    ah[m], bl, acc1[m][n], 0, 0, 0);
#pragma unroll
            for (int m = 0; m < 4; ++m)
                acc1[m][n] = __builtin_amdgcn_mfma_f32_16x16x32_f16(
                    al[m], bh, acc1[m][n], 0, 0, 0);
        }
    }

    // fold into d2f (store in acc0): d2 = xx - 2*dot + cc
#pragma unroll
    for (int m = 0; m < 4; ++m)
#pragma unroll
        for (int n = 0; n < 4; ++n) {
            const int col = wc + n * 16 + (lane & 15);
            const float cf = ccf[col];
#pragma unroll
            for (int q = 0; q < 4; ++q) {
                const int rl = wr + m * 16 + (lane >> 4) * 4 + q;
                float dot = acc0[m][n][q] + SPLIT_SCALE * acc1[m][n][q];
                acc0[m][n][q] = (xxf[rl] - 2.0f * dot) + cf;
            }
        }

    // ---- phase C: argmin reduction (first-min) ----
    float bvr[4][4]; int bir[4][4];
#pragma unroll
    for (int m = 0; m < 4; ++m)
#pragma unroll
        for (int q = 0; q < 4; ++q) {
            float bv = 3.4e38f; int bi = 0;
#pragma unroll
            for (int n = 0; n < 4; ++n) {
                const int col = wc + n * 16 + (lane & 15);
                const float v = acc0[m][n][q];
                if (v < bv || (v == bv && col < bi)) { bv = v; bi = col; }
            }
            bvr[m][q] = bv; bir[m][q] = bi;
        }
#pragma unroll
    for (int mask = 1; mask < 16; mask <<= 1) {
#pragma unroll
        for (int m = 0; m < 4; ++m)
#pragma unroll
            for (int q = 0; q < 4; ++q) {
                float ov = __shfl_xor(bvr[m][q], mask);
                int   oi = __shfl_xor(bir[m][q], mask);
                if (ov < bvr[m][q] || (ov == bvr[m][q] && oi < bir[m][q])) {
                    bvr[m][q] = ov; bir[m][q] = oi;
                }
            }
    }
    if ((lane & 15) == 0) {
#pragma unroll
        for (int m = 0; m < 4; ++m)
#pragma unroll
            for (int q = 0; q < 4; ++q) {
                const int rl = wr + m * 16 + (lane >> 4) * 4 + q;
                redv[w & 3][rl] = bvr[m][q];
                redi[w & 3][rl] = bir[m][q];
            }
    }
    __syncthreads();

    if (tid < 128) {
        float bv = 3.4e38f; int bi = 0;
#pragma unroll
        for (int nw = 0; nw < 4; ++nw) {        // ascending entry ranges
            float v = redv[nw][tid];
            if (v < bv) { bv = v; bi = redi[nw][tid]; }
        }
        bv1s[tid] = bv; bis[tid] = bi;
    }
    __syncthreads();

    // ---- phase D: near-tie detection ----
#pragma unroll
    for (int m = 0; m < 4; ++m)
#pragma unroll
        for (int q = 0; q < 4; ++q) {
            const int rl = wr + m * 16 + (lane >> 4) * 4 + q;
            const float thr = bv1s[rl] + VQ_EPS;
            const int   win = bis[rl];
#pragma unroll
            for (int n = 0; n < 4; ++n) {
                const int col = wc + n * 16 + (lane & 15);
                if (acc0[m][n][q] <= thr && col != win) flags[rl] = 1;
            }
        }
    __syncthreads();

    // compact flagged rows
    if (tid < 128 && flags[tid]) {
        int s = atomicAdd(&nflag, 1);
        flaglist[s] = tid;
    }
    __syncthreads();

    // ---- phase E: exact rescan, one WAVE per flagged row ----
    for (int fi = w; fi < nflag; fi += 8) {
        const int rl = flaglist[fi];
        const float* zr = Z + (size_t)(bm + rl) * 64;
        const double xx = xxd[rl];
        double best = 1.0e300; int bi = 256;
#pragma unroll
        for (int j = 0; j < 4; ++j) {
            const int e = lane + j * 64;
            const float* c = CB + (size_t)e * 64;
            double dot = 0.0;
#pragma unroll
            for (int d = 0; d < 64; ++d)
                dot = fma((double)zr[d], (double)c[d], dot);
            double d2x = (xx - 2.0 * dot) + ccd[e];
            if (d2x < best || (d2x == best && e < bi)) { best = d2x; bi = e; }
        }
#pragma unroll
        for (int mask = 1; mask < 64; mask <<= 1) {
            double ov = __shfl_xor(best, mask);
            int    oi = __shfl_xor(bi, mask);
            if (ov < best || (ov == best && oi < bi)) { best = ov; bi = oi; }
        }
        if (lane == 0) bis[rl] = bi;
    }
    __syncthreads();

    // ---- phase F: gather ----
    {
        const int row  = tid >> 2;
        const int part = tid & 3;
        const int bi   = bis[row];
        const float4* src = reinterpret_cast<const float4*>(CB + (size_t)bi * 64) + part * 4;
        float* dst = OUT + (size_t)(bm + row) * 64 + part * 16;
        unsigned short* dq = ZQB + (size_t)(bm + row) * 64 + part * 16;
#pragma unroll
        for (int v = 0; v < 4; ++v) {
            float4 f = src[v];
            *reinterpret_cast<float4*>(dst + v * 4) = f;
            ushort4 qb = { f2bf(f.x), f2bf(f.y), f2bf(f.z), f2bf(f.w) };
            *reinterpret_cast<ushort4*>(dq + v * 4) = qb;
        }
    }
}

// ---------------------------------------------------------------------------
// bf16 MFMA GEMM (decoder) -- single-buffered (round-5 known-good).
// ---------------------------------------------------------------------------
template<bool RELU, bool OUT_BF16>
__global__ __launch_bounds__(256)
void gemm_mfma_bt(const unsigned short* __restrict__ A,
                  const unsigned short* __restrict__ Bt,
                  const float* __restrict__ bias,
                  void* __restrict__ Cv, int M, int N, int K)
{
    constexpr int BK  = 64;
    constexpr int LDP = BK + 8;

    __shared__ alignas(16) unsigned short Asl[128][LDP];
    __shared__ alignas(16) unsigned short Bsl[128][LDP];

    const int tid  = threadIdx.x;
    const int lane = tid & 63;
    const int w    = tid >> 6;
    const int wr   = (w >> 1) * 64;
    const int wc   = (w & 1) * 64;
    const int bm   = blockIdx.y * 128;
    const int bn   = blockIdx.x * 128;

    f32x4 acc[4][4];
#pragma unroll
    for (int m = 0; m < 4; ++m)
#pragma unroll
        for (int n = 0; n < 4; ++n) acc[m][n] = (f32x4){0.f, 0.f, 0.f, 0.f};

    const int sr = tid >> 1;
    const int sc = (tid & 1) * 32;

    for (int k0 = 0; k0 < K; k0 += BK) {
        {
            const float4* ga = reinterpret_cast<const float4*>(
                &A[(size_t)(bm + sr) * K + k0 + sc]);
            const float4* gb = reinterpret_cast<const float4*>(
                &Bt[(size_t)(bn + sr) * K + k0 + sc]);
            float4 va0 = ga[0], va1 = ga[1], va2 = ga[2], va3 = ga[3];
            float4 vb0 = gb[0], vb1 = gb[1], vb2 = gb[2], vb3 = gb[3];
            float4* da = reinterpret_cast<float4*>(&Asl[sr][sc]);
            float4* db = reinterpret_cast<float4*>(&Bsl[sr][sc]);
            da[0] = va0; da[1] = va1; da[2] = va2; da[3] = va3;
            db[0] = vb0; db[1] = vb1; db[2] = vb2; db[3] = vb3;
        }
        __syncthreads();

#pragma unroll
        for (int ks = 0; ks < 2; ++ks) {
            bf16x8 af[4], bf[4];
            const int kc = ks * 32 + (lane >> 4) * 8;
#pragma unroll
            for (int m = 0; m < 4; ++m)
                af[m] = *reinterpret_cast<const bf16x8*>(
                    &Asl[wr + m * 16 + (lane & 15)][kc]);
#pragma unroll
            for (int n = 0; n < 4; ++n)
                bf[n] = *reinterpret_cast<const bf16x8*>(
                    &Bsl[wc + n * 16 + (lane & 15)][kc]);
#pragma unroll
            for (int m = 0; m < 4; ++m)
#pragma unroll
                for (int n = 0; n < 4; ++n)
                    acc[m][n] = __builtin_amdgcn_mfma_f32_16x16x32_bf16(
                        af[m], bf[n], acc[m][n], 0, 0, 0);
        }
        __syncthreads();
    }

#pragma unroll
    for (int m = 0; m < 4; ++m)
#pragma unroll
        for (int n = 0; n < 4; ++n) {
            const int col = bn + wc + n * 16 + (lane & 15);
            const float bv = bias[col];
#pragma unroll
            for (int q = 0; q < 4; ++q) {
                const int row = bm + wr + m * 16 + (lane >> 4) * 4 + q;
                float v = acc[m][n][q] + bv;
                if (RELU) v = fmaxf(v, 0.f);
                if (OUT_BF16)
                    reinterpret_cast<unsigned short*>(Cv)[(size_t)row * N + col] = f2bf(v);
                else
                    reinterpret_cast<float*>(Cv)[(size_t)row * N + col] = v;
            }
        }
}

// ---------------------------------------------------------------------------
// small prep kernels
// ---------------------------------------------------------------------------
__global__ __launch_bounds__(256)
void transpose_bf16(const float* __restrict__ W, unsigned short* __restrict__ Wt,
                    int K, int N)
{
    int idx = blockIdx.x * 256 + threadIdx.x;
    if (idx >= K * N) return;
    int n = idx / K, k = idx % K;
    Wt[idx] = f2bf(W[(size_t)k * N + n]);
}

__global__ __launch_bounds__(256)
void transpose_split_f16(const float* __restrict__ W,
                         _Float16* __restrict__ Whi, _Float16* __restrict__ Wlo,
                         int K, int N)
{
    int idx = blockIdx.x * 256 + threadIdx.x;
    if (idx >= K * N) return;
    int n = idx / K, k = idx % K;
    _Float16 hi, lo; fsplit(W[(size_t)k * N + n], hi, lo);
    Whi[idx] = hi; Wlo[idx] = lo;
}

__global__ __launch_bounds__(256)
void split_flat_f16(const float* __restrict__ src,
                    _Float16* __restrict__ hi, _Float16* __restrict__ lo, int n)
{
    int i = blockIdx.x * 256 + threadIdx.x;
    if (i >= n) return;
    _Float16 h, l; fsplit(src[i], h, l);
    hi[i] = h; lo[i] = l;
}

// ---------------------------------------------------------------------------
extern "C" void kernel_launch(void* const* d_in, const int* in_sizes, int n_in,
                              void* d_out, int out_size, void* d_ws, size_t ws_size,
                              hipStream_t stream)
{
    const float* X  = (const float*)d_in[0];
    const float* W0 = (const float*)d_in[1];
    const float* b0 = (const float*)d_in[2];
    const float* W1 = (const float*)d_in[3];
    const float* b1 = (const float*)d_in[4];
    const float* W2 = (const float*)d_in[5];
    const float* b2 = (const float*)d_in[6];
    const float* CB = (const float*)d_in[7];
    const float* W3 = (const float*)d_in[8];
    const float* b3 = (const float*)d_in[9];
    const float* W4 = (const float*)d_in[10];
    const float* b4 = (const float*)d_in[11];
    const float* W5 = (const float*)d_in[12];
    const float* b5 = (const float*)d_in[13];

    const int D_in = 256, H = 512, R = 64, S = 512, NA = 8;
    const int Mtot = in_sizes[0] / D_in;          // 131072

    float* recon = (float*)d_out;
    float* ze    = recon + (size_t)(Mtot / NA) * S;
    float* remb  = ze + (size_t)Mtot * R;

    // ---- workspace: fixed weight planes ----
    char* p = (char*)d_ws;
    _Float16* W0hi = (_Float16*)p;  p += (size_t)H * D_in * 2;
    _Float16* W0lo = (_Float16*)p;  p += (size_t)H * D_in * 2;
    _Float16* W1hi = (_Float16*)p;  p += (size_t)H * H * 2;
    _Float16* W1lo = (_Float16*)p;  p += (size_t)H * H * 2;
    _Float16* W2thi = (_Float16*)p; p += (size_t)R * H * 2;        // [64][512]
    _Float16* W2tlo = (_Float16*)p; p += (size_t)R * H * 2;
    _Float16* CBhi = (_Float16*)p;  p += (size_t)256 * R * 2;      // [256][64]
    _Float16* CBlo = (_Float16*)p;  p += (size_t)256 * R * 2;
    unsigned short* W3t = (unsigned short*)p;  p += (size_t)H * R * 2;
    unsigned short* W4t = (unsigned short*)p;  p += (size_t)H * (NA * H) * 2;
    unsigned short* W5t = (unsigned short*)p;  p += (size_t)S * H * 2;
    size_t fixed = (size_t)(p - (char*)d_ws);
    fixed = (fixed + 255) & ~(size_t)255;

    // per-row chunk bytes: h0 pair 2048 + h1 pair 2048 + zqb 128
    int nc = 2;
    while (nc < 128) {
        size_t rpcT = (size_t)Mtot / nc;
        if (fixed + rpcT * 4224 + 1024 <= ws_size) break;
        nc *= 2;
    }
    const int rpc = Mtot / nc;
    char* q = (char*)d_ws + fixed;
    // h0hi/h0lo and h1hi/h1lo contiguous (split4 AF32=false uses Ahi + M*K)
    _Float16* h0hi = (_Float16*)q;                 q += (size_t)rpc * H * 2;
    _Float16* h0lo = (_Float16*)q;                 q += (size_t)rpc * H * 2;
    _Float16* h1hi = (_Float16*)q;                 q += (size_t)rpc * H * 2;
    _Float16* h1lo = (_Float16*)q;                 q += (size_t)rpc * H * 2;
    unsigned short* zqb = (unsigned short*)q;      q += (size_t)rpc * R * 2;
    unsigned short* rec1b = (unsigned short*)h0hi;     // alias (h0 dead after h1)
    unsigned short* rec2b = (unsigned short*)h1hi;     // alias (h1 dead after ze)

    // ---- one-time weight prep ----
    transpose_split_f16<<<(H * D_in + 255) / 256, 256, 0, stream>>>(W0, W0hi, W0lo, D_in, H);
    transpose_split_f16<<<(H * H + 255) / 256, 256, 0, stream>>>(W1, W1hi, W1lo, H, H);
    transpose_split_f16<<<(H * R + 255) / 256, 256, 0, stream>>>(W2, W2thi, W2tlo, H, R);
    split_flat_f16<<<(256 * R + 255) / 256, 256, 0, stream>>>(CB, CBhi, CBlo, 256 * R);
    transpose_bf16<<<(H * R + 255) / 256, 256, 0, stream>>>(W3, W3t, R, H);
    transpose_bf16<<<(H * NA * H + 255) / 256, 256, 0, stream>>>(W4, W4t, NA * H, H);
    transpose_bf16<<<(S * H + 255) / 256, 256, 0, stream>>>(W5, W5t, H, S);

    for (int r0 = 0; r0 < Mtot; r0 += rpc) {
        const int M6 = rpc / NA;
        // encoder: split-fp16 MFMA (+XCD swizzle)
        gemm_split4<256, true><<<dim3(H / 256, rpc / 128), 512, 0, stream>>>(
            X + (size_t)r0 * D_in, W0hi, W0lo, b0, h0hi, h0lo, rpc, H);
        gemm_split4<512, false><<<dim3(H / 256, rpc / 128), 512, 0, stream>>>(
            h0hi, W1hi, W1lo, b1, h1hi, h1lo, rpc, H);
        // z_e: split-fp16 MFMA, fp32 accum -> output zone 1
        gemm_ze_mfma<<<rpc / 128, 256, 0, stream>>>(
            h1hi, h1lo, W2thi, W2tlo, b2, ze + (size_t)r0 * R, rpc);
        // VQ via MFMA (fp32 filter + wave-parallel fp64 near-tie rescan)
        vq_mfma<<<rpc / 128, 512, 0, stream>>>(
            ze + (size_t)r0 * R, CB, CBhi, CBlo,
            remb + (size_t)r0 * R, zqb);
        // decoder: bf16 MFMA
        gemm_mfma_bt<true, true><<<dim3(H / 128, rpc / 128), 256, 0, stream>>>(
            zqb, W3t, b3, rec1b, rpc, H, R);
        gemm_mfma_bt<true, true><<<dim3(H / 128, M6 / 128), 256, 0, stream>>>(
            rec1b, W4t, b4, rec2b, M6, H, NA * H);
        gemm_mfma_bt<false, false><<<dim3(S / 128, M6 / 128), 256, 0, stream>>>(
            rec2b, W5t, b5, recon + (size_t)(r0 / NA) * S, M6, S, H);
    }
}

// Round 10
// 1283.942 us; speedup vs baseline: 1.3892x; 1.1299x over previous
//
#include <hip/hip_runtime.h>
#include <hip/hip_bf16.h>
#include <cstddef>

__device__ __forceinline__ unsigned short f2bf(float f) {
    union { float f; unsigned int u; } v; v.f = f;
    unsigned int r = (v.u + 0x7fffu + ((v.u >> 16) & 1u)) >> 16;   // RNE
    return (unsigned short)r;
}

typedef __bf16    bf16x8 __attribute__((ext_vector_type(8)));
typedef float     f32x4  __attribute__((ext_vector_type(4)));
typedef _Float16  f16x8  __attribute__((ext_vector_type(8)));

#define SPLIT_SCALE 2.44140625e-4f   // 2^-12

// fp32 -> fp16 (hi, lo*4096) split: hi + 2^-12*lo == v to ~2^-22 relative.
__device__ __forceinline__ void fsplit(float v, _Float16& hi, _Float16& lo) {
    hi = (_Float16)v;
    lo = (_Float16)((v - (float)hi) * 4096.0f);
}

// ---------------------------------------------------------------------------
// Split-fp16 MFMA GEMM v5 (encoder): C = relu(A @ Bt^T + bias).
// Register-lean occupancy redesign: 128x64 block tile, 256 thr, wave tile
// 32x64 (wr = w*32; B panel shared by all 4 waves -> LDS broadcast reads).
// acc = 64 VGPR, A-frag dbuf = 32 -> ~125 total -> 4 waves/SIMD (2x the 64x64
// variant whose 128-reg accumulators capped at 2/SIMD). LDS 20 KB -> 4
// blocks/CU resident; grid (N/64, M/128) = 4096 blocks so barrier stalls
// interleave across blocks. B hi/lo double-buffered; A direct from global
// (issue-early / write-late). + bijective XCD chunk swizzle.
// ---------------------------------------------------------------------------
template<int K, bool AF32>
__global__ __launch_bounds__(256, AF32 ? 3 : 4)
void gemm_split5(const void* __restrict__ Asrc,
                 const _Float16* __restrict__ Bhi, const _Float16* __restrict__ Blo,
                 const float* __restrict__ bias,
                 _Float16* __restrict__ Chi, _Float16* __restrict__ Clo,
                 int M, int N)
{
    constexpr int BK  = 32;
    constexpr int LDP = 40;                      // 80B row stride
    constexpr int NS  = K / BK;

    __shared__ alignas(16) _Float16 Bh[2][64][LDP];   // 10240 B
    __shared__ alignas(16) _Float16 Bl[2][64][LDP];   // 10240 B

    const int tid  = threadIdx.x;
    const int lane = tid & 63;
    const int w    = tid >> 6;                   // 0..3

    int bx = blockIdx.x, by = blockIdx.y;
    {
        const int gx = gridDim.x, nwg = gx * gridDim.y;
        if ((nwg & 7) == 0) {
            int d = bx + by * gx;
            int L = (d & 7) * (nwg >> 3) + (d >> 3);
            bx = L % gx; by = L / gx;
        }
    }
    const int bm = by * 128;
    const int bn = bx * 64;

    f32x4 acc0[2][4], acc1[2][4];
#pragma unroll
    for (int m = 0; m < 2; ++m)
#pragma unroll
        for (int n = 0; n < 4; ++n) {
            acc0[m][n] = (f32x4){0.f, 0.f, 0.f, 0.f};
            acc1[m][n] = (f32x4){0.f, 0.f, 0.f, 0.f};
        }

    const int arow = bm + w * 32 + (lane & 15);  // A-frag row (m=0)
    const int kgrp = (lane >> 4) * 8;            // k sub-offset
    const int brow = tid >> 2;                   // B staging: 4 thr/row (0..63)
    const int bcol = (tid & 3) * 8;              // 8 f16 (16B) each

    const _Float16* Ahi_ = (const _Float16*)Asrc;
    const float*    Af_  = (const float*)Asrc;

    f16x8 ah[2], al[2], ahn[2], aln[2];
    float4 rbh, rbl;

    auto loadB = [&](int k0) {
        const size_t gb = (size_t)(bn + brow) * K + k0 + bcol;
        rbh = *reinterpret_cast<const float4*>(Bhi + gb);
        rbl = *reinterpret_cast<const float4*>(Blo + gb);
    };
    auto storeB = [&](int p) {
        *reinterpret_cast<float4*>(&Bh[p][brow][bcol]) = rbh;
        *reinterpret_cast<float4*>(&Bl[p][brow][bcol]) = rbl;
    };
    auto loadA = [&](int k0, f16x8* h, f16x8* l) {
#pragma unroll
        for (int m = 0; m < 2; ++m) {
            const size_t ga = (size_t)(arow + m * 16) * K + k0 + kgrp;
            if constexpr (AF32) {
                float4 v0 = *reinterpret_cast<const float4*>(Af_ + ga);
                float4 v1 = *reinterpret_cast<const float4*>(Af_ + ga + 4);
                float vv[8] = {v0.x, v0.y, v0.z, v0.w, v1.x, v1.y, v1.z, v1.w};
                f16x8 hh, ll;
#pragma unroll
                for (int j = 0; j < 8; ++j) {
                    _Float16 hi, lo; fsplit(vv[j], hi, lo);
                    hh[j] = hi; ll[j] = lo;
                }
                h[m] = hh; l[m] = ll;
            } else {
                h[m] = *reinterpret_cast<const f16x8*>(Ahi_ + ga);
                l[m] = *reinterpret_cast<const f16x8*>(Ahi_ + (size_t)M * K + ga);
            }
        }
    };

    loadB(0);
    loadA(0, ah, al);
    storeB(0);
    __syncthreads();

#pragma unroll
    for (int s = 0; s < NS; ++s) {
        const int p = s & 1;
        if (s + 1 < NS) {                        // issue next-tile loads EARLY
            loadB((s + 1) * BK);
            loadA((s + 1) * BK, ahn, aln);
        }
#pragma unroll
        for (int n = 0; n < 4; ++n) {
            const f16x8 bh = *reinterpret_cast<const f16x8*>(
                &Bh[p][n * 16 + (lane & 15)][kgrp]);
            const f16x8 bl = *reinterpret_cast<const f16x8*>(
                &Bl[p][n * 16 + (lane & 15)][kgrp]);
#pragma unroll
            for (int m = 0; m < 2; ++m)
                acc0[m][n] = __builtin_amdgcn_mfma_f32_16x16x32_f16(
                    ah[m], bh, acc0[m][n], 0, 0, 0);
#pragma unroll
            for (int m = 0; m < 2; ++m)
                acc1[m][n] = __builtin_amdgcn_mfma_f32_16x16x32_f16(
                    ah[m], bl, acc1[m][n], 0, 0, 0);
#pragma unroll
            for (int m = 0; m < 2; ++m)
                acc1[m][n] = __builtin_amdgcn_mfma_f32_16x16x32_f16(
                    al[m], bh, acc1[m][n], 0, 0, 0);
        }
        if (s + 1 < NS) {                        // write-late into other buffer
            storeB(p ^ 1);
#pragma unroll
            for (int m = 0; m < 2; ++m) { ah[m] = ahn[m]; al[m] = aln[m]; }
        }
        __syncthreads();
    }

    // epilogue: combine, bias, relu, write fp16 pair planes
#pragma unroll
    for (int m = 0; m < 2; ++m)
#pragma unroll
        for (int n = 0; n < 4; ++n) {
            const int col = bn + n * 16 + (lane & 15);
            const float bv = bias[col];
#pragma unroll
            for (int q = 0; q < 4; ++q) {
                const int row = bm + w * 32 + m * 16 + (lane >> 4) * 4 + q;
                float v = acc0[m][n][q] + SPLIT_SCALE * acc1[m][n][q] + bv;
                v = fmaxf(v, 0.f);
                _Float16 hi, lo; fsplit(v, hi, lo);
                Chi[(size_t)row * N + col] = hi;
                Clo[(size_t)row * N + col] = lo;
            }
        }
}

// ---------------------------------------------------------------------------
// z_e GEMM via split-fp16 MFMA: ze[M,64] = h1 @ W2 + b2, fp32 accumulation.
// ---------------------------------------------------------------------------
__global__ __launch_bounds__(256)
void gemm_ze_mfma(const _Float16* __restrict__ Ahi, const _Float16* __restrict__ Alo,
                  const _Float16* __restrict__ Bhi, const _Float16* __restrict__ Blo,
                  const float* __restrict__ bias, float* __restrict__ C, int M)
{
    constexpr int K = 512, N = 64;
    const int tid  = threadIdx.x;
    const int lane = tid & 63;
    const int w    = tid >> 6;
    const int wr   = (w >> 1) * 64;
    const int wc   = (w & 1) * 32;
    const int bm   = blockIdx.x * 128;

    f32x4 acc0[4][2], acc1[4][2];
#pragma unroll
    for (int m = 0; m < 4; ++m)
#pragma unroll
        for (int n = 0; n < 2; ++n) {
            acc0[m][n] = (f32x4){0.f, 0.f, 0.f, 0.f};
            acc1[m][n] = (f32x4){0.f, 0.f, 0.f, 0.f};
        }

    const int arow = bm + wr + (lane & 15);
    const int kgrp = (lane >> 4) * 8;

#pragma unroll
    for (int ks = 0; ks < K / 32; ++ks) {
        const int k0 = ks * 32 + kgrp;
        f16x8 ah[4], al[4];
#pragma unroll
        for (int m = 0; m < 4; ++m) {
            const size_t ga = (size_t)(arow + m * 16) * K + k0;
            ah[m] = *reinterpret_cast<const f16x8*>(Ahi + ga);
            al[m] = *reinterpret_cast<const f16x8*>(Alo + ga);
        }
#pragma unroll
        for (int n = 0; n < 2; ++n) {
            const size_t gb = (size_t)(wc + n * 16 + (lane & 15)) * K + k0;
            const f16x8 bh = *reinterpret_cast<const f16x8*>(Bhi + gb);
            const f16x8 bl = *reinterpret_cast<const f16x8*>(Blo + gb);
#pragma unroll
            for (int m = 0; m < 4; ++m)
                acc0[m][n] = __builtin_amdgcn_mfma_f32_16x16x32_f16(
                    ah[m], bh, acc0[m][n], 0, 0, 0);
#pragma unroll
            for (int m = 0; m < 4; ++m)
                acc1[m][n] = __builtin_amdgcn_mfma_f32_16x16x32_f16(
                    ah[m], bl, acc1[m][n], 0, 0, 0);
#pragma unroll
            for (int m = 0; m < 4; ++m)
                acc1[m][n] = __builtin_amdgcn_mfma_f32_16x16x32_f16(
                    al[m], bh, acc1[m][n], 0, 0, 0);
        }
    }

#pragma unroll
    for (int m = 0; m < 4; ++m)
#pragma unroll
        for (int n = 0; n < 2; ++n) {
            const int col = wc + n * 16 + (lane & 15);
            const float bv = bias[col];
#pragma unroll
            for (int q = 0; q < 4; ++q) {
                const int row = bm + wr + m * 16 + (lane >> 4) * 4 + q;
                C[(size_t)row * N + col] = acc0[m][n][q] + SPLIT_SCALE * acc1[m][n][q] + bv;
            }
        }
}

// ---------------------------------------------------------------------------
// VQ via MFMA: 128 rows x 256 entries split-fp16 GEMM -> fp32 d2 filter ->
// argmin reduce -> near-tie rows rescanned EXACTLY (fp64, first-min) by one
// WAVE per flagged row (lane l handles entries {l, l+64, l+128, l+192}).
// ---------------------------------------------------------------------------
#define VQ_EPS 1e-3f
__global__ __launch_bounds__(512)
void vq_mfma(const float* __restrict__ Z, const float* __restrict__ CB,
             const _Float16* __restrict__ Chi, const _Float16* __restrict__ Clo,
             float* __restrict__ OUT, unsigned short* __restrict__ ZQB)
{
    __shared__ float  ccf[256];
    __shared__ double ccd[256];
    __shared__ float  xxf[128];
    __shared__ double xxd[128];
    __shared__ float  redv[4][128];
    __shared__ int    redi[4][128];
    __shared__ float  bv1s[128];
    __shared__ int    bis[128];
    __shared__ int    flags[128];
    __shared__ int    flaglist[128];
    __shared__ int    nflag;

    const int tid  = threadIdx.x;
    const int lane = tid & 63;
    const int w    = tid >> 6;
    const int wr   = (w >> 2) * 64;              // 2 M-waves
    const int wc   = (w & 3) * 64;               // 4 N-waves
    const int bm   = blockIdx.x * 128;

    if (tid == 0) nflag = 0;
    if (tid < 256) {
        const float4* c4 = reinterpret_cast<const float4*>(CB + (size_t)tid * 64);
        double cc = 0.0;
#pragma unroll
        for (int v = 0; v < 16; ++v) {
            float4 f = c4[v];
            cc = fma((double)f.x, (double)f.x, cc);
            cc = fma((double)f.y, (double)f.y, cc);
            cc = fma((double)f.z, (double)f.z, cc);
            cc = fma((double)f.w, (double)f.w, cc);
        }
        ccd[tid] = cc; ccf[tid] = (float)cc;
    }
    if (tid < 128) {
        const float4* z4 = reinterpret_cast<const float4*>(Z + (size_t)(bm + tid) * 64);
        double xx = 0.0;
#pragma unroll
        for (int v = 0; v < 16; ++v) {
            float4 f = z4[v];
            xx = fma((double)f.x, (double)f.x, xx);
            xx = fma((double)f.y, (double)f.y, xx);
            xx = fma((double)f.z, (double)f.z, xx);
            xx = fma((double)f.w, (double)f.w, xx);
        }
        xxd[tid] = xx; xxf[tid] = (float)xx;
        flags[tid] = 0;
    }
    __syncthreads();

    f32x4 acc0[4][4], acc1[4][4];
#pragma unroll
    for (int m = 0; m < 4; ++m)
#pragma unroll
        for (int n = 0; n < 4; ++n) {
            acc0[m][n] = (f32x4){0.f, 0.f, 0.f, 0.f};
            acc1[m][n] = (f32x4){0.f, 0.f, 0.f, 0.f};
        }

    const int arow = bm + wr + (lane & 15);
    const int kgrp = (lane >> 4) * 8;

#pragma unroll
    for (int ks = 0; ks < 2; ++ks) {
        const int k0 = ks * 32 + kgrp;
        f16x8 ah[4], al[4];
#pragma unroll
        for (int m = 0; m < 4; ++m) {
            const float* src = Z + (size_t)(arow + m * 16) * 64 + k0;
            float4 v0 = *reinterpret_cast<const float4*>(src);
            float4 v1 = *reinterpret_cast<const float4*>(src + 4);
            float vv[8] = {v0.x, v0.y, v0.z, v0.w, v1.x, v1.y, v1.z, v1.w};
            f16x8 hh, ll;
#pragma unroll
            for (int j = 0; j < 8; ++j) {
                _Float16 hi, lo; fsplit(vv[j], hi, lo);
                hh[j] = hi; ll[j] = lo;
            }
            ah[m] = hh; al[m] = ll;
        }
#pragma unroll
        for (int n = 0; n < 4; ++n) {
            const size_t gb = (size_t)(wc + n * 16 + (lane & 15)) * 64 + k0;
            const f16x8 bh = *reinterpret_cast<const f16x8*>(Chi + gb);
            const f16x8 bl = *reinterpret_cast<const f16x8*>(Clo + gb);
#pragma unroll
            for (int m = 0; m < 4; ++m)
                acc0[m][n] = __builtin_amdgcn_mfma_f32_16x16x32_f16(
                    ah[m], bh, acc0[m][n], 0, 0, 0);
#pragma unroll
            for (int m = 0; m < 4; ++m)
                acc1[m][n] = __builtin_amdgcn_mfma_f32_16x16x32_f16(
                    ah[m], bl, acc1[m][n], 0, 0, 0);
#pragma unroll
            for (int m = 0; m < 4; ++m)
                acc1[m][n] = __builtin_amdgcn_mfma_f32_16x16x32_f16(
                    al[m], bh, acc1[m][n], 0, 0, 0);
        }
    }

#pragma unroll
    for (int m = 0; m < 4; ++m)
#pragma unroll
        for (int n = 0; n < 4; ++n) {
            const int col = wc + n * 16 + (lane & 15);
            const float cf = ccf[col];
#pragma unroll
            for (int q = 0; q < 4; ++q) {
                const int rl = wr + m * 16 + (lane >> 4) * 4 + q;
                float dot = acc0[m][n][q] + SPLIT_SCALE * acc1[m][n][q];
                acc0[m][n][q] = (xxf[rl] - 2.0f * dot) + cf;
            }
        }

    float bvr[4][4]; int bir[4][4];
#pragma unroll
    for (int m = 0; m < 4; ++m)
#pragma unroll
        for (int q = 0; q < 4; ++q) {
            float bv = 3.4e38f; int bi = 0;
#pragma unroll
            for (int n = 0; n < 4; ++n) {
                const int col = wc + n * 16 + (lane & 15);
                const float v = acc0[m][n][q];
                if (v < bv || (v == bv && col < bi)) { bv = v; bi = col; }
            }
            bvr[m][q] = bv; bir[m][q] = bi;
        }
#pragma unroll
    for (int mask = 1; mask < 16; mask <<= 1) {
#pragma unroll
        for (int m = 0; m < 4; ++m)
#pragma unroll
            for (int q = 0; q < 4; ++q) {
                float ov = __shfl_xor(bvr[m][q], mask);
                int   oi = __shfl_xor(bir[m][q], mask);
                if (ov < bvr[m][q] || (ov == bvr[m][q] && oi < bir[m][q])) {
                    bvr[m][q] = ov; bir[m][q] = oi;
                }
            }
    }
    if ((lane & 15) == 0) {
#pragma unroll
        for (int m = 0; m < 4; ++m)
#pragma unroll
            for (int q = 0; q < 4; ++q) {
                const int rl = wr + m * 16 + (lane >> 4) * 4 + q;
                redv[w & 3][rl] = bvr[m][q];
                redi[w & 3][rl] = bir[m][q];
            }
    }
    __syncthreads();

    if (tid < 128) {
        float bv = 3.4e38f; int bi = 0;
#pragma unroll
        for (int nw = 0; nw < 4; ++nw) {
            float v = redv[nw][tid];
            if (v < bv) { bv = v; bi = redi[nw][tid]; }
        }
        bv1s[tid] = bv; bis[tid] = bi;
    }
    __syncthreads();

#pragma unroll
    for (int m = 0; m < 4; ++m)
#pragma unroll
        for (int q = 0; q < 4; ++q) {
            const int rl = wr + m * 16 + (lane >> 4) * 4 + q;
            const float thr = bv1s[rl] + VQ_EPS;
            const int   win = bis[rl];
#pragma unroll
            for (int n = 0; n < 4; ++n) {
                const int col = wc + n * 16 + (lane & 15);
                if (acc0[m][n][q] <= thr && col != win) flags[rl] = 1;
            }
        }
    __syncthreads();

    if (tid < 128 && flags[tid]) {
        int s = atomicAdd(&nflag, 1);
        flaglist[s] = tid;
    }
    __syncthreads();

    for (int fi = w; fi < nflag; fi += 8) {
        const int rl = flaglist[fi];
        const float* zr = Z + (size_t)(bm + rl) * 64;
        const double xx = xxd[rl];
        double best = 1.0e300; int bi = 256;
#pragma unroll
        for (int j = 0; j < 4; ++j) {
            const int e = lane + j * 64;
            const float* c = CB + (size_t)e * 64;
            double dot = 0.0;
#pragma unroll
            for (int d = 0; d < 64; ++d)
                dot = fma((double)zr[d], (double)c[d], dot);
            double d2x = (xx - 2.0 * dot) + ccd[e];
            if (d2x < best || (d2x == best && e < bi)) { best = d2x; bi = e; }
        }
#pragma unroll
        for (int mask = 1; mask < 64; mask <<= 1) {
            double ov = __shfl_xor(best, mask);
            int    oi = __shfl_xor(bi, mask);
            if (ov < best || (ov == best && oi < bi)) { best = ov; bi = oi; }
        }
        if (lane == 0) bis[rl] = bi;
    }
    __syncthreads();

    {
        const int row  = tid >> 2;
        const int part = tid & 3;
        const int bi   = bis[row];
        const float4* src = reinterpret_cast<const float4*>(CB + (size_t)bi * 64) + part * 4;
        float* dst = OUT + (size_t)(bm + row) * 64 + part * 16;
        unsigned short* dq = ZQB + (size_t)(bm + row) * 64 + part * 16;
#pragma unroll
        for (int v = 0; v < 4; ++v) {
            float4 f = src[v];
            *reinterpret_cast<float4*>(dst + v * 4) = f;
            ushort4 qb = { f2bf(f.x), f2bf(f.y), f2bf(f.z), f2bf(f.w) };
            *reinterpret_cast<ushort4*>(dq + v * 4) = qb;
        }
    }
}

// ---------------------------------------------------------------------------
// bf16 MFMA GEMM (decoder) -- single-buffered (round-5 known-good).
// ---------------------------------------------------------------------------
template<bool RELU, bool OUT_BF16>
__global__ __launch_bounds__(256)
void gemm_mfma_bt(const unsigned short* __restrict__ A,
                  const unsigned short* __restrict__ Bt,
                  const float* __restrict__ bias,
                  void* __restrict__ Cv, int M, int N, int K)
{
    constexpr int BK  = 64;
    constexpr int LDP = BK + 8;

    __shared__ alignas(16) unsigned short Asl[128][LDP];
    __shared__ alignas(16) unsigned short Bsl[128][LDP];

    const int tid  = threadIdx.x;
    const int lane = tid & 63;
    const int w    = tid >> 6;
    const int wr   = (w >> 1) * 64;
    const int wc   = (w & 1) * 64;
    const int bm   = blockIdx.y * 128;
    const int bn   = blockIdx.x * 128;

    f32x4 acc[4][4];
#pragma unroll
    for (int m = 0; m < 4; ++m)
#pragma unroll
        for (int n = 0; n < 4; ++n) acc[m][n] = (f32x4){0.f, 0.f, 0.f, 0.f};

    const int sr = tid >> 1;
    const int sc = (tid & 1) * 32;

    for (int k0 = 0; k0 < K; k0 += BK) {
        {
            const float4* ga = reinterpret_cast<const float4*>(
                &A[(size_t)(bm + sr) * K + k0 + sc]);
            const float4* gb = reinterpret_cast<const float4*>(
                &Bt[(size_t)(bn + sr) * K + k0 + sc]);
            float4 va0 = ga[0], va1 = ga[1], va2 = ga[2], va3 = ga[3];
            float4 vb0 = gb[0], vb1 = gb[1], vb2 = gb[2], vb3 = gb[3];
            float4* da = reinterpret_cast<float4*>(&Asl[sr][sc]);
            float4* db = reinterpret_cast<float4*>(&Bsl[sr][sc]);
            da[0] = va0; da[1] = va1; da[2] = va2; da[3] = va3;
            db[0] = vb0; db[1] = vb1; db[2] = vb2; db[3] = vb3;
        }
        __syncthreads();

#pragma unroll
        for (int ks = 0; ks < 2; ++ks) {
            bf16x8 af[4], bf[4];
            const int kc = ks * 32 + (lane >> 4) * 8;
#pragma unroll
            for (int m = 0; m < 4; ++m)
                af[m] = *reinterpret_cast<const bf16x8*>(
                    &Asl[wr + m * 16 + (lane & 15)][kc]);
#pragma unroll
            for (int n = 0; n < 4; ++n)
                bf[n] = *reinterpret_cast<const bf16x8*>(
                    &Bsl[wc + n * 16 + (lane & 15)][kc]);
#pragma unroll
            for (int m = 0; m < 4; ++m)
#pragma unroll
                for (int n = 0; n < 4; ++n)
                    acc[m][n] = __builtin_amdgcn_mfma_f32_16x16x32_bf16(
                        af[m], bf[n], acc[m][n], 0, 0, 0);
        }
        __syncthreads();
    }

#pragma unroll
    for (int m = 0; m < 4; ++m)
#pragma unroll
        for (int n = 0; n < 4; ++n) {
            const int col = bn + wc + n * 16 + (lane & 15);
            const float bv = bias[col];
#pragma unroll
            for (int q = 0; q < 4; ++q) {
                const int row = bm + wr + m * 16 + (lane >> 4) * 4 + q;
                float v = acc[m][n][q] + bv;
                if (RELU) v = fmaxf(v, 0.f);
                if (OUT_BF16)
                    reinterpret_cast<unsigned short*>(Cv)[(size_t)row * N + col] = f2bf(v);
                else
                    reinterpret_cast<float*>(Cv)[(size_t)row * N + col] = v;
            }
        }
}

// ---------------------------------------------------------------------------
// small prep kernels
// ---------------------------------------------------------------------------
__global__ __launch_bounds__(256)
void transpose_bf16(const float* __restrict__ W, unsigned short* __restrict__ Wt,
                    int K, int N)
{
    int idx = blockIdx.x * 256 + threadIdx.x;
    if (idx >= K * N) return;
    int n = idx / K, k = idx % K;
    Wt[idx] = f2bf(W[(size_t)k * N + n]);
}

__global__ __launch_bounds__(256)
void transpose_split_f16(const float* __restrict__ W,
                         _Float16* __restrict__ Whi, _Float16* __restrict__ Wlo,
                         int K, int N)
{
    int idx = blockIdx.x * 256 + threadIdx.x;
    if (idx >= K * N) return;
    int n = idx / K, k = idx % K;
    _Float16 hi, lo; fsplit(W[(size_t)k * N + n], hi, lo);
    Whi[idx] = hi; Wlo[idx] = lo;
}

__global__ __launch_bounds__(256)
void split_flat_f16(const float* __restrict__ src,
                    _Float16* __restrict__ hi, _Float16* __restrict__ lo, int n)
{
    int i = blockIdx.x * 256 + threadIdx.x;
    if (i >= n) return;
    _Float16 h, l; fsplit(src[i], h, l);
    hi[i] = h; lo[i] = l;
}

// ---------------------------------------------------------------------------
extern "C" void kernel_launch(void* const* d_in, const int* in_sizes, int n_in,
                              void* d_out, int out_size, void* d_ws, size_t ws_size,
                              hipStream_t stream)
{
    const float* X  = (const float*)d_in[0];
    const float* W0 = (const float*)d_in[1];
    const float* b0 = (const float*)d_in[2];
    const float* W1 = (const float*)d_in[3];
    const float* b1 = (const float*)d_in[4];
    const float* W2 = (const float*)d_in[5];
    const float* b2 = (const float*)d_in[6];
    const float* CB = (const float*)d_in[7];
    const float* W3 = (const float*)d_in[8];
    const float* b3 = (const float*)d_in[9];
    const float* W4 = (const float*)d_in[10];
    const float* b4 = (const float*)d_in[11];
    const float* W5 = (const float*)d_in[12];
    const float* b5 = (const float*)d_in[13];

    const int D_in = 256, H = 512, R = 64, S = 512, NA = 8;
    const int Mtot = in_sizes[0] / D_in;          // 131072

    float* recon = (float*)d_out;
    float* ze    = recon + (size_t)(Mtot / NA) * S;
    float* remb  = ze + (size_t)Mtot * R;

    // ---- workspace: fixed weight planes ----
    char* p = (char*)d_ws;
    _Float16* W0hi = (_Float16*)p;  p += (size_t)H * D_in * 2;
    _Float16* W0lo = (_Float16*)p;  p += (size_t)H * D_in * 2;
    _Float16* W1hi = (_Float16*)p;  p += (size_t)H * H * 2;
    _Float16* W1lo = (_Float16*)p;  p += (size_t)H * H * 2;
    _Float16* W2thi = (_Float16*)p; p += (size_t)R * H * 2;        // [64][512]
    _Float16* W2tlo = (_Float16*)p; p += (size_t)R * H * 2;
    _Float16* CBhi = (_Float16*)p;  p += (size_t)256 * R * 2;      // [256][64]
    _Float16* CBlo = (_Float16*)p;  p += (size_t)256 * R * 2;
    unsigned short* W3t = (unsigned short*)p;  p += (size_t)H * R * 2;
    unsigned short* W4t = (unsigned short*)p;  p += (size_t)H * (NA * H) * 2;
    unsigned short* W5t = (unsigned short*)p;  p += (size_t)S * H * 2;
    size_t fixed = (size_t)(p - (char*)d_ws);
    fixed = (fixed + 255) & ~(size_t)255;

    // per-row chunk bytes: h0 pair 2048 + h1 pair 2048 + zqb 128
    int nc = 2;
    while (nc < 128) {
        size_t rpcT = (size_t)Mtot / nc;
        if (fixed + rpcT * 4224 + 1024 <= ws_size) break;
        nc *= 2;
    }
    const int rpc = Mtot / nc;
    char* q = (char*)d_ws + fixed;
    // h0hi/h0lo and h1hi/h1lo contiguous (split5 AF32=false uses Ahi + M*K)
    _Float16* h0hi = (_Float16*)q;                 q += (size_t)rpc * H * 2;
    _Float16* h0lo = (_Float16*)q;                 q += (size_t)rpc * H * 2;
    _Float16* h1hi = (_Float16*)q;                 q += (size_t)rpc * H * 2;
    _Float16* h1lo = (_Float16*)q;                 q += (size_t)rpc * H * 2;
    unsigned short* zqb = (unsigned short*)q;      q += (size_t)rpc * R * 2;
    unsigned short* rec1b = (unsigned short*)h0hi;     // alias (h0 dead after h1)
    unsigned short* rec2b = (unsigned short*)h1hi;     // alias (h1 dead after ze)

    // ---- one-time weight prep ----
    transpose_split_f16<<<(H * D_in + 255) / 256, 256, 0, stream>>>(W0, W0hi, W0lo, D_in, H);
    transpose_split_f16<<<(H * H + 255) / 256, 256, 0, stream>>>(W1, W1hi, W1lo, H, H);
    transpose_split_f16<<<(H * R + 255) / 256, 256, 0, stream>>>(W2, W2thi, W2tlo, H, R);
    split_flat_f16<<<(256 * R + 255) / 256, 256, 0, stream>>>(CB, CBhi, CBlo, 256 * R);
    transpose_bf16<<<(H * R + 255) / 256, 256, 0, stream>>>(W3, W3t, R, H);
    transpose_bf16<<<(H * NA * H + 255) / 256, 256, 0, stream>>>(W4, W4t, NA * H, H);
    transpose_bf16<<<(S * H + 255) / 256, 256, 0, stream>>>(W5, W5t, H, S);

    for (int r0 = 0; r0 < Mtot; r0 += rpc) {
        const int M6 = rpc / NA;
        // encoder: register-lean split-fp16 MFMA (4 waves/SIMD target)
        gemm_split5<256, true><<<dim3(H / 64, rpc / 128), 256, 0, stream>>>(
            X + (size_t)r0 * D_in, W0hi, W0lo, b0, h0hi, h0lo, rpc, H);
        gemm_split5<512, false><<<dim3(H / 64, rpc / 128), 256, 0, stream>>>(
            h0hi, W1hi, W1lo, b1, h1hi, h1lo, rpc, H);
        // z_e: split-fp16 MFMA, fp32 accum -> output zone 1
        gemm_ze_mfma<<<rpc / 128, 256, 0, stream>>>(
            h1hi, h1lo, W2thi, W2tlo, b2, ze + (size_t)r0 * R, rpc);
        // VQ via MFMA (fp32 filter + wave-parallel fp64 near-tie rescan)
        vq_mfma<<<rpc / 128, 512, 0, stream>>>(
            ze + (size_t)r0 * R, CB, CBhi, CBlo,
            remb + (size_t)r0 * R, zqb);
        // decoder: bf16 MFMA
        gemm_mfma_bt<true, true><<<dim3(H / 128, rpc / 128), 256, 0, stream>>>(
            zqb, W3t, b3, rec1b, rpc, H, R);
        gemm_mfma_bt<true, true><<<dim3(H / 128, M6 / 128), 256, 0, stream>>>(
            rec1b, W4t, b4, rec2b, M6, H, NA * H);
        gemm_mfma_bt<false, false><<<dim3(S / 128, M6 / 128), 256, 0, stream>>>(
            rec2b, W5t, b5, recon + (size_t)(r0 / NA) * S, M6, S, H);
    }
}

// Round 11
// 1035.364 us; speedup vs baseline: 1.7227x; 1.2401x over previous
//
#include <hip/hip_runtime.h>
#include <hip/hip_bf16.h>
#include <cstddef>

__device__ __forceinline__ unsigned short f2bf(float f) {
    union { float f; unsigned int u; } v; v.f = f;
    unsigned int r = (v.u + 0x7fffu + ((v.u >> 16) & 1u)) >> 16;   // RNE
    return (unsigned short)r;
}

typedef __bf16    bf16x8 __attribute__((ext_vector_type(8)));
typedef float     f32x4  __attribute__((ext_vector_type(4)));
typedef _Float16  f16x8  __attribute__((ext_vector_type(8)));

#define SPLIT_SCALE 2.44140625e-4f   // 2^-12

// fp32 -> fp16 (hi, lo*4096) split: hi + 2^-12*lo == v to ~2^-22 relative.
__device__ __forceinline__ void fsplit(float v, _Float16& hi, _Float16& lo) {
    hi = (_Float16)v;
    lo = (_Float16)((v - (float)hi) * 4096.0f);
}

// ---------------------------------------------------------------------------
// Split-fp16 MFMA GEMM v5 (encoder): C = relu(A @ Bt^T + bias).
// 128x64 block tile, 256 thr, wave tile 32x64; ~125 VGPR -> 4 waves/SIMD.
// B hi/lo double-buffered LDS (20KB); A direct from global (issue-early /
// write-late); bijective XCD chunk swizzle.
// ---------------------------------------------------------------------------
template<int K, bool AF32>
__global__ __launch_bounds__(256, AF32 ? 3 : 4)
void gemm_split5(const void* __restrict__ Asrc,
                 const _Float16* __restrict__ Bhi, const _Float16* __restrict__ Blo,
                 const float* __restrict__ bias,
                 _Float16* __restrict__ Chi, _Float16* __restrict__ Clo,
                 int M, int N)
{
    constexpr int BK  = 32;
    constexpr int LDP = 40;                      // 80B row stride
    constexpr int NS  = K / BK;

    __shared__ alignas(16) _Float16 Bh[2][64][LDP];   // 10240 B
    __shared__ alignas(16) _Float16 Bl[2][64][LDP];   // 10240 B

    const int tid  = threadIdx.x;
    const int lane = tid & 63;
    const int w    = tid >> 6;                   // 0..3

    int bx = blockIdx.x, by = blockIdx.y;
    {
        const int gx = gridDim.x, nwg = gx * gridDim.y;
        if ((nwg & 7) == 0) {
            int d = bx + by * gx;
            int L = (d & 7) * (nwg >> 3) + (d >> 3);
            bx = L % gx; by = L / gx;
        }
    }
    const int bm = by * 128;
    const int bn = bx * 64;

    f32x4 acc0[2][4], acc1[2][4];
#pragma unroll
    for (int m = 0; m < 2; ++m)
#pragma unroll
        for (int n = 0; n < 4; ++n) {
            acc0[m][n] = (f32x4){0.f, 0.f, 0.f, 0.f};
            acc1[m][n] = (f32x4){0.f, 0.f, 0.f, 0.f};
        }

    const int arow = bm + w * 32 + (lane & 15);  // A-frag row (m=0)
    const int kgrp = (lane >> 4) * 8;            // k sub-offset
    const int brow = tid >> 2;                   // B staging: 4 thr/row (0..63)
    const int bcol = (tid & 3) * 8;              // 8 f16 (16B) each

    const _Float16* Ahi_ = (const _Float16*)Asrc;
    const float*    Af_  = (const float*)Asrc;

    f16x8 ah[2], al[2], ahn[2], aln[2];
    float4 rbh, rbl;

    auto loadB = [&](int k0) {
        const size_t gb = (size_t)(bn + brow) * K + k0 + bcol;
        rbh = *reinterpret_cast<const float4*>(Bhi + gb);
        rbl = *reinterpret_cast<const float4*>(Blo + gb);
    };
    auto storeB = [&](int p) {
        *reinterpret_cast<float4*>(&Bh[p][brow][bcol]) = rbh;
        *reinterpret_cast<float4*>(&Bl[p][brow][bcol]) = rbl;
    };
    auto loadA = [&](int k0, f16x8* h, f16x8* l) {
#pragma unroll
        for (int m = 0; m < 2; ++m) {
            const size_t ga = (size_t)(arow + m * 16) * K + k0 + kgrp;
            if constexpr (AF32) {
                float4 v0 = *reinterpret_cast<const float4*>(Af_ + ga);
                float4 v1 = *reinterpret_cast<const float4*>(Af_ + ga + 4);
                float vv[8] = {v0.x, v0.y, v0.z, v0.w, v1.x, v1.y, v1.z, v1.w};
                f16x8 hh, ll;
#pragma unroll
                for (int j = 0; j < 8; ++j) {
                    _Float16 hi, lo; fsplit(vv[j], hi, lo);
                    hh[j] = hi; ll[j] = lo;
                }
                h[m] = hh; l[m] = ll;
            } else {
                h[m] = *reinterpret_cast<const f16x8*>(Ahi_ + ga);
                l[m] = *reinterpret_cast<const f16x8*>(Ahi_ + (size_t)M * K + ga);
            }
        }
    };

    loadB(0);
    loadA(0, ah, al);
    storeB(0);
    __syncthreads();

#pragma unroll
    for (int s = 0; s < NS; ++s) {
        const int p = s & 1;
        if (s + 1 < NS) {                        // issue next-tile loads EARLY
            loadB((s + 1) * BK);
            loadA((s + 1) * BK, ahn, aln);
        }
#pragma unroll
        for (int n = 0; n < 4; ++n) {
            const f16x8 bh = *reinterpret_cast<const f16x8*>(
                &Bh[p][n * 16 + (lane & 15)][kgrp]);
            const f16x8 bl = *reinterpret_cast<const f16x8*>(
                &Bl[p][n * 16 + (lane & 15)][kgrp]);
#pragma unroll
            for (int m = 0; m < 2; ++m)
                acc0[m][n] = __builtin_amdgcn_mfma_f32_16x16x32_f16(
                    ah[m], bh, acc0[m][n], 0, 0, 0);
#pragma unroll
            for (int m = 0; m < 2; ++m)
                acc1[m][n] = __builtin_amdgcn_mfma_f32_16x16x32_f16(
                    ah[m], bl, acc1[m][n], 0, 0, 0);
#pragma unroll
            for (int m = 0; m < 2; ++m)
                acc1[m][n] = __builtin_amdgcn_mfma_f32_16x16x32_f16(
                    al[m], bh, acc1[m][n], 0, 0, 0);
        }
        if (s + 1 < NS) {                        // write-late into other buffer
            storeB(p ^ 1);
#pragma unroll
            for (int m = 0; m < 2; ++m) { ah[m] = ahn[m]; al[m] = aln[m]; }
        }
        __syncthreads();
    }

#pragma unroll
    for (int m = 0; m < 2; ++m)
#pragma unroll
        for (int n = 0; n < 4; ++n) {
            const int col = bn + n * 16 + (lane & 15);
            const float bv = bias[col];
#pragma unroll
            for (int q = 0; q < 4; ++q) {
                const int row = bm + w * 32 + m * 16 + (lane >> 4) * 4 + q;
                float v = acc0[m][n][q] + SPLIT_SCALE * acc1[m][n][q] + bv;
                v = fmaxf(v, 0.f);
                _Float16 hi, lo; fsplit(v, hi, lo);
                Chi[(size_t)row * N + col] = hi;
                Clo[(size_t)row * N + col] = lo;
            }
        }
}

// ---------------------------------------------------------------------------
// z_e GEMM via split-fp16 MFMA: ze[M,64] = h1 @ W2 + b2, fp32 accumulation.
// ---------------------------------------------------------------------------
__global__ __launch_bounds__(256)
void gemm_ze_mfma(const _Float16* __restrict__ Ahi, const _Float16* __restrict__ Alo,
                  const _Float16* __restrict__ Bhi, const _Float16* __restrict__ Blo,
                  const float* __restrict__ bias, float* __restrict__ C, int M)
{
    constexpr int K = 512, N = 64;
    const int tid  = threadIdx.x;
    const int lane = tid & 63;
    const int w    = tid >> 6;
    const int wr   = (w >> 1) * 64;
    const int wc   = (w & 1) * 32;
    const int bm   = blockIdx.x * 128;

    f32x4 acc0[4][2], acc1[4][2];
#pragma unroll
    for (int m = 0; m < 4; ++m)
#pragma unroll
        for (int n = 0; n < 2; ++n) {
            acc0[m][n] = (f32x4){0.f, 0.f, 0.f, 0.f};
            acc1[m][n] = (f32x4){0.f, 0.f, 0.f, 0.f};
        }

    const int arow = bm + wr + (lane & 15);
    const int kgrp = (lane >> 4) * 8;

#pragma unroll
    for (int ks = 0; ks < K / 32; ++ks) {
        const int k0 = ks * 32 + kgrp;
        f16x8 ah[4], al[4];
#pragma unroll
        for (int m = 0; m < 4; ++m) {
            const size_t ga = (size_t)(arow + m * 16) * K + k0;
            ah[m] = *reinterpret_cast<const f16x8*>(Ahi + ga);
            al[m] = *reinterpret_cast<const f16x8*>(Alo + ga);
        }
#pragma unroll
        for (int n = 0; n < 2; ++n) {
            const size_t gb = (size_t)(wc + n * 16 + (lane & 15)) * K + k0;
            const f16x8 bh = *reinterpret_cast<const f16x8*>(Bhi + gb);
            const f16x8 bl = *reinterpret_cast<const f16x8*>(Blo + gb);
#pragma unroll
            for (int m = 0; m < 4; ++m)
                acc0[m][n] = __builtin_amdgcn_mfma_f32_16x16x32_f16(
                    ah[m], bh, acc0[m][n], 0, 0, 0);
#pragma unroll
            for (int m = 0; m < 4; ++m)
                acc1[m][n] = __builtin_amdgcn_mfma_f32_16x16x32_f16(
                    ah[m], bl, acc1[m][n], 0, 0, 0);
#pragma unroll
            for (int m = 0; m < 4; ++m)
                acc1[m][n] = __builtin_amdgcn_mfma_f32_16x16x32_f16(
                    al[m], bh, acc1[m][n], 0, 0, 0);
        }
    }

#pragma unroll
    for (int m = 0; m < 4; ++m)
#pragma unroll
        for (int n = 0; n < 2; ++n) {
            const int col = wc + n * 16 + (lane & 15);
            const float bv = bias[col];
#pragma unroll
            for (int q = 0; q < 4; ++q) {
                const int row = bm + wr + m * 16 + (lane >> 4) * 4 + q;
                C[(size_t)row * N + col] = acc0[m][n][q] + SPLIT_SCALE * acc1[m][n][q] + bv;
            }
        }
}

// ---------------------------------------------------------------------------
// VQ via MFMA: 128 rows x 256 entries split-fp16 GEMM -> fp32 d2 filter ->
// argmin reduce -> CANDIDATE-ONLY exact fp64 re-check. Every entry with
// d2f <= bv1+EPS is recorded (LDS list, atomicAdd); rows with >1 candidate
// get exact fp64 d2 over just those entries (owner thread, ~2x64 FMA),
// lexicographic (d2,idx) first-min. EPS=1e-3 >= 30x worst-case d2f error ->
// exact winner provably in the candidate set. Overflow (>16) -> full
// wave-parallel fp64 rescan fallback (practically never taken).
// ---------------------------------------------------------------------------
#define VQ_EPS 1e-3f
__global__ __launch_bounds__(512)
void vq_mfma(const float* __restrict__ Z, const float* __restrict__ CB,
             const _Float16* __restrict__ Chi, const _Float16* __restrict__ Clo,
             float* __restrict__ OUT, unsigned short* __restrict__ ZQB)
{
    __shared__ float  ccf[256];
    __shared__ double ccd[256];
    __shared__ float  xxf[128];
    __shared__ double xxd[128];
    __shared__ float  redv[4][128];
    __shared__ int    redi[4][128];
    __shared__ float  bv1s[128];
    __shared__ int    bis[128];
    __shared__ int    cand[128][16];
    __shared__ int    ncand[128];
    __shared__ int    fullflag[128];
    __shared__ int    flaglist[128];
    __shared__ int    nflag;

    const int tid  = threadIdx.x;
    const int lane = tid & 63;
    const int w    = tid >> 6;
    const int wr   = (w >> 2) * 64;              // 2 M-waves
    const int wc   = (w & 3) * 64;               // 4 N-waves
    const int bm   = blockIdx.x * 128;

    if (tid == 0) nflag = 0;
    if (tid < 256) {
        const float4* c4 = reinterpret_cast<const float4*>(CB + (size_t)tid * 64);
        double cc = 0.0;
#pragma unroll
        for (int v = 0; v < 16; ++v) {
            float4 f = c4[v];
            cc = fma((double)f.x, (double)f.x, cc);
            cc = fma((double)f.y, (double)f.y, cc);
            cc = fma((double)f.z, (double)f.z, cc);
            cc = fma((double)f.w, (double)f.w, cc);
        }
        ccd[tid] = cc; ccf[tid] = (float)cc;
    }
    if (tid < 128) {
        const float4* z4 = reinterpret_cast<const float4*>(Z + (size_t)(bm + tid) * 64);
        double xx = 0.0;
#pragma unroll
        for (int v = 0; v < 16; ++v) {
            float4 f = z4[v];
            xx = fma((double)f.x, (double)f.x, xx);
            xx = fma((double)f.y, (double)f.y, xx);
            xx = fma((double)f.z, (double)f.z, xx);
            xx = fma((double)f.w, (double)f.w, xx);
        }
        xxd[tid] = xx; xxf[tid] = (float)xx;
        ncand[tid] = 0; fullflag[tid] = 0;
    }
    __syncthreads();

    // ---- phase B: split-fp16 MFMA dot products ----
    f32x4 acc0[4][4], acc1[4][4];
#pragma unroll
    for (int m = 0; m < 4; ++m)
#pragma unroll
        for (int n = 0; n < 4; ++n) {
            acc0[m][n] = (f32x4){0.f, 0.f, 0.f, 0.f};
            acc1[m][n] = (f32x4){0.f, 0.f, 0.f, 0.f};
        }

    const int arow = bm + wr + (lane & 15);
    const int kgrp = (lane >> 4) * 8;

#pragma unroll
    for (int ks = 0; ks < 2; ++ks) {
        const int k0 = ks * 32 + kgrp;
        f16x8 ah[4], al[4];
#pragma unroll
        for (int m = 0; m < 4; ++m) {
            const float* src = Z + (size_t)(arow + m * 16) * 64 + k0;
            float4 v0 = *reinterpret_cast<const float4*>(src);
            float4 v1 = *reinterpret_cast<const float4*>(src + 4);
            float vv[8] = {v0.x, v0.y, v0.z, v0.w, v1.x, v1.y, v1.z, v1.w};
            f16x8 hh, ll;
#pragma unroll
            for (int j = 0; j < 8; ++j) {
                _Float16 hi, lo; fsplit(vv[j], hi, lo);
                hh[j] = hi; ll[j] = lo;
            }
            ah[m] = hh; al[m] = ll;
        }
#pragma unroll
        for (int n = 0; n < 4; ++n) {
            const size_t gb = (size_t)(wc + n * 16 + (lane & 15)) * 64 + k0;
            const f16x8 bh = *reinterpret_cast<const f16x8*>(Chi + gb);
            const f16x8 bl = *reinterpret_cast<const f16x8*>(Clo + gb);
#pragma unroll
            for (int m = 0; m < 4; ++m)
                acc0[m][n] = __builtin_amdgcn_mfma_f32_16x16x32_f16(
                    ah[m], bh, acc0[m][n], 0, 0, 0);
#pragma unroll
            for (int m = 0; m < 4; ++m)
                acc1[m][n] = __builtin_amdgcn_mfma_f32_16x16x32_f16(
                    ah[m], bl, acc1[m][n], 0, 0, 0);
#pragma unroll
            for (int m = 0; m < 4; ++m)
                acc1[m][n] = __builtin_amdgcn_mfma_f32_16x16x32_f16(
                    al[m], bh, acc1[m][n], 0, 0, 0);
        }
    }

    // fold into d2f (store in acc0): d2 = xx - 2*dot + cc
#pragma unroll
    for (int m = 0; m < 4; ++m)
#pragma unroll
        for (int n = 0; n < 4; ++n) {
            const int col = wc + n * 16 + (lane & 15);
            const float cf = ccf[col];
#pragma unroll
            for (int q = 0; q < 4; ++q) {
                const int rl = wr + m * 16 + (lane >> 4) * 4 + q;
                float dot = acc0[m][n][q] + SPLIT_SCALE * acc1[m][n][q];
                acc0[m][n][q] = (xxf[rl] - 2.0f * dot) + cf;
            }
        }

    // ---- phase C: fp32 argmin reduction (first-min) ----
    float bvr[4][4]; int bir[4][4];
#pragma unroll
    for (int m = 0; m < 4; ++m)
#pragma unroll
        for (int q = 0; q < 4; ++q) {
            float bv = 3.4e38f; int bi = 0;
#pragma unroll
            for (int n = 0; n < 4; ++n) {
                const int col = wc + n * 16 + (lane & 15);
                const float v = acc0[m][n][q];
                if (v < bv || (v == bv && col < bi)) { bv = v; bi = col; }
            }
            bvr[m][q] = bv; bir[m][q] = bi;
        }
#pragma unroll
    for (int mask = 1; mask < 16; mask <<= 1) {
#pragma unroll
        for (int m = 0; m < 4; ++m)
#pragma unroll
            for (int q = 0; q < 4; ++q) {
                float ov = __shfl_xor(bvr[m][q], mask);
                int   oi = __shfl_xor(bir[m][q], mask);
                if (ov < bvr[m][q] || (ov == bvr[m][q] && oi < bir[m][q])) {
                    bvr[m][q] = ov; bir[m][q] = oi;
                }
            }
    }
    if ((lane & 15) == 0) {
#pragma unroll
        for (int m = 0; m < 4; ++m)
#pragma unroll
            for (int q = 0; q < 4; ++q) {
                const int rl = wr + m * 16 + (lane >> 4) * 4 + q;
                redv[w & 3][rl] = bvr[m][q];
                redi[w & 3][rl] = bir[m][q];
            }
    }
    __syncthreads();

    if (tid < 128) {
        float bv = 3.4e38f; int bi = 0;
#pragma unroll
        for (int nw = 0; nw < 4; ++nw) {        // ascending entry ranges
            float v = redv[nw][tid];
            if (v < bv) { bv = v; bi = redi[nw][tid]; }
        }
        bv1s[tid] = bv; bis[tid] = bi;
    }
    __syncthreads();

    // ---- phase D: candidate collection (includes the winner) ----
#pragma unroll
    for (int m = 0; m < 4; ++m)
#pragma unroll
        for (int q = 0; q < 4; ++q) {
            const int rl = wr + m * 16 + (lane >> 4) * 4 + q;
            const float thr = bv1s[rl] + VQ_EPS;
#pragma unroll
            for (int n = 0; n < 4; ++n) {
                const int col = wc + n * 16 + (lane & 15);
                if (acc0[m][n][q] <= thr) {
                    int s = atomicAdd(&ncand[rl], 1);
                    if (s < 16) cand[rl][s] = col;
                    else        fullflag[rl] = 1;
                }
            }
        }
    __syncthreads();

    // ---- phase E1: exact fp64 over candidates (owner thread, tiny) ----
    if (tid < 128) {
        const int nc_ = ncand[tid] < 16 ? ncand[tid] : 16;
        if (nc_ > 1 && !fullflag[tid]) {
            const float4* z4p = reinterpret_cast<const float4*>(Z + (size_t)(bm + tid) * 64);
            const double xx = xxd[tid];
            double best = 1.0e300; int bi = 256;
            for (int s = 0; s < nc_; ++s) {
                const int e = cand[tid][s];
                const float4* c4p = reinterpret_cast<const float4*>(CB + (size_t)e * 64);
                double dot = 0.0;
#pragma unroll
                for (int v = 0; v < 16; ++v) {
                    float4 zf = z4p[v], cf4 = c4p[v];
                    dot = fma((double)zf.x, (double)cf4.x, dot);
                    dot = fma((double)zf.y, (double)cf4.y, dot);
                    dot = fma((double)zf.z, (double)cf4.z, dot);
                    dot = fma((double)zf.w, (double)cf4.w, dot);
                }
                double d2x = (xx - 2.0 * dot) + ccd[e];
                if (d2x < best || (d2x == best && e < bi)) { best = d2x; bi = e; }
            }
            bis[tid] = bi;
        }
        if (fullflag[tid]) {
            int s = atomicAdd(&nflag, 1);
            flaglist[s] = tid;
        }
    }
    __syncthreads();

    // ---- phase E2: overflow fallback — full fp64 rescan, one wave/row ----
    for (int fi = w; fi < nflag; fi += 8) {
        const int rl = flaglist[fi];
        const float* zr = Z + (size_t)(bm + rl) * 64;
        const double xx = xxd[rl];
        double best = 1.0e300; int bi = 256;
#pragma unroll
        for (int j = 0; j < 4; ++j) {
            const int e = lane + j * 64;
            const float* c = CB + (size_t)e * 64;
            double dot = 0.0;
#pragma unroll
            for (int d = 0; d < 64; ++d)
                dot = fma((double)zr[d], (double)c[d], dot);
            double d2x = (xx - 2.0 * dot) + ccd[e];
            if (d2x < best || (d2x == best && e < bi)) { best = d2x; bi = e; }
        }
#pragma unroll
        for (int mask = 1; mask < 64; mask <<= 1) {
            double ov = __shfl_xor(best, mask);
            int    oi = __shfl_xor(bi, mask);
            if (ov < best || (ov == best && oi < bi)) { best = ov; bi = oi; }
        }
        if (lane == 0) bis[rl] = bi;
    }
    __syncthreads();

    // ---- phase F: gather ----
    {
        const int row  = tid >> 2;
        const int part = tid & 3;
        const int bi   = bis[row];
        const float4* src = reinterpret_cast<const float4*>(CB + (size_t)bi * 64) + part * 4;
        float* dst = OUT + (size_t)(bm + row) * 64 + part * 16;
        unsigned short* dq = ZQB + (size_t)(bm + row) * 64 + part * 16;
#pragma unroll
        for (int v = 0; v < 4; ++v) {
            float4 f = src[v];
            *reinterpret_cast<float4*>(dst + v * 4) = f;
            ushort4 qb = { f2bf(f.x), f2bf(f.y), f2bf(f.z), f2bf(f.w) };
            *reinterpret_cast<ushort4*>(dq + v * 4) = qb;
        }
    }
}

// ---------------------------------------------------------------------------
// bf16 MFMA GEMM (decoder) -- single-buffered (round-5 known-good).
// ---------------------------------------------------------------------------
template<bool RELU, bool OUT_BF16>
__global__ __launch_bounds__(256)
void gemm_mfma_bt(const unsigned short* __restrict__ A,
                  const unsigned short* __restrict__ Bt,
                  const float* __restrict__ bias,
                  void* __restrict__ Cv, int M, int N, int K)
{
    constexpr int BK  = 64;
    constexpr int LDP = BK + 8;

    __shared__ alignas(16) unsigned short Asl[128][LDP];
    __shared__ alignas(16) unsigned short Bsl[128][LDP];

    const int tid  = threadIdx.x;
    const int lane = tid & 63;
    const int w    = tid >> 6;
    const int wr   = (w >> 1) * 64;
    const int wc   = (w & 1) * 64;
    const int bm   = blockIdx.y * 128;
    const int bn   = blockIdx.x * 128;

    f32x4 acc[4][4];
#pragma unroll
    for (int m = 0; m < 4; ++m)
#pragma unroll
        for (int n = 0; n < 4; ++n) acc[m][n] = (f32x4){0.f, 0.f, 0.f, 0.f};

    const int sr = tid >> 1;
    const int sc = (tid & 1) * 32;

    for (int k0 = 0; k0 < K; k0 += BK) {
        {
            const float4* ga = reinterpret_cast<const float4*>(
                &A[(size_t)(bm + sr) * K + k0 + sc]);
            const float4* gb = reinterpret_cast<const float4*>(
                &Bt[(size_t)(bn + sr) * K + k0 + sc]);
            float4 va0 = ga[0], va1 = ga[1], va2 = ga[2], va3 = ga[3];
            float4 vb0 = gb[0], vb1 = gb[1], vb2 = gb[2], vb3 = gb[3];
            float4* da = reinterpret_cast<float4*>(&Asl[sr][sc]);
            float4* db = reinterpret_cast<float4*>(&Bsl[sr][sc]);
            da[0] = va0; da[1] = va1; da[2] = va2; da[3] = va3;
            db[0] = vb0; db[1] = vb1; db[2] = vb2; db[3] = vb3;
        }
        __syncthreads();

#pragma unroll
        for (int ks = 0; ks < 2; ++ks) {
            bf16x8 af[4], bf[4];
            const int kc = ks * 32 + (lane >> 4) * 8;
#pragma unroll
            for (int m = 0; m < 4; ++m)
                af[m] = *reinterpret_cast<const bf16x8*>(
                    &Asl[wr + m * 16 + (lane & 15)][kc]);
#pragma unroll
            for (int n = 0; n < 4; ++n)
                bf[n] = *reinterpret_cast<const bf16x8*>(
                    &Bsl[wc + n * 16 + (lane & 15)][kc]);
#pragma unroll
            for (int m = 0; m < 4; ++m)
#pragma unroll
                for (int n = 0; n < 4; ++n)
                    acc[m][n] = __builtin_amdgcn_mfma_f32_16x16x32_bf16(
                        af[m], bf[n], acc[m][n], 0, 0, 0);
        }
        __syncthreads();
    }

#pragma unroll
    for (int m = 0; m < 4; ++m)
#pragma unroll
        for (int n = 0; n < 4; ++n) {
            const int col = bn + wc + n * 16 + (lane & 15);
            const float bv = bias[col];
#pragma unroll
            for (int q = 0; q < 4; ++q) {
                const int row = bm + wr + m * 16 + (lane >> 4) * 4 + q;
                float v = acc[m][n][q] + bv;
                if (RELU) v = fmaxf(v, 0.f);
                if (OUT_BF16)
                    reinterpret_cast<unsigned short*>(Cv)[(size_t)row * N + col] = f2bf(v);
                else
                    reinterpret_cast<float*>(Cv)[(size_t)row * N + col] = v;
            }
        }
}

// ---------------------------------------------------------------------------
// small prep kernels
// ---------------------------------------------------------------------------
__global__ __launch_bounds__(256)
void transpose_bf16(const float* __restrict__ W, unsigned short* __restrict__ Wt,
                    int K, int N)
{
    int idx = blockIdx.x * 256 + threadIdx.x;
    if (idx >= K * N) return;
    int n = idx / K, k = idx % K;
    Wt[idx] = f2bf(W[(size_t)k * N + n]);
}

__global__ __launch_bounds__(256)
void transpose_split_f16(const float* __restrict__ W,
                         _Float16* __restrict__ Whi, _Float16* __restrict__ Wlo,
                         int K, int N)
{
    int idx = blockIdx.x * 256 + threadIdx.x;
    if (idx >= K * N) return;
    int n = idx / K, k = idx % K;
    _Float16 hi, lo; fsplit(W[(size_t)k * N + n], hi, lo);
    Whi[idx] = hi; Wlo[idx] = lo;
}

__global__ __launch_bounds__(256)
void split_flat_f16(const float* __restrict__ src,
                    _Float16* __restrict__ hi, _Float16* __restrict__ lo, int n)
{
    int i = blockIdx.x * 256 + threadIdx.x;
    if (i >= n) return;
    _Float16 h, l; fsplit(src[i], h, l);
    hi[i] = h; lo[i] = l;
}

// ---------------------------------------------------------------------------
extern "C" void kernel_launch(void* const* d_in, const int* in_sizes, int n_in,
                              void* d_out, int out_size, void* d_ws, size_t ws_size,
                              hipStream_t stream)
{
    const float* X  = (const float*)d_in[0];
    const float* W0 = (const float*)d_in[1];
    const float* b0 = (const float*)d_in[2];
    const float* W1 = (const float*)d_in[3];
    const float* b1 = (const float*)d_in[4];
    const float* W2 = (const float*)d_in[5];
    const float* b2 = (const float*)d_in[6];
    const float* CB = (const float*)d_in[7];
    const float* W3 = (const float*)d_in[8];
    const float* b3 = (const float*)d_in[9];
    const float* W4 = (const float*)d_in[10];
    const float* b4 = (const float*)d_in[11];
    const float* W5 = (const float*)d_in[12];
    const float* b5 = (const float*)d_in[13];

    const int D_in = 256, H = 512, R = 64, S = 512, NA = 8;
    const int Mtot = in_sizes[0] / D_in;          // 131072

    float* recon = (float*)d_out;
    float* ze    = recon + (size_t)(Mtot / NA) * S;
    float* remb  = ze + (size_t)Mtot * R;

    // ---- workspace: fixed weight planes ----
    char* p = (char*)d_ws;
    _Float16* W0hi = (_Float16*)p;  p += (size_t)H * D_in * 2;
    _Float16* W0lo = (_Float16*)p;  p += (size_t)H * D_in * 2;
    _Float16* W1hi = (_Float16*)p;  p += (size_t)H * H * 2;
    _Float16* W1lo = (_Float16*)p;  p += (size_t)H * H * 2;
    _Float16* W2thi = (_Float16*)p; p += (size_t)R * H * 2;        // [64][512]
    _Float16* W2tlo = (_Float16*)p; p += (size_t)R * H * 2;
    _Float16* CBhi = (_Float16*)p;  p += (size_t)256 * R * 2;      // [256][64]
    _Float16* CBlo = (_Float16*)p;  p += (size_t)256 * R * 2;
    unsigned short* W3t = (unsigned short*)p;  p += (size_t)H * R * 2;
    unsigned short* W4t = (unsigned short*)p;  p += (size_t)H * (NA * H) * 2;
    unsigned short* W5t = (unsigned short*)p;  p += (size_t)S * H * 2;
    size_t fixed = (size_t)(p - (char*)d_ws);
    fixed = (fixed + 255) & ~(size_t)255;

    // per-row chunk bytes: h0 pair 2048 + h1 pair 2048 + zqb 128
    int nc = 2;
    while (nc < 128) {
        size_t rpcT = (size_t)Mtot / nc;
        if (fixed + rpcT * 4224 + 1024 <= ws_size) break;
        nc *= 2;
    }
    const int rpc = Mtot / nc;
    char* q = (char*)d_ws + fixed;
    // h0hi/h0lo and h1hi/h1lo contiguous (split5 AF32=false uses Ahi + M*K)
    _Float16* h0hi = (_Float16*)q;                 q += (size_t)rpc * H * 2;
    _Float16* h0lo = (_Float16*)q;                 q += (size_t)rpc * H * 2;
    _Float16* h1hi = (_Float16*)q;                 q += (size_t)rpc * H * 2;
    _Float16* h1lo = (_Float16*)q;                 q += (size_t)rpc * H * 2;
    unsigned short* zqb = (unsigned short*)q;      q += (size_t)rpc * R * 2;
    unsigned short* rec1b = (unsigned short*)h0hi;     // alias (h0 dead after h1)
    unsigned short* rec2b = (unsigned short*)h1hi;     // alias (h1 dead after ze)

    // ---- one-time weight prep ----
    transpose_split_f16<<<(H * D_in + 255) / 256, 256, 0, stream>>>(W0, W0hi, W0lo, D_in, H);
    transpose_split_f16<<<(H * H + 255) / 256, 256, 0, stream>>>(W1, W1hi, W1lo, H, H);
    transpose_split_f16<<<(H * R + 255) / 256, 256, 0, stream>>>(W2, W2thi, W2tlo, H, R);
    split_flat_f16<<<(256 * R + 255) / 256, 256, 0, stream>>>(CB, CBhi, CBlo, 256 * R);
    transpose_bf16<<<(H * R + 255) / 256, 256, 0, stream>>>(W3, W3t, R, H);
    transpose_bf16<<<(H * NA * H + 255) / 256, 256, 0, stream>>>(W4, W4t, NA * H, H);
    transpose_bf16<<<(S * H + 255) / 256, 256, 0, stream>>>(W5, W5t, H, S);

    for (int r0 = 0; r0 < Mtot; r0 += rpc) {
        const int M6 = rpc / NA;
        // encoder: register-lean split-fp16 MFMA
        gemm_split5<256, true><<<dim3(H / 64, rpc / 128), 256, 0, stream>>>(
            X + (size_t)r0 * D_in, W0hi, W0lo, b0, h0hi, h0lo, rpc, H);
        gemm_split5<512, false><<<dim3(H / 64, rpc / 128), 256, 0, stream>>>(
            h0hi, W1hi, W1lo, b1, h1hi, h1lo, rpc, H);
        // z_e: split-fp16 MFMA, fp32 accum -> output zone 1
        gemm_ze_mfma<<<rpc / 128, 256, 0, stream>>>(
            h1hi, h1lo, W2thi, W2tlo, b2, ze + (size_t)r0 * R, rpc);
        // VQ via MFMA (fp32 filter + candidate-only fp64 re-check)
        vq_mfma<<<rpc / 128, 512, 0, stream>>>(
            ze + (size_t)r0 * R, CB, CBhi, CBlo,
            remb + (size_t)r0 * R, zqb);
        // decoder: bf16 MFMA
        gemm_mfma_bt<true, true><<<dim3(H / 128, rpc / 128), 256, 0, stream>>>(
            zqb, W3t, b3, rec1b, rpc, H, R);
        gemm_mfma_bt<true, true><<<dim3(H / 128, M6 / 128), 256, 0, stream>>>(
            rec1b, W4t, b4, rec2b, M6, H, NA * H);
        gemm_mfma_bt<false, false><<<dim3(S / 128, M6 / 128), 256, 0, stream>>>(
            rec2b, W5t, b5, recon + (size_t)(r0 / NA) * S, M6, S, H);
    }
}

// Round 12
// 981.850 us; speedup vs baseline: 1.8166x; 1.0545x over previous
//
#include <hip/hip_runtime.h>
#include <hip/hip_bf16.h>
#include <cstddef>

__device__ __forceinline__ unsigned short f2bf(float f) {
    union { float f; unsigned int u; } v; v.f = f;
    unsigned int r = (v.u + 0x7fffu + ((v.u >> 16) & 1u)) >> 16;   // RNE
    return (unsigned short)r;
}

typedef __bf16    bf16x8 __attribute__((ext_vector_type(8)));
typedef float     f32x4  __attribute__((ext_vector_type(4)));
typedef _Float16  f16x8  __attribute__((ext_vector_type(8)));

#define SPLIT_SCALE 2.44140625e-4f   // 2^-12

typedef const __attribute__((address_space(1))) void cglb_t;
typedef __attribute__((address_space(3))) void lds_t;

// fp32 -> fp16 (hi, lo*4096) split: hi + 2^-12*lo == v to ~2^-22 relative.
__device__ __forceinline__ void fsplit(float v, _Float16& hi, _Float16& lo) {
    hi = (_Float16)v;
    lo = (_Float16)((v - (float)hi) * 4096.0f);
}

// chunk swizzle for linear [row][32-f16] LDS tiles (row stride 64B = 4x16B):
// physical chunk = logical chunk ^ swz(row). Involution; makes 16-row b128
// fragment reads hit every bank-quad exactly twice per 16 lanes (uniform).
__device__ __forceinline__ int swz4(int r) { return (r & 3) ^ ((r >> 2) & 3); }

// ---------------------------------------------------------------------------
// Split-fp16 MFMA GEMM v7 (h1): C = relu(A @ Bt^T + bias), A/B hi-lo planes.
// m97 structure: A(128x32) and B(64x32) hi/lo tiles staged by
// global_load_lds (async DMA, zero VGPR), linear LDS + source/read chunk
// swizzle (rule 21), double-buffered, ONE barrier per K-step. 48KB LDS ->
// 3 blocks/CU; the barrier drain is covered by 12 waves' MFMA work.
// ---------------------------------------------------------------------------
template<int K>
__global__ __launch_bounds__(256, 3)
void gemm_split7(const _Float16* __restrict__ Ahi, const _Float16* __restrict__ Alo,
                 const _Float16* __restrict__ Bhi, const _Float16* __restrict__ Blo,
                 const float* __restrict__ bias,
                 _Float16* __restrict__ Chi, _Float16* __restrict__ Clo,
                 int M, int N)
{
    constexpr int BK = 32;
    constexpr int NS = K / BK;

    __shared__ alignas(16) _Float16 SA[2][2][128 * 32];   // [buf][pl] 8KB each
    __shared__ alignas(16) _Float16 SB[2][2][64 * 32];    // [buf][pl] 4KB each

    const int tid  = threadIdx.x;
    const int lane = tid & 63;
    const int w    = tid >> 6;                   // 0..3

    int bx = blockIdx.x, by = blockIdx.y;
    {
        const int gx = gridDim.x, nwg = gx * gridDim.y;
        if ((nwg & 7) == 0) {
            int d = bx + by * gx;
            int L = (d & 7) * (nwg >> 3) + (d >> 3);
            bx = L % gx; by = L / gx;
        }
    }
    const int bm = by * 128;
    const int bn = bx * 64;

    f32x4 acc0[2][4], acc1[2][4];
#pragma unroll
    for (int m = 0; m < 2; ++m)
#pragma unroll
        for (int n = 0; n < 4; ++n) {
            acc0[m][n] = (f32x4){0.f, 0.f, 0.f, 0.f};
            acc1[m][n] = (f32x4){0.f, 0.f, 0.f, 0.f};
        }

    // stage one K-step's tiles into buffer `buf` (async; completes at barrier)
    auto stage = [&](int buf, int k0) {
        // A planes: 512 chunks of 16B, 8 wave-issues; this wave does 2/plane
#pragma unroll
        for (int pl = 0; pl < 2; ++pl) {
            const _Float16* src = pl ? Alo : Ahi;
#pragma unroll
            for (int j = 0; j < 2; ++j) {
                const int p16 = (w * 2 + j) * 64 + lane;     // 0..511
                const int r   = p16 >> 2;
                const int c   = (p16 & 3) ^ swz4(r);
                const _Float16* g = src + (size_t)(bm + r) * K + k0 + c * 8;
                __builtin_amdgcn_global_load_lds((cglb_t*)g,
                    (lds_t*)&SA[buf][pl][p16 * 8], 16, 0, 0);
            }
            // B plane: 256 chunks, 4 wave-issues; this wave does 1
            const _Float16* srcB = pl ? Blo : Bhi;
            const int p16b = w * 64 + lane;                  // 0..255
            const int rb   = p16b >> 2;
            const int cb   = (p16b & 3) ^ swz4(rb);
            const _Float16* gB = srcB + (size_t)(bn + rb) * K + k0 + cb * 8;
            __builtin_amdgcn_global_load_lds((cglb_t*)gB,
                (lds_t*)&SB[buf][pl][p16b * 8], 16, 0, 0);
        }
    };

    stage(0, 0);
    __syncthreads();                              // drains DMA (vmcnt at barrier)

    const int g   = lane >> 4;                    // k chunk 0..3
    const int r15 = lane & 15;

#pragma unroll
    for (int s = 0; s < NS; ++s) {
        const int p = s & 1;
        if (s + 1 < NS) stage(p ^ 1, (s + 1) * BK);   // async into other buffer

        // A fragments from LDS (swizzled read)
        f16x8 ah[2], al[2];
#pragma unroll
        for (int m = 0; m < 2; ++m) {
            const int R = w * 32 + m * 16 + r15;
            const int a16 = R * 4 + (g ^ swz4(R));
            ah[m] = *reinterpret_cast<const f16x8*>(&SA[p][0][a16 * 8]);
            al[m] = *reinterpret_cast<const f16x8*>(&SA[p][1][a16 * 8]);
        }
#pragma unroll
        for (int n = 0; n < 4; ++n) {
            const int rB = n * 16 + r15;
            const int b16 = rB * 4 + (g ^ swz4(rB));
            const f16x8 bh = *reinterpret_cast<const f16x8*>(&SB[p][0][b16 * 8]);
            const f16x8 bl = *reinterpret_cast<const f16x8*>(&SB[p][1][b16 * 8]);
#pragma unroll
            for (int m = 0; m < 2; ++m)
                acc0[m][n] = __builtin_amdgcn_mfma_f32_16x16x32_f16(
                    ah[m], bh, acc0[m][n], 0, 0, 0);
#pragma unroll
            for (int m = 0; m < 2; ++m)
                acc1[m][n] = __builtin_amdgcn_mfma_f32_16x16x32_f16(
                    ah[m], bl, acc1[m][n], 0, 0, 0);
#pragma unroll
            for (int m = 0; m < 2; ++m)
                acc1[m][n] = __builtin_amdgcn_mfma_f32_16x16x32_f16(
                    al[m], bh, acc1[m][n], 0, 0, 0);
        }
        __syncthreads();          // all reads of buf p done; DMA for p^1 drained
    }

    // epilogue: combine, bias, relu, write fp16 pair planes
#pragma unroll
    for (int m = 0; m < 2; ++m)
#pragma unroll
        for (int n = 0; n < 4; ++n) {
            const int col = bn + n * 16 + r15;
            const float bv = bias[col];
#pragma unroll
            for (int q = 0; q < 4; ++q) {
                const int row = bm + w * 32 + m * 16 + (lane >> 4) * 4 + q;
                float v = acc0[m][n][q] + SPLIT_SCALE * acc1[m][n][q] + bv;
                v = fmaxf(v, 0.f);
                _Float16 hi, lo; fsplit(v, hi, lo);
                Chi[(size_t)row * N + col] = hi;
                Clo[(size_t)row * N + col] = lo;
            }
        }
}

// ---------------------------------------------------------------------------
// Split-fp16 MFMA GEMM v5 (h0: A = fp32 X, split in-register; reg staging).
// ---------------------------------------------------------------------------
template<int K, bool AF32>
__global__ __launch_bounds__(256, AF32 ? 3 : 4)
void gemm_split5(const void* __restrict__ Asrc,
                 const _Float16* __restrict__ Bhi, const _Float16* __restrict__ Blo,
                 const float* __restrict__ bias,
                 _Float16* __restrict__ Chi, _Float16* __restrict__ Clo,
                 int M, int N)
{
    constexpr int BK  = 32;
    constexpr int LDP = 40;                      // 80B row stride
    constexpr int NS  = K / BK;

    __shared__ alignas(16) _Float16 Bh[2][64][LDP];
    __shared__ alignas(16) _Float16 Bl[2][64][LDP];

    const int tid  = threadIdx.x;
    const int lane = tid & 63;
    const int w    = tid >> 6;

    int bx = blockIdx.x, by = blockIdx.y;
    {
        const int gx = gridDim.x, nwg = gx * gridDim.y;
        if ((nwg & 7) == 0) {
            int d = bx + by * gx;
            int L = (d & 7) * (nwg >> 3) + (d >> 3);
            bx = L % gx; by = L / gx;
        }
    }
    const int bm = by * 128;
    const int bn = bx * 64;

    f32x4 acc0[2][4], acc1[2][4];
#pragma unroll
    for (int m = 0; m < 2; ++m)
#pragma unroll
        for (int n = 0; n < 4; ++n) {
            acc0[m][n] = (f32x4){0.f, 0.f, 0.f, 0.f};
            acc1[m][n] = (f32x4){0.f, 0.f, 0.f, 0.f};
        }

    const int arow = bm + w * 32 + (lane & 15);
    const int kgrp = (lane >> 4) * 8;
    const int brow = tid >> 2;
    const int bcol = (tid & 3) * 8;

    const _Float16* Ahi_ = (const _Float16*)Asrc;
    const float*    Af_  = (const float*)Asrc;

    f16x8 ah[2], al[2], ahn[2], aln[2];
    float4 rbh, rbl;

    auto loadB = [&](int k0) {
        const size_t gb = (size_t)(bn + brow) * K + k0 + bcol;
        rbh = *reinterpret_cast<const float4*>(Bhi + gb);
        rbl = *reinterpret_cast<const float4*>(Blo + gb);
    };
    auto storeB = [&](int p) {
        *reinterpret_cast<float4*>(&Bh[p][brow][bcol]) = rbh;
        *reinterpret_cast<float4*>(&Bl[p][brow][bcol]) = rbl;
    };
    auto loadA = [&](int k0, f16x8* h, f16x8* l) {
#pragma unroll
        for (int m = 0; m < 2; ++m) {
            const size_t ga = (size_t)(arow + m * 16) * K + k0 + kgrp;
            if constexpr (AF32) {
                float4 v0 = *reinterpret_cast<const float4*>(Af_ + ga);
                float4 v1 = *reinterpret_cast<const float4*>(Af_ + ga + 4);
                float vv[8] = {v0.x, v0.y, v0.z, v0.w, v1.x, v1.y, v1.z, v1.w};
                f16x8 hh, ll;
#pragma unroll
                for (int j = 0; j < 8; ++j) {
                    _Float16 hi, lo; fsplit(vv[j], hi, lo);
                    hh[j] = hi; ll[j] = lo;
                }
                h[m] = hh; l[m] = ll;
            } else {
                h[m] = *reinterpret_cast<const f16x8*>(Ahi_ + ga);
                l[m] = *reinterpret_cast<const f16x8*>(Ahi_ + (size_t)M * K + ga);
            }
        }
    };

    loadB(0);
    loadA(0, ah, al);
    storeB(0);
    __syncthreads();

#pragma unroll
    for (int s = 0; s < NS; ++s) {
        const int p = s & 1;
        if (s + 1 < NS) {
            loadB((s + 1) * BK);
            loadA((s + 1) * BK, ahn, aln);
        }
#pragma unroll
        for (int n = 0; n < 4; ++n) {
            const f16x8 bh = *reinterpret_cast<const f16x8*>(
                &Bh[p][n * 16 + (lane & 15)][kgrp]);
            const f16x8 bl = *reinterpret_cast<const f16x8*>(
                &Bl[p][n * 16 + (lane & 15)][kgrp]);
#pragma unroll
            for (int m = 0; m < 2; ++m)
                acc0[m][n] = __builtin_amdgcn_mfma_f32_16x16x32_f16(
                    ah[m], bh, acc0[m][n], 0, 0, 0);
#pragma unroll
            for (int m = 0; m < 2; ++m)
                acc1[m][n] = __builtin_amdgcn_mfma_f32_16x16x32_f16(
                    ah[m], bl, acc1[m][n], 0, 0, 0);
#pragma unroll
            for (int m = 0; m < 2; ++m)
                acc1[m][n] = __builtin_amdgcn_mfma_f32_16x16x32_f16(
                    al[m], bh, acc1[m][n], 0, 0, 0);
        }
        if (s + 1 < NS) {
            storeB(p ^ 1);
#pragma unroll
            for (int m = 0; m < 2; ++m) { ah[m] = ahn[m]; al[m] = aln[m]; }
        }
        __syncthreads();
    }

#pragma unroll
    for (int m = 0; m < 2; ++m)
#pragma unroll
        for (int n = 0; n < 4; ++n) {
            const int col = bn + n * 16 + (lane & 15);
            const float bv = bias[col];
#pragma unroll
            for (int q = 0; q < 4; ++q) {
                const int row = bm + w * 32 + m * 16 + (lane >> 4) * 4 + q;
                float v = acc0[m][n][q] + SPLIT_SCALE * acc1[m][n][q] + bv;
                v = fmaxf(v, 0.f);
                _Float16 hi, lo; fsplit(v, hi, lo);
                Chi[(size_t)row * N + col] = hi;
                Clo[(size_t)row * N + col] = lo;
            }
        }
}

// ---------------------------------------------------------------------------
// z_e GEMM via split-fp16 MFMA: ze[M,64] = h1 @ W2 + b2, fp32 accumulation.
// ---------------------------------------------------------------------------
__global__ __launch_bounds__(256)
void gemm_ze_mfma(const _Float16* __restrict__ Ahi, const _Float16* __restrict__ Alo,
                  const _Float16* __restrict__ Bhi, const _Float16* __restrict__ Blo,
                  const float* __restrict__ bias, float* __restrict__ C, int M)
{
    constexpr int K = 512, N = 64;
    const int tid  = threadIdx.x;
    const int lane = tid & 63;
    const int w    = tid >> 6;
    const int wr   = (w >> 1) * 64;
    const int wc   = (w & 1) * 32;
    const int bm   = blockIdx.x * 128;

    f32x4 acc0[4][2], acc1[4][2];
#pragma unroll
    for (int m = 0; m < 4; ++m)
#pragma unroll
        for (int n = 0; n < 2; ++n) {
            acc0[m][n] = (f32x4){0.f, 0.f, 0.f, 0.f};
            acc1[m][n] = (f32x4){0.f, 0.f, 0.f, 0.f};
        }

    const int arow = bm + wr + (lane & 15);
    const int kgrp = (lane >> 4) * 8;

#pragma unroll
    for (int ks = 0; ks < K / 32; ++ks) {
        const int k0 = ks * 32 + kgrp;
        f16x8 ah[4], al[4];
#pragma unroll
        for (int m = 0; m < 4; ++m) {
            const size_t ga = (size_t)(arow + m * 16) * K + k0;
            ah[m] = *reinterpret_cast<const f16x8*>(Ahi + ga);
            al[m] = *reinterpret_cast<const f16x8*>(Alo + ga);
        }
#pragma unroll
        for (int n = 0; n < 2; ++n) {
            const size_t gb = (size_t)(wc + n * 16 + (lane & 15)) * K + k0;
            const f16x8 bh = *reinterpret_cast<const f16x8*>(Bhi + gb);
            const f16x8 bl = *reinterpret_cast<const f16x8*>(Blo + gb);
#pragma unroll
            for (int m = 0; m < 4; ++m)
                acc0[m][n] = __builtin_amdgcn_mfma_f32_16x16x32_f16(
                    ah[m], bh, acc0[m][n], 0, 0, 0);
#pragma unroll
            for (int m = 0; m < 4; ++m)
                acc1[m][n] = __builtin_amdgcn_mfma_f32_16x16x32_f16(
                    ah[m], bl, acc1[m][n], 0, 0, 0);
#pragma unroll
            for (int m = 0; m < 4; ++m)
                acc1[m][n] = __builtin_amdgcn_mfma_f32_16x16x32_f16(
                    al[m], bh, acc1[m][n], 0, 0, 0);
        }
    }

#pragma unroll
    for (int m = 0; m < 4; ++m)
#pragma unroll
        for (int n = 0; n < 2; ++n) {
            const int col = wc + n * 16 + (lane & 15);
            const float bv = bias[col];
#pragma unroll
            for (int q = 0; q < 4; ++q) {
                const int row = bm + wr + m * 16 + (lane >> 4) * 4 + q;
                C[(size_t)row * N + col] = acc0[m][n][q] + SPLIT_SCALE * acc1[m][n][q] + bv;
            }
        }
}

// ---------------------------------------------------------------------------
// VQ via MFMA: fp32 d2 filter -> candidate-only exact fp64 re-check.
// ---------------------------------------------------------------------------
#define VQ_EPS 1e-3f
__global__ __launch_bounds__(512)
void vq_mfma(const float* __restrict__ Z, const float* __restrict__ CB,
             const _Float16* __restrict__ Chi, const _Float16* __restrict__ Clo,
             float* __restrict__ OUT, unsigned short* __restrict__ ZQB)
{
    __shared__ float  ccf[256];
    __shared__ double ccd[256];
    __shared__ float  xxf[128];
    __shared__ double xxd[128];
    __shared__ float  redv[4][128];
    __shared__ int    redi[4][128];
    __shared__ float  bv1s[128];
    __shared__ int    bis[128];
    __shared__ int    cand[128][16];
    __shared__ int    ncand[128];
    __shared__ int    fullflag[128];
    __shared__ int    flaglist[128];
    __shared__ int    nflag;

    const int tid  = threadIdx.x;
    const int lane = tid & 63;
    const int w    = tid >> 6;
    const int wr   = (w >> 2) * 64;
    const int wc   = (w & 3) * 64;
    const int bm   = blockIdx.x * 128;

    if (tid == 0) nflag = 0;
    if (tid < 256) {
        const float4* c4 = reinterpret_cast<const float4*>(CB + (size_t)tid * 64);
        double cc = 0.0;
#pragma unroll
        for (int v = 0; v < 16; ++v) {
            float4 f = c4[v];
            cc = fma((double)f.x, (double)f.x, cc);
            cc = fma((double)f.y, (double)f.y, cc);
            cc = fma((double)f.z, (double)f.z, cc);
            cc = fma((double)f.w, (double)f.w, cc);
        }
        ccd[tid] = cc; ccf[tid] = (float)cc;
    }
    if (tid < 128) {
        const float4* z4 = reinterpret_cast<const float4*>(Z + (size_t)(bm + tid) * 64);
        double xx = 0.0;
#pragma unroll
        for (int v = 0; v < 16; ++v) {
            float4 f = z4[v];
            xx = fma((double)f.x, (double)f.x, xx);
            xx = fma((double)f.y, (double)f.y, xx);
            xx = fma((double)f.z, (double)f.z, xx);
            xx = fma((double)f.w, (double)f.w, xx);
        }
        xxd[tid] = xx; xxf[tid] = (float)xx;
        ncand[tid] = 0; fullflag[tid] = 0;
    }
    __syncthreads();

    f32x4 acc0[4][4], acc1[4][4];
#pragma unroll
    for (int m = 0; m < 4; ++m)
#pragma unroll
        for (int n = 0; n < 4; ++n) {
            acc0[m][n] = (f32x4){0.f, 0.f, 0.f, 0.f};
            acc1[m][n] = (f32x4){0.f, 0.f, 0.f, 0.f};
        }

    const int arow = bm + wr + (lane & 15);
    const int kgrp = (lane >> 4) * 8;

#pragma unroll
    for (int ks = 0; ks < 2; ++ks) {
        const int k0 = ks * 32 + kgrp;
        f16x8 ah[4], al[4];
#pragma unroll
        for (int m = 0; m < 4; ++m) {
            const float* src = Z + (size_t)(arow + m * 16) * 64 + k0;
            float4 v0 = *reinterpret_cast<const float4*>(src);
            float4 v1 = *reinterpret_cast<const float4*>(src + 4);
            float vv[8] = {v0.x, v0.y, v0.z, v0.w, v1.x, v1.y, v1.z, v1.w};
            f16x8 hh, ll;
#pragma unroll
            for (int j = 0; j < 8; ++j) {
                _Float16 hi, lo; fsplit(vv[j], hi, lo);
                hh[j] = hi; ll[j] = lo;
            }
            ah[m] = hh; al[m] = ll;
        }
#pragma unroll
        for (int n = 0; n < 4; ++n) {
            const size_t gb = (size_t)(wc + n * 16 + (lane & 15)) * 64 + k0;
            const f16x8 bh = *reinterpret_cast<const f16x8*>(Chi + gb);
            const f16x8 bl = *reinterpret_cast<const f16x8*>(Clo + gb);
#pragma unroll
            for (int m = 0; m < 4; ++m)
                acc0[m][n] = __builtin_amdgcn_mfma_f32_16x16x32_f16(
                    ah[m], bh, acc0[m][n], 0, 0, 0);
#pragma unroll
            for (int m = 0; m < 4; ++m)
                acc1[m][n] = __builtin_amdgcn_mfma_f32_16x16x32_f16(
                    ah[m], bl, acc1[m][n], 0, 0, 0);
#pragma unroll
            for (int m = 0; m < 4; ++m)
                acc1[m][n] = __builtin_amdgcn_mfma_f32_16x16x32_f16(
                    al[m], bh, acc1[m][n], 0, 0, 0);
        }
    }

#pragma unroll
    for (int m = 0; m < 4; ++m)
#pragma unroll
        for (int n = 0; n < 4; ++n) {
            const int col = wc + n * 16 + (lane & 15);
            const float cf = ccf[col];
#pragma unroll
            for (int q = 0; q < 4; ++q) {
                const int rl = wr + m * 16 + (lane >> 4) * 4 + q;
                float dot = acc0[m][n][q] + SPLIT_SCALE * acc1[m][n][q];
                acc0[m][n][q] = (xxf[rl] - 2.0f * dot) + cf;
            }
        }

    float bvr[4][4]; int bir[4][4];
#pragma unroll
    for (int m = 0; m < 4; ++m)
#pragma unroll
        for (int q = 0; q < 4; ++q) {
            float bv = 3.4e38f; int bi = 0;
#pragma unroll
            for (int n = 0; n < 4; ++n) {
                const int col = wc + n * 16 + (lane & 15);
                const float v = acc0[m][n][q];
                if (v < bv || (v == bv && col < bi)) { bv = v; bi = col; }
            }
            bvr[m][q] = bv; bir[m][q] = bi;
        }
#pragma unroll
    for (int mask = 1; mask < 16; mask <<= 1) {
#pragma unroll
        for (int m = 0; m < 4; ++m)
#pragma unroll
            for (int q = 0; q < 4; ++q) {
                float ov = __shfl_xor(bvr[m][q], mask);
                int   oi = __shfl_xor(bir[m][q], mask);
                if (ov < bvr[m][q] || (ov == bvr[m][q] && oi < bir[m][q])) {
                    bvr[m][q] = ov; bir[m][q] = oi;
                }
            }
    }
    if ((lane & 15) == 0) {
#pragma unroll
        for (int m = 0; m < 4; ++m)
#pragma unroll
            for (int q = 0; q < 4; ++q) {
                const int rl = wr + m * 16 + (lane >> 4) * 4 + q;
                redv[w & 3][rl] = bvr[m][q];
                redi[w & 3][rl] = bir[m][q];
            }
    }
    __syncthreads();

    if (tid < 128) {
        float bv = 3.4e38f; int bi = 0;
#pragma unroll
        for (int nw = 0; nw < 4; ++nw) {
            float v = redv[nw][tid];
            if (v < bv) { bv = v; bi = redi[nw][tid]; }
        }
        bv1s[tid] = bv; bis[tid] = bi;
    }
    __syncthreads();

#pragma unroll
    for (int m = 0; m < 4; ++m)
#pragma unroll
        for (int q = 0; q < 4; ++q) {
            const int rl = wr + m * 16 + (lane >> 4) * 4 + q;
            const float thr = bv1s[rl] + VQ_EPS;
#pragma unroll
            for (int n = 0; n < 4; ++n) {
                const int col = wc + n * 16 + (lane & 15);
                if (acc0[m][n][q] <= thr) {
                    int s = atomicAdd(&ncand[rl], 1);
                    if (s < 16) cand[rl][s] = col;
                    else        fullflag[rl] = 1;
                }
            }
        }
    __syncthreads();

    if (tid < 128) {
        const int nc_ = ncand[tid] < 16 ? ncand[tid] : 16;
        if (nc_ > 1 && !fullflag[tid]) {
            const float4* z4p = reinterpret_cast<const float4*>(Z + (size_t)(bm + tid) * 64);
            const double xx = xxd[tid];
            double best = 1.0e300; int bi = 256;
            for (int s = 0; s < nc_; ++s) {
                const int e = cand[tid][s];
                const float4* c4p = reinterpret_cast<const float4*>(CB + (size_t)e * 64);
                double dot = 0.0;
#pragma unroll
                for (int v = 0; v < 16; ++v) {
                    float4 zf = z4p[v], cf4 = c4p[v];
                    dot = fma((double)zf.x, (double)cf4.x, dot);
                    dot = fma((double)zf.y, (double)cf4.y, dot);
                    dot = fma((double)zf.z, (double)cf4.z, dot);
                    dot = fma((double)zf.w, (double)cf4.w, dot);
                }
                double d2x = (xx - 2.0 * dot) + ccd[e];
                if (d2x < best || (d2x == best && e < bi)) { best = d2x; bi = e; }
            }
            bis[tid] = bi;
        }
        if (fullflag[tid]) {
            int s = atomicAdd(&nflag, 1);
            flaglist[s] = tid;
        }
    }
    __syncthreads();

    for (int fi = w; fi < nflag; fi += 8) {
        const int rl = flaglist[fi];
        const float* zr = Z + (size_t)(bm + rl) * 64;
        const double xx = xxd[rl];
        double best = 1.0e300; int bi = 256;
#pragma unroll
        for (int j = 0; j < 4; ++j) {
            const int e = lane + j * 64;
            const float* c = CB + (size_t)e * 64;
            double dot = 0.0;
#pragma unroll
            for (int d = 0; d < 64; ++d)
                dot = fma((double)zr[d], (double)c[d], dot);
            double d2x = (xx - 2.0 * dot) + ccd[e];
            if (d2x < best || (d2x == best && e < bi)) { best = d2x; bi = e; }
        }
#pragma unroll
        for (int mask = 1; mask < 64; mask <<= 1) {
            double ov = __shfl_xor(best, mask);
            int    oi = __shfl_xor(bi, mask);
            if (ov < best || (ov == best && oi < bi)) { best = ov; bi = oi; }
        }
        if (lane == 0) bis[rl] = bi;
    }
    __syncthreads();

    {
        const int row  = tid >> 2;
        const int part = tid & 3;
        const int bi   = bis[row];
        const float4* src = reinterpret_cast<const float4*>(CB + (size_t)bi * 64) + part * 4;
        float* dst = OUT + (size_t)(bm + row) * 64 + part * 16;
        unsigned short* dq = ZQB + (size_t)(bm + row) * 64 + part * 16;
#pragma unroll
        for (int v = 0; v < 4; ++v) {
            float4 f = src[v];
            *reinterpret_cast<float4*>(dst + v * 4) = f;
            ushort4 qb = { f2bf(f.x), f2bf(f.y), f2bf(f.z), f2bf(f.w) };
            *reinterpret_cast<ushort4*>(dq + v * 4) = qb;
        }
    }
}

// ---------------------------------------------------------------------------
// bf16 MFMA GEMM (decoder) -- single-buffered (round-5 known-good).
// ---------------------------------------------------------------------------
template<bool RELU, bool OUT_BF16>
__global__ __launch_bounds__(256)
void gemm_mfma_bt(const unsigned short* __restrict__ A,
                  const unsigned short* __restrict__ Bt,
                  const float* __restrict__ bias,
                  void* __restrict__ Cv, int M, int N, int K)
{
    constexpr int BK  = 64;
    constexpr int LDP = BK + 8;

    __shared__ alignas(16) unsigned short Asl[128][LDP];
    __shared__ alignas(16) unsigned short Bsl[128][LDP];

    const int tid  = threadIdx.x;
    const int lane = tid & 63;
    const int w    = tid >> 6;
    const int wr   = (w >> 1) * 64;
    const int wc   = (w & 1) * 64;
    const int bm   = blockIdx.y * 128;
    const int bn   = blockIdx.x * 128;

    f32x4 acc[4][4];
#pragma unroll
    for (int m = 0; m < 4; ++m)
#pragma unroll
        for (int n = 0; n < 4; ++n) acc[m][n] = (f32x4){0.f, 0.f, 0.f, 0.f};

    const int sr = tid >> 1;
    const int sc = (tid & 1) * 32;

    for (int k0 = 0; k0 < K; k0 += BK) {
        {
            const float4* ga = reinterpret_cast<const float4*>(
                &A[(size_t)(bm + sr) * K + k0 + sc]);
            const float4* gb = reinterpret_cast<const float4*>(
                &Bt[(size_t)(bn + sr) * K + k0 + sc]);
            float4 va0 = ga[0], va1 = ga[1], va2 = ga[2], va3 = ga[3];
            float4 vb0 = gb[0], vb1 = gb[1], vb2 = gb[2], vb3 = gb[3];
            float4* da = reinterpret_cast<float4*>(&Asl[sr][sc]);
            float4* db = reinterpret_cast<float4*>(&Bsl[sr][sc]);
            da[0] = va0; da[1] = va1; da[2] = va2; da[3] = va3;
            db[0] = vb0; db[1] = vb1; db[2] = vb2; db[3] = vb3;
        }
        __syncthreads();

#pragma unroll
        for (int ks = 0; ks < 2; ++ks) {
            bf16x8 af[4], bf[4];
            const int kc = ks * 32 + (lane >> 4) * 8;
#pragma unroll
            for (int m = 0; m < 4; ++m)
                af[m] = *reinterpret_cast<const bf16x8*>(
                    &Asl[wr + m * 16 + (lane & 15)][kc]);
#pragma unroll
            for (int n = 0; n < 4; ++n)
                bf[n] = *reinterpret_cast<const bf16x8*>(
                    &Bsl[wc + n * 16 + (lane & 15)][kc]);
#pragma unroll
            for (int m = 0; m < 4; ++m)
#pragma unroll
                for (int n = 0; n < 4; ++n)
                    acc[m][n] = __builtin_amdgcn_mfma_f32_16x16x32_bf16(
                        af[m], bf[n], acc[m][n], 0, 0, 0);
        }
        __syncthreads();
    }

#pragma unroll
    for (int m = 0; m < 4; ++m)
#pragma unroll
        for (int n = 0; n < 4; ++n) {
            const int col = bn + wc + n * 16 + (lane & 15);
            const float bv = bias[col];
#pragma unroll
            for (int q = 0; q < 4; ++q) {
                const int row = bm + wr + m * 16 + (lane >> 4) * 4 + q;
                float v = acc[m][n][q] + bv;
                if (RELU) v = fmaxf(v, 0.f);
                if (OUT_BF16)
                    reinterpret_cast<unsigned short*>(Cv)[(size_t)row * N + col] = f2bf(v);
                else
                    reinterpret_cast<float*>(Cv)[(size_t)row * N + col] = v;
            }
        }
}

// ---------------------------------------------------------------------------
// small prep kernels
// ---------------------------------------------------------------------------
__global__ __launch_bounds__(256)
void transpose_bf16(const float* __restrict__ W, unsigned short* __restrict__ Wt,
                    int K, int N)
{
    int idx = blockIdx.x * 256 + threadIdx.x;
    if (idx >= K * N) return;
    int n = idx / K, k = idx % K;
    Wt[idx] = f2bf(W[(size_t)k * N + n]);
}

__global__ __launch_bounds__(256)
void transpose_split_f16(const float* __restrict__ W,
                         _Float16* __restrict__ Whi, _Float16* __restrict__ Wlo,
                         int K, int N)
{
    int idx = blockIdx.x * 256 + threadIdx.x;
    if (idx >= K * N) return;
    int n = idx / K, k = idx % K;
    _Float16 hi, lo; fsplit(W[(size_t)k * N + n], hi, lo);
    Whi[idx] = hi; Wlo[idx] = lo;
}

__global__ __launch_bounds__(256)
void split_flat_f16(const float* __restrict__ src,
                    _Float16* __restrict__ hi, _Float16* __restrict__ lo, int n)
{
    int i = blockIdx.x * 256 + threadIdx.x;
    if (i >= n) return;
    _Float16 h, l; fsplit(src[i], h, l);
    hi[i] = h; lo[i] = l;
}

// ---------------------------------------------------------------------------
extern "C" void kernel_launch(void* const* d_in, const int* in_sizes, int n_in,
                              void* d_out, int out_size, void* d_ws, size_t ws_size,
                              hipStream_t stream)
{
    const float* X  = (const float*)d_in[0];
    const float* W0 = (const float*)d_in[1];
    const float* b0 = (const float*)d_in[2];
    const float* W1 = (const float*)d_in[3];
    const float* b1 = (const float*)d_in[4];
    const float* W2 = (const float*)d_in[5];
    const float* b2 = (const float*)d_in[6];
    const float* CB = (const float*)d_in[7];
    const float* W3 = (const float*)d_in[8];
    const float* b3 = (const float*)d_in[9];
    const float* W4 = (const float*)d_in[10];
    const float* b4 = (const float*)d_in[11];
    const float* W5 = (const float*)d_in[12];
    const float* b5 = (const float*)d_in[13];

    const int D_in = 256, H = 512, R = 64, S = 512, NA = 8;
    const int Mtot = in_sizes[0] / D_in;          // 131072

    float* recon = (float*)d_out;
    float* ze    = recon + (size_t)(Mtot / NA) * S;
    float* remb  = ze + (size_t)Mtot * R;

    // ---- workspace: fixed weight planes ----
    char* p = (char*)d_ws;
    _Float16* W0hi = (_Float16*)p;  p += (size_t)H * D_in * 2;
    _Float16* W0lo = (_Float16*)p;  p += (size_t)H * D_in * 2;
    _Float16* W1hi = (_Float16*)p;  p += (size_t)H * H * 2;
    _Float16* W1lo = (_Float16*)p;  p += (size_t)H * H * 2;
    _Float16* W2thi = (_Float16*)p; p += (size_t)R * H * 2;
    _Float16* W2tlo = (_Float16*)p; p += (size_t)R * H * 2;
    _Float16* CBhi = (_Float16*)p;  p += (size_t)256 * R * 2;
    _Float16* CBlo = (_Float16*)p;  p += (size_t)256 * R * 2;
    unsigned short* W3t = (unsigned short*)p;  p += (size_t)H * R * 2;
    unsigned short* W4t = (unsigned short*)p;  p += (size_t)H * (NA * H) * 2;
    unsigned short* W5t = (unsigned short*)p;  p += (size_t)S * H * 2;
    size_t fixed = (size_t)(p - (char*)d_ws);
    fixed = (fixed + 255) & ~(size_t)255;

    int nc = 2;
    while (nc < 128) {
        size_t rpcT = (size_t)Mtot / nc;
        if (fixed + rpcT * 4224 + 1024 <= ws_size) break;
        nc *= 2;
    }
    const int rpc = Mtot / nc;
    char* q = (char*)d_ws + fixed;
    _Float16* h0hi = (_Float16*)q;                 q += (size_t)rpc * H * 2;
    _Float16* h0lo = (_Float16*)q;                 q += (size_t)rpc * H * 2;
    _Float16* h1hi = (_Float16*)q;                 q += (size_t)rpc * H * 2;
    _Float16* h1lo = (_Float16*)q;                 q += (size_t)rpc * H * 2;
    unsigned short* zqb = (unsigned short*)q;      q += (size_t)rpc * R * 2;
    unsigned short* rec1b = (unsigned short*)h0hi;     // alias (h0 dead after h1)
    unsigned short* rec2b = (unsigned short*)h1hi;     // alias (h1 dead after ze)

    // ---- one-time weight prep ----
    transpose_split_f16<<<(H * D_in + 255) / 256, 256, 0, stream>>>(W0, W0hi, W0lo, D_in, H);
    transpose_split_f16<<<(H * H + 255) / 256, 256, 0, stream>>>(W1, W1hi, W1lo, H, H);
    transpose_split_f16<<<(H * R + 255) / 256, 256, 0, stream>>>(W2, W2thi, W2tlo, H, R);
    split_flat_f16<<<(256 * R + 255) / 256, 256, 0, stream>>>(CB, CBhi, CBlo, 256 * R);
    transpose_bf16<<<(H * R + 255) / 256, 256, 0, stream>>>(W3, W3t, R, H);
    transpose_bf16<<<(H * NA * H + 255) / 256, 256, 0, stream>>>(W4, W4t, NA * H, H);
    transpose_bf16<<<(S * H + 255) / 256, 256, 0, stream>>>(W5, W5t, H, S);

    for (int r0 = 0; r0 < Mtot; r0 += rpc) {
        const int M6 = rpc / NA;
        // h0: reg-staged split (A = fp32 X, in-register split)
        gemm_split5<256, true><<<dim3(H / 64, rpc / 128), 256, 0, stream>>>(
            X + (size_t)r0 * D_in, W0hi, W0lo, b0, h0hi, h0lo, rpc, H);
        // h1: global_load_lds-staged split (m97 structure, swizzled linear LDS)
        gemm_split7<512><<<dim3(H / 64, rpc / 128), 256, 0, stream>>>(
            h0hi, h0lo, W1hi, W1lo, b1, h1hi, h1lo, rpc, H);
        // z_e: split-fp16 MFMA, fp32 accum -> output zone 1
        gemm_ze_mfma<<<rpc / 128, 256, 0, stream>>>(
            h1hi, h1lo, W2thi, W2tlo, b2, ze + (size_t)r0 * R, rpc);
        // VQ (fp32 filter + candidate-only fp64 re-check)
        vq_mfma<<<rpc / 128, 512, 0, stream>>>(
            ze + (size_t)r0 * R, CB, CBhi, CBlo,
            remb + (size_t)r0 * R, zqb);
        // decoder: bf16 MFMA
        gemm_mfma_bt<true, true><<<dim3(H / 128, rpc / 128), 256, 0, stream>>>(
            zqb, W3t, b3, rec1b, rpc, H, R);
        gemm_mfma_bt<true, true><<<dim3(H / 128, M6 / 128), 256, 0, stream>>>(
            rec1b, W4t, b4, rec2b, M6, H, NA * H);
        gemm_mfma_bt<false, false><<<dim3(S / 128, M6 / 128), 256, 0, stream>>>(
            rec2b, W5t, b5, recon + (size_t)(r0 / NA) * S, M6, S, H);
    }
}

// Round 13
// 945.770 us; speedup vs baseline: 1.8859x; 1.0381x over previous
//
#include <hip/hip_runtime.h>
#include <hip/hip_bf16.h>
#include <cstddef>

__device__ __forceinline__ unsigned short f2bf(float f) {
    union { float f; unsigned int u; } v; v.f = f;
    unsigned int r = (v.u + 0x7fffu + ((v.u >> 16) & 1u)) >> 16;   // RNE
    return (unsigned short)r;
}

typedef __bf16    bf16x8 __attribute__((ext_vector_type(8)));
typedef float     f32x4  __attribute__((ext_vector_type(4)));
typedef _Float16  f16x8  __attribute__((ext_vector_type(8)));

#define SPLIT_SCALE 2.44140625e-4f   // 2^-12

typedef const __attribute__((address_space(1))) void cglb_t;
typedef __attribute__((address_space(3))) void lds_t;

// fp32 -> fp16 (hi, lo*4096) split: hi + 2^-12*lo == v to ~2^-22 relative.
__device__ __forceinline__ void fsplit(float v, _Float16& hi, _Float16& lo) {
    hi = (_Float16)v;
    lo = (_Float16)((v - (float)hi) * 4096.0f);
}

// chunk swizzle for linear [row][32-elem] LDS tiles (row = 4 x 16B chunks):
// physical chunk = logical chunk ^ swz4(row). Involution; uniform bank-quads.
__device__ __forceinline__ int swz4(int r) { return (r & 3) ^ ((r >> 2) & 3); }

// ---------------------------------------------------------------------------
// Split-fp16 MFMA GEMM v7 (h1): global_load_lds staging, swizzled linear LDS,
// double-buffered, one barrier per K-step. 48KB LDS, ~68 VGPR.
// ---------------------------------------------------------------------------
template<int K>
__global__ __launch_bounds__(256, 3)
void gemm_split7(const _Float16* __restrict__ Ahi, const _Float16* __restrict__ Alo,
                 const _Float16* __restrict__ Bhi, const _Float16* __restrict__ Blo,
                 const float* __restrict__ bias,
                 _Float16* __restrict__ Chi, _Float16* __restrict__ Clo,
                 int M, int N)
{
    constexpr int BK = 32;
    constexpr int NS = K / BK;

    __shared__ alignas(16) _Float16 SA[2][2][128 * 32];
    __shared__ alignas(16) _Float16 SB[2][2][64 * 32];

    const int tid  = threadIdx.x;
    const int lane = tid & 63;
    const int w    = tid >> 6;

    int bx = blockIdx.x, by = blockIdx.y;
    {
        const int gx = gridDim.x, nwg = gx * gridDim.y;
        if ((nwg & 7) == 0) {
            int d = bx + by * gx;
            int L = (d & 7) * (nwg >> 3) + (d >> 3);
            bx = L % gx; by = L / gx;
        }
    }
    const int bm = by * 128;
    const int bn = bx * 64;

    f32x4 acc0[2][4], acc1[2][4];
#pragma unroll
    for (int m = 0; m < 2; ++m)
#pragma unroll
        for (int n = 0; n < 4; ++n) {
            acc0[m][n] = (f32x4){0.f, 0.f, 0.f, 0.f};
            acc1[m][n] = (f32x4){0.f, 0.f, 0.f, 0.f};
        }

    auto stage = [&](int buf, int k0) {
#pragma unroll
        for (int pl = 0; pl < 2; ++pl) {
            const _Float16* src = pl ? Alo : Ahi;
#pragma unroll
            for (int j = 0; j < 2; ++j) {
                const int p16 = (w * 2 + j) * 64 + lane;
                const int r   = p16 >> 2;
                const int c   = (p16 & 3) ^ swz4(r);
                const _Float16* g = src + (size_t)(bm + r) * K + k0 + c * 8;
                __builtin_amdgcn_global_load_lds((cglb_t*)g,
                    (lds_t*)&SA[buf][pl][p16 * 8], 16, 0, 0);
            }
            const _Float16* srcB = pl ? Blo : Bhi;
            const int p16b = w * 64 + lane;
            const int rb   = p16b >> 2;
            const int cb   = (p16b & 3) ^ swz4(rb);
            const _Float16* gB = srcB + (size_t)(bn + rb) * K + k0 + cb * 8;
            __builtin_amdgcn_global_load_lds((cglb_t*)gB,
                (lds_t*)&SB[buf][pl][p16b * 8], 16, 0, 0);
        }
    };

    stage(0, 0);
    __syncthreads();

    const int g   = lane >> 4;
    const int r15 = lane & 15;

#pragma unroll
    for (int s = 0; s < NS; ++s) {
        const int p = s & 1;
        if (s + 1 < NS) stage(p ^ 1, (s + 1) * BK);

        f16x8 ah[2], al[2];
#pragma unroll
        for (int m = 0; m < 2; ++m) {
            const int R = w * 32 + m * 16 + r15;
            const int a16 = R * 4 + (g ^ swz4(R));
            ah[m] = *reinterpret_cast<const f16x8*>(&SA[p][0][a16 * 8]);
            al[m] = *reinterpret_cast<const f16x8*>(&SA[p][1][a16 * 8]);
        }
#pragma unroll
        for (int n = 0; n < 4; ++n) {
            const int rB = n * 16 + r15;
            const int b16 = rB * 4 + (g ^ swz4(rB));
            const f16x8 bh = *reinterpret_cast<const f16x8*>(&SB[p][0][b16 * 8]);
            const f16x8 bl = *reinterpret_cast<const f16x8*>(&SB[p][1][b16 * 8]);
#pragma unroll
            for (int m = 0; m < 2; ++m)
                acc0[m][n] = __builtin_amdgcn_mfma_f32_16x16x32_f16(
                    ah[m], bh, acc0[m][n], 0, 0, 0);
#pragma unroll
            for (int m = 0; m < 2; ++m)
                acc1[m][n] = __builtin_amdgcn_mfma_f32_16x16x32_f16(
                    ah[m], bl, acc1[m][n], 0, 0, 0);
#pragma unroll
            for (int m = 0; m < 2; ++m)
                acc1[m][n] = __builtin_amdgcn_mfma_f32_16x16x32_f16(
                    al[m], bh, acc1[m][n], 0, 0, 0);
        }
        __syncthreads();
    }

#pragma unroll
    for (int m = 0; m < 2; ++m)
#pragma unroll
        for (int n = 0; n < 4; ++n) {
            const int col = bn + n * 16 + r15;
            const float bv = bias[col];
#pragma unroll
            for (int q = 0; q < 4; ++q) {
                const int row = bm + w * 32 + m * 16 + (lane >> 4) * 4 + q;
                float v = acc0[m][n][q] + SPLIT_SCALE * acc1[m][n][q] + bv;
                v = fmaxf(v, 0.f);
                _Float16 hi, lo; fsplit(v, hi, lo);
                Chi[(size_t)row * N + col] = hi;
                Clo[(size_t)row * N + col] = lo;
            }
        }
}

// ---------------------------------------------------------------------------
// bf16 MFMA GEMM v7 (decoder): same DMA-staged swizzled structure, 128x128
// tile, 4 waves 64x64, BK=32, double-buffered, one barrier per K-step.
// 32KB LDS. Same ascending-k MFMA order as the old decoder -> bit-identical.
// ---------------------------------------------------------------------------
template<bool RELU, bool OUT_BF16>
__global__ __launch_bounds__(256, 3)
void gemm_bt7(const unsigned short* __restrict__ A,
              const unsigned short* __restrict__ Bt,
              const float* __restrict__ bias,
              void* __restrict__ Cv, int M, int N, int K)
{
    constexpr int BK = 32;

    __shared__ alignas(16) unsigned short SA[2][128 * 32];   // 8KB each buf
    __shared__ alignas(16) unsigned short SB[2][128 * 32];

    const int tid  = threadIdx.x;
    const int lane = tid & 63;
    const int w    = tid >> 6;
    const int wr   = (w >> 1) * 64;
    const int wc   = (w & 1) * 64;

    int bx = blockIdx.x, by = blockIdx.y;
    {
        const int gx = gridDim.x, nwg = gx * gridDim.y;
        if ((nwg & 7) == 0) {
            int d = bx + by * gx;
            int L = (d & 7) * (nwg >> 3) + (d >> 3);
            bx = L % gx; by = L / gx;
        }
    }
    const int bm = by * 128;
    const int bn = bx * 128;

    f32x4 acc[4][4];
#pragma unroll
    for (int m = 0; m < 4; ++m)
#pragma unroll
        for (int n = 0; n < 4; ++n) acc[m][n] = (f32x4){0.f, 0.f, 0.f, 0.f};

    auto stage = [&](int buf, int k0) {
#pragma unroll
        for (int j = 0; j < 2; ++j) {
            const int p16 = (w * 2 + j) * 64 + lane;         // 0..511
            const int r   = p16 >> 2;
            const int c   = (p16 & 3) ^ swz4(r);
            const unsigned short* gA = A + (size_t)(bm + r) * K + k0 + c * 8;
            __builtin_amdgcn_global_load_lds((cglb_t*)gA,
                (lds_t*)&SA[buf][p16 * 8], 16, 0, 0);
            const unsigned short* gB = Bt + (size_t)(bn + r) * K + k0 + c * 8;
            __builtin_amdgcn_global_load_lds((cglb_t*)gB,
                (lds_t*)&SB[buf][p16 * 8], 16, 0, 0);
        }
    };

    stage(0, 0);
    __syncthreads();

    const int g   = lane >> 4;
    const int r15 = lane & 15;
    const int NS  = K / BK;

    for (int s = 0; s < NS; ++s) {
        const int p = s & 1;
        if (s + 1 < NS) stage(p ^ 1, (s + 1) * BK);

        bf16x8 af[4], bf[4];
#pragma unroll
        for (int m = 0; m < 4; ++m) {
            const int R = wr + m * 16 + r15;
            const int a16 = R * 4 + (g ^ swz4(R));
            af[m] = *reinterpret_cast<const bf16x8*>(&SA[p][a16 * 8]);
        }
#pragma unroll
        for (int n = 0; n < 4; ++n) {
            const int RB = wc + n * 16 + r15;
            const int b16 = RB * 4 + (g ^ swz4(RB));
            bf[n] = *reinterpret_cast<const bf16x8*>(&SB[p][b16 * 8]);
        }
#pragma unroll
        for (int m = 0; m < 4; ++m)
#pragma unroll
            for (int n = 0; n < 4; ++n)
                acc[m][n] = __builtin_amdgcn_mfma_f32_16x16x32_bf16(
                    af[m], bf[n], acc[m][n], 0, 0, 0);
        __syncthreads();
    }

#pragma unroll
    for (int m = 0; m < 4; ++m)
#pragma unroll
        for (int n = 0; n < 4; ++n) {
            const int col = bn + wc + n * 16 + r15;
            const float bv = bias[col];
#pragma unroll
            for (int q = 0; q < 4; ++q) {
                const int row = bm + wr + m * 16 + (lane >> 4) * 4 + q;
                float v = acc[m][n][q] + bv;
                if (RELU) v = fmaxf(v, 0.f);
                if (OUT_BF16)
                    reinterpret_cast<unsigned short*>(Cv)[(size_t)row * N + col] = f2bf(v);
                else
                    reinterpret_cast<float*>(Cv)[(size_t)row * N + col] = v;
            }
        }
}

// ---------------------------------------------------------------------------
// Split-fp16 MFMA GEMM v5 (h0: A = fp32 X, split in-register; reg staging).
// ---------------------------------------------------------------------------
template<int K, bool AF32>
__global__ __launch_bounds__(256, AF32 ? 3 : 4)
void gemm_split5(const void* __restrict__ Asrc,
                 const _Float16* __restrict__ Bhi, const _Float16* __restrict__ Blo,
                 const float* __restrict__ bias,
                 _Float16* __restrict__ Chi, _Float16* __restrict__ Clo,
                 int M, int N)
{
    constexpr int BK  = 32;
    constexpr int LDP = 40;
    constexpr int NS  = K / BK;

    __shared__ alignas(16) _Float16 Bh[2][64][LDP];
    __shared__ alignas(16) _Float16 Bl[2][64][LDP];

    const int tid  = threadIdx.x;
    const int lane = tid & 63;
    const int w    = tid >> 6;

    int bx = blockIdx.x, by = blockIdx.y;
    {
        const int gx = gridDim.x, nwg = gx * gridDim.y;
        if ((nwg & 7) == 0) {
            int d = bx + by * gx;
            int L = (d & 7) * (nwg >> 3) + (d >> 3);
            bx = L % gx; by = L / gx;
        }
    }
    const int bm = by * 128;
    const int bn = bx * 64;

    f32x4 acc0[2][4], acc1[2][4];
#pragma unroll
    for (int m = 0; m < 2; ++m)
#pragma unroll
        for (int n = 0; n < 4; ++n) {
            acc0[m][n] = (f32x4){0.f, 0.f, 0.f, 0.f};
            acc1[m][n] = (f32x4){0.f, 0.f, 0.f, 0.f};
        }

    const int arow = bm + w * 32 + (lane & 15);
    const int kgrp = (lane >> 4) * 8;
    const int brow = tid >> 2;
    const int bcol = (tid & 3) * 8;

    const _Float16* Ahi_ = (const _Float16*)Asrc;
    const float*    Af_  = (const float*)Asrc;

    f16x8 ah[2], al[2], ahn[2], aln[2];
    float4 rbh, rbl;

    auto loadB = [&](int k0) {
        const size_t gb = (size_t)(bn + brow) * K + k0 + bcol;
        rbh = *reinterpret_cast<const float4*>(Bhi + gb);
        rbl = *reinterpret_cast<const float4*>(Blo + gb);
    };
    auto storeB = [&](int p) {
        *reinterpret_cast<float4*>(&Bh[p][brow][bcol]) = rbh;
        *reinterpret_cast<float4*>(&Bl[p][brow][bcol]) = rbl;
    };
    auto loadA = [&](int k0, f16x8* h, f16x8* l) {
#pragma unroll
        for (int m = 0; m < 2; ++m) {
            const size_t ga = (size_t)(arow + m * 16) * K + k0 + kgrp;
            if constexpr (AF32) {
                float4 v0 = *reinterpret_cast<const float4*>(Af_ + ga);
                float4 v1 = *reinterpret_cast<const float4*>(Af_ + ga + 4);
                float vv[8] = {v0.x, v0.y, v0.z, v0.w, v1.x, v1.y, v1.z, v1.w};
                f16x8 hh, ll;
#pragma unroll
                for (int j = 0; j < 8; ++j) {
                    _Float16 hi, lo; fsplit(vv[j], hi, lo);
                    hh[j] = hi; ll[j] = lo;
                }
                h[m] = hh; l[m] = ll;
            } else {
                h[m] = *reinterpret_cast<const f16x8*>(Ahi_ + ga);
                l[m] = *reinterpret_cast<const f16x8*>(Ahi_ + (size_t)M * K + ga);
            }
        }
    };

    loadB(0);
    loadA(0, ah, al);
    storeB(0);
    __syncthreads();

#pragma unroll
    for (int s = 0; s < NS; ++s) {
        const int p = s & 1;
        if (s + 1 < NS) {
            loadB((s + 1) * BK);
            loadA((s + 1) * BK, ahn, aln);
        }
#pragma unroll
        for (int n = 0; n < 4; ++n) {
            const f16x8 bh = *reinterpret_cast<const f16x8*>(
                &Bh[p][n * 16 + (lane & 15)][kgrp]);
            const f16x8 bl = *reinterpret_cast<const f16x8*>(
                &Bl[p][n * 16 + (lane & 15)][kgrp]);
#pragma unroll
            for (int m = 0; m < 2; ++m)
                acc0[m][n] = __builtin_amdgcn_mfma_f32_16x16x32_f16(
                    ah[m], bh, acc0[m][n], 0, 0, 0);
#pragma unroll
            for (int m = 0; m < 2; ++m)
                acc1[m][n] = __builtin_amdgcn_mfma_f32_16x16x32_f16(
                    ah[m], bl, acc1[m][n], 0, 0, 0);
#pragma unroll
            for (int m = 0; m < 2; ++m)
                acc1[m][n] = __builtin_amdgcn_mfma_f32_16x16x32_f16(
                    al[m], bh, acc1[m][n], 0, 0, 0);
        }
        if (s + 1 < NS) {
            storeB(p ^ 1);
#pragma unroll
            for (int m = 0; m < 2; ++m) { ah[m] = ahn[m]; al[m] = aln[m]; }
        }
        __syncthreads();
    }

#pragma unroll
    for (int m = 0; m < 2; ++m)
#pragma unroll
        for (int n = 0; n < 4; ++n) {
            const int col = bn + n * 16 + (lane & 15);
            const float bv = bias[col];
#pragma unroll
            for (int q = 0; q < 4; ++q) {
                const int row = bm + w * 32 + m * 16 + (lane >> 4) * 4 + q;
                float v = acc0[m][n][q] + SPLIT_SCALE * acc1[m][n][q] + bv;
                v = fmaxf(v, 0.f);
                _Float16 hi, lo; fsplit(v, hi, lo);
                Chi[(size_t)row * N + col] = hi;
                Clo[(size_t)row * N + col] = lo;
            }
        }
}

// ---------------------------------------------------------------------------
// z_e GEMM via split-fp16 MFMA: ze[M,64] = h1 @ W2 + b2, fp32 accumulation.
// ---------------------------------------------------------------------------
__global__ __launch_bounds__(256)
void gemm_ze_mfma(const _Float16* __restrict__ Ahi, const _Float16* __restrict__ Alo,
                  const _Float16* __restrict__ Bhi, const _Float16* __restrict__ Blo,
                  const float* __restrict__ bias, float* __restrict__ C, int M)
{
    constexpr int K = 512, N = 64;
    const int tid  = threadIdx.x;
    const int lane = tid & 63;
    const int w    = tid >> 6;
    const int wr   = (w >> 1) * 64;
    const int wc   = (w & 1) * 32;
    const int bm   = blockIdx.x * 128;

    f32x4 acc0[4][2], acc1[4][2];
#pragma unroll
    for (int m = 0; m < 4; ++m)
#pragma unroll
        for (int n = 0; n < 2; ++n) {
            acc0[m][n] = (f32x4){0.f, 0.f, 0.f, 0.f};
            acc1[m][n] = (f32x4){0.f, 0.f, 0.f, 0.f};
        }

    const int arow = bm + wr + (lane & 15);
    const int kgrp = (lane >> 4) * 8;

#pragma unroll
    for (int ks = 0; ks < K / 32; ++ks) {
        const int k0 = ks * 32 + kgrp;
        f16x8 ah[4], al[4];
#pragma unroll
        for (int m = 0; m < 4; ++m) {
            const size_t ga = (size_t)(arow + m * 16) * K + k0;
            ah[m] = *reinterpret_cast<const f16x8*>(Ahi + ga);
            al[m] = *reinterpret_cast<const f16x8*>(Alo + ga);
        }
#pragma unroll
        for (int n = 0; n < 2; ++n) {
            const size_t gb = (size_t)(wc + n * 16 + (lane & 15)) * K + k0;
            const f16x8 bh = *reinterpret_cast<const f16x8*>(Bhi + gb);
            const f16x8 bl = *reinterpret_cast<const f16x8*>(Blo + gb);
#pragma unroll
            for (int m = 0; m < 4; ++m)
                acc0[m][n] = __builtin_amdgcn_mfma_f32_16x16x32_f16(
                    ah[m], bh, acc0[m][n], 0, 0, 0);
#pragma unroll
            for (int m = 0; m < 4; ++m)
                acc1[m][n] = __builtin_amdgcn_mfma_f32_16x16x32_f16(
                    ah[m], bl, acc1[m][n], 0, 0, 0);
#pragma unroll
            for (int m = 0; m < 4; ++m)
                acc1[m][n] = __builtin_amdgcn_mfma_f32_16x16x32_f16(
                    al[m], bh, acc1[m][n], 0, 0, 0);
        }
    }

#pragma unroll
    for (int m = 0; m < 4; ++m)
#pragma unroll
        for (int n = 0; n < 2; ++n) {
            const int col = wc + n * 16 + (lane & 15);
            const float bv = bias[col];
#pragma unroll
            for (int q = 0; q < 4; ++q) {
                const int row = bm + wr + m * 16 + (lane >> 4) * 4 + q;
                C[(size_t)row * N + col] = acc0[m][n][q] + SPLIT_SCALE * acc1[m][n][q] + bv;
            }
        }
}

// ---------------------------------------------------------------------------
// VQ via MFMA: fp32 d2 filter -> candidate-only exact fp64 re-check.
// ---------------------------------------------------------------------------
#define VQ_EPS 1e-3f
__global__ __launch_bounds__(512)
void vq_mfma(const float* __restrict__ Z, const float* __restrict__ CB,
             const _Float16* __restrict__ Chi, const _Float16* __restrict__ Clo,
             float* __restrict__ OUT, unsigned short* __restrict__ ZQB)
{
    __shared__ float  ccf[256];
    __shared__ double ccd[256];
    __shared__ float  xxf[128];
    __shared__ double xxd[128];
    __shared__ float  redv[4][128];
    __shared__ int    redi[4][128];
    __shared__ float  bv1s[128];
    __shared__ int    bis[128];
    __shared__ int    cand[128][16];
    __shared__ int    ncand[128];
    __shared__ int    fullflag[128];
    __shared__ int    flaglist[128];
    __shared__ int    nflag;

    const int tid  = threadIdx.x;
    const int lane = tid & 63;
    const int w    = tid >> 6;
    const int wr   = (w >> 2) * 64;
    const int wc   = (w & 3) * 64;
    const int bm   = blockIdx.x * 128;

    if (tid == 0) nflag = 0;
    if (tid < 256) {
        const float4* c4 = reinterpret_cast<const float4*>(CB + (size_t)tid * 64);
        double cc = 0.0;
#pragma unroll
        for (int v = 0; v < 16; ++v) {
            float4 f = c4[v];
            cc = fma((double)f.x, (double)f.x, cc);
            cc = fma((double)f.y, (double)f.y, cc);
            cc = fma((double)f.z, (double)f.z, cc);
            cc = fma((double)f.w, (double)f.w, cc);
        }
        ccd[tid] = cc; ccf[tid] = (float)cc;
    }
    if (tid < 128) {
        const float4* z4 = reinterpret_cast<const float4*>(Z + (size_t)(bm + tid) * 64);
        double xx = 0.0;
#pragma unroll
        for (int v = 0; v < 16; ++v) {
            float4 f = z4[v];
            xx = fma((double)f.x, (double)f.x, xx);
            xx = fma((double)f.y, (double)f.y, xx);
            xx = fma((double)f.z, (double)f.z, xx);
            xx = fma((double)f.w, (double)f.w, xx);
        }
        xxd[tid] = xx; xxf[tid] = (float)xx;
        ncand[tid] = 0; fullflag[tid] = 0;
    }
    __syncthreads();

    f32x4 acc0[4][4], acc1[4][4];
#pragma unroll
    for (int m = 0; m < 4; ++m)
#pragma unroll
        for (int n = 0; n < 4; ++n) {
            acc0[m][n] = (f32x4){0.f, 0.f, 0.f, 0.f};
            acc1[m][n] = (f32x4){0.f, 0.f, 0.f, 0.f};
        }

    const int arow = bm + wr + (lane & 15);
    const int kgrp = (lane >> 4) * 8;

#pragma unroll
    for (int ks = 0; ks < 2; ++ks) {
        const int k0 = ks * 32 + kgrp;
        f16x8 ah[4], al[4];
#pragma unroll
        for (int m = 0; m < 4; ++m) {
            const float* src = Z + (size_t)(arow + m * 16) * 64 + k0;
            float4 v0 = *reinterpret_cast<const float4*>(src);
            float4 v1 = *reinterpret_cast<const float4*>(src + 4);
            float vv[8] = {v0.x, v0.y, v0.z, v0.w, v1.x, v1.y, v1.z, v1.w};
            f16x8 hh, ll;
#pragma unroll
            for (int j = 0; j < 8; ++j) {
                _Float16 hi, lo; fsplit(vv[j], hi, lo);
                hh[j] = hi; ll[j] = lo;
            }
            ah[m] = hh; al[m] = ll;
        }
#pragma unroll
        for (int n = 0; n < 4; ++n) {
            const size_t gb = (size_t)(wc + n * 16 + (lane & 15)) * 64 + k0;
            const f16x8 bh = *reinterpret_cast<const f16x8*>(Chi + gb);
            const f16x8 bl = *reinterpret_cast<const f16x8*>(Clo + gb);
#pragma unroll
            for (int m = 0; m < 4; ++m)
                acc0[m][n] = __builtin_amdgcn_mfma_f32_16x16x32_f16(
                    ah[m], bh, acc0[m][n], 0, 0, 0);
#pragma unroll
            for (int m = 0; m < 4; ++m)
                acc1[m][n] = __builtin_amdgcn_mfma_f32_16x16x32_f16(
                    ah[m], bl, acc1[m][n], 0, 0, 0);
#pragma unroll
            for (int m = 0; m < 4; ++m)
                acc1[m][n] = __builtin_amdgcn_mfma_f32_16x16x32_f16(
                    al[m], bh, acc1[m][n], 0, 0, 0);
        }
    }

#pragma unroll
    for (int m = 0; m < 4; ++m)
#pragma unroll
        for (int n = 0; n < 4; ++n) {
            const int col = wc + n * 16 + (lane & 15);
            const float cf = ccf[col];
#pragma unroll
            for (int q = 0; q < 4; ++q) {
                const int rl = wr + m * 16 + (lane >> 4) * 4 + q;
                float dot = acc0[m][n][q] + SPLIT_SCALE * acc1[m][n][q];
                acc0[m][n][q] = (xxf[rl] - 2.0f * dot) + cf;
            }
        }

    float bvr[4][4]; int bir[4][4];
#pragma unroll
    for (int m = 0; m < 4; ++m)
#pragma unroll
        for (int q = 0; q < 4; ++q) {
            float bv = 3.4e38f; int bi = 0;
#pragma unroll
            for (int n = 0; n < 4; ++n) {
                const int col = wc + n * 16 + (lane & 15);
                const float v = acc0[m][n][q];
                if (v < bv || (v == bv && col < bi)) { bv = v; bi = col; }
            }
            bvr[m][q] = bv; bir[m][q] = bi;
        }
#pragma unroll
    for (int mask = 1; mask < 16; mask <<= 1) {
#pragma unroll
        for (int m = 0; m < 4; ++m)
#pragma unroll
            for (int q = 0; q < 4; ++q) {
                float ov = __shfl_xor(bvr[m][q], mask);
                int   oi = __shfl_xor(bir[m][q], mask);
                if (ov < bvr[m][q] || (ov == bvr[m][q] && oi < bir[m][q])) {
                    bvr[m][q] = ov; bir[m][q] = oi;
                }
            }
    }
    if ((lane & 15) == 0) {
#pragma unroll
        for (int m = 0; m < 4; ++m)
#pragma unroll
            for (int q = 0; q < 4; ++q) {
                const int rl = wr + m * 16 + (lane >> 4) * 4 + q;
                redv[w & 3][rl] = bvr[m][q];
                redi[w & 3][rl] = bir[m][q];
            }
    }
    __syncthreads();

    if (tid < 128) {
        float bv = 3.4e38f; int bi = 0;
#pragma unroll
        for (int nw = 0; nw < 4; ++nw) {
            float v = redv[nw][tid];
            if (v < bv) { bv = v; bi = redi[nw][tid]; }
        }
        bv1s[tid] = bv; bis[tid] = bi;
    }
    __syncthreads();

#pragma unroll
    for (int m = 0; m < 4; ++m)
#pragma unroll
        for (int q = 0; q < 4; ++q) {
            const int rl = wr + m * 16 + (lane >> 4) * 4 + q;
            const float thr = bv1s[rl] + VQ_EPS;
#pragma unroll
            for (int n = 0; n < 4; ++n) {
                const int col = wc + n * 16 + (lane & 15);
                if (acc0[m][n][q] <= thr) {
                    int s = atomicAdd(&ncand[rl], 1);
                    if (s < 16) cand[rl][s] = col;
                    else        fullflag[rl] = 1;
                }
            }
        }
    __syncthreads();

    if (tid < 128) {
        const int nc_ = ncand[tid] < 16 ? ncand[tid] : 16;
        if (nc_ > 1 && !fullflag[tid]) {
            const float4* z4p = reinterpret_cast<const float4*>(Z + (size_t)(bm + tid) * 64);
            const double xx = xxd[tid];
            double best = 1.0e300; int bi = 256;
            for (int s = 0; s < nc_; ++s) {
                const int e = cand[tid][s];
                const float4* c4p = reinterpret_cast<const float4*>(CB + (size_t)e * 64);
                double dot = 0.0;
#pragma unroll
                for (int v = 0; v < 16; ++v) {
                    float4 zf = z4p[v], cf4 = c4p[v];
                    dot = fma((double)zf.x, (double)cf4.x, dot);
                    dot = fma((double)zf.y, (double)cf4.y, dot);
                    dot = fma((double)zf.z, (double)cf4.z, dot);
                    dot = fma((double)zf.w, (double)cf4.w, dot);
                }
                double d2x = (xx - 2.0 * dot) + ccd[e];
                if (d2x < best || (d2x == best && e < bi)) { best = d2x; bi = e; }
            }
            bis[tid] = bi;
        }
        if (fullflag[tid]) {
            int s = atomicAdd(&nflag, 1);
            flaglist[s] = tid;
        }
    }
    __syncthreads();

    for (int fi = w; fi < nflag; fi += 8) {
        const int rl = flaglist[fi];
        const float* zr = Z + (size_t)(bm + rl) * 64;
        const double xx = xxd[rl];
        double best = 1.0e300; int bi = 256;
#pragma unroll
        for (int j = 0; j < 4; ++j) {
            const int e = lane + j * 64;
            const float* c = CB + (size_t)e * 64;
            double dot = 0.0;
#pragma unroll
            for (int d = 0; d < 64; ++d)
                dot = fma((double)zr[d], (double)c[d], dot);
            double d2x = (xx - 2.0 * dot) + ccd[e];
            if (d2x < best || (d2x == best && e < bi)) { best = d2x; bi = e; }
        }
#pragma unroll
        for (int mask = 1; mask < 64; mask <<= 1) {
            double ov = __shfl_xor(best, mask);
            int    oi = __shfl_xor(bi, mask);
            if (ov < best || (ov == best && oi < bi)) { best = ov; bi = oi; }
        }
        if (lane == 0) bis[rl] = bi;
    }
    __syncthreads();

    {
        const int row  = tid >> 2;
        const int part = tid & 3;
        const int bi   = bis[row];
        const float4* src = reinterpret_cast<const float4*>(CB + (size_t)bi * 64) + part * 4;
        float* dst = OUT + (size_t)(bm + row) * 64 + part * 16;
        unsigned short* dq = ZQB + (size_t)(bm + row) * 64 + part * 16;
#pragma unroll
        for (int v = 0; v < 4; ++v) {
            float4 f = src[v];
            *reinterpret_cast<float4*>(dst + v * 4) = f;
            ushort4 qb = { f2bf(f.x), f2bf(f.y), f2bf(f.z), f2bf(f.w) };
            *reinterpret_cast<ushort4*>(dq + v * 4) = qb;
        }
    }
}

// ---------------------------------------------------------------------------
// small prep kernels
// ---------------------------------------------------------------------------
__global__ __launch_bounds__(256)
void transpose_bf16(const float* __restrict__ W, unsigned short* __restrict__ Wt,
                    int K, int N)
{
    int idx = blockIdx.x * 256 + threadIdx.x;
    if (idx >= K * N) return;
    int n = idx / K, k = idx % K;
    Wt[idx] = f2bf(W[(size_t)k * N + n]);
}

__global__ __launch_bounds__(256)
void transpose_split_f16(const float* __restrict__ W,
                         _Float16* __restrict__ Whi, _Float16* __restrict__ Wlo,
                         int K, int N)
{
    int idx = blockIdx.x * 256 + threadIdx.x;
    if (idx >= K * N) return;
    int n = idx / K, k = idx % K;
    _Float16 hi, lo; fsplit(W[(size_t)k * N + n], hi, lo);
    Whi[idx] = hi; Wlo[idx] = lo;
}

__global__ __launch_bounds__(256)
void split_flat_f16(const float* __restrict__ src,
                    _Float16* __restrict__ hi, _Float16* __restrict__ lo, int n)
{
    int i = blockIdx.x * 256 + threadIdx.x;
    if (i >= n) return;
    _Float16 h, l; fsplit(src[i], h, l);
    hi[i] = h; lo[i] = l;
}

// ---------------------------------------------------------------------------
extern "C" void kernel_launch(void* const* d_in, const int* in_sizes, int n_in,
                              void* d_out, int out_size, void* d_ws, size_t ws_size,
                              hipStream_t stream)
{
    const float* X  = (const float*)d_in[0];
    const float* W0 = (const float*)d_in[1];
    const float* b0 = (const float*)d_in[2];
    const float* W1 = (const float*)d_in[3];
    const float* b1 = (const float*)d_in[4];
    const float* W2 = (const float*)d_in[5];
    const float* b2 = (const float*)d_in[6];
    const float* CB = (const float*)d_in[7];
    const float* W3 = (const float*)d_in[8];
    const float* b3 = (const float*)d_in[9];
    const float* W4 = (const float*)d_in[10];
    const float* b4 = (const float*)d_in[11];
    const float* W5 = (const float*)d_in[12];
    const float* b5 = (const float*)d_in[13];

    const int D_in = 256, H = 512, R = 64, S = 512, NA = 8;
    const int Mtot = in_sizes[0] / D_in;          // 131072

    float* recon = (float*)d_out;
    float* ze    = recon + (size_t)(Mtot / NA) * S;
    float* remb  = ze + (size_t)Mtot * R;

    // ---- workspace: fixed weight planes ----
    char* p = (char*)d_ws;
    _Float16* W0hi = (_Float16*)p;  p += (size_t)H * D_in * 2;
    _Float16* W0lo = (_Float16*)p;  p += (size_t)H * D_in * 2;
    _Float16* W1hi = (_Float16*)p;  p += (size_t)H * H * 2;
    _Float16* W1lo = (_Float16*)p;  p += (size_t)H * H * 2;
    _Float16* W2thi = (_Float16*)p; p += (size_t)R * H * 2;
    _Float16* W2tlo = (_Float16*)p; p += (size_t)R * H * 2;
    _Float16* CBhi = (_Float16*)p;  p += (size_t)256 * R * 2;
    _Float16* CBlo = (_Float16*)p;  p += (size_t)256 * R * 2;
    unsigned short* W3t = (unsigned short*)p;  p += (size_t)H * R * 2;
    unsigned short* W4t = (unsigned short*)p;  p += (size_t)H * (NA * H) * 2;
    unsigned short* W5t = (unsigned short*)p;  p += (size_t)S * H * 2;
    size_t fixed = (size_t)(p - (char*)d_ws);
    fixed = (fixed + 255) & ~(size_t)255;

    // try nc=1 first (fewer launches, bigger grids); adapt down if ws small
    int nc = 1;
    while (nc < 128) {
        size_t rpcT = (size_t)Mtot / nc;
        if (fixed + rpcT * 4224 + 1024 <= ws_size) break;
        nc *= 2;
    }
    const int rpc = Mtot / nc;
    char* q = (char*)d_ws + fixed;
    _Float16* h0hi = (_Float16*)q;                 q += (size_t)rpc * H * 2;
    _Float16* h0lo = (_Float16*)q;                 q += (size_t)rpc * H * 2;
    _Float16* h1hi = (_Float16*)q;                 q += (size_t)rpc * H * 2;
    _Float16* h1lo = (_Float16*)q;                 q += (size_t)rpc * H * 2;
    unsigned short* zqb = (unsigned short*)q;      q += (size_t)rpc * R * 2;
    unsigned short* rec1b = (unsigned short*)h0hi;     // alias (h0 dead after h1)
    unsigned short* rec2b = (unsigned short*)h1hi;     // alias (h1 dead after ze)

    // ---- one-time weight prep ----
    transpose_split_f16<<<(H * D_in + 255) / 256, 256, 0, stream>>>(W0, W0hi, W0lo, D_in, H);
    transpose_split_f16<<<(H * H + 255) / 256, 256, 0, stream>>>(W1, W1hi, W1lo, H, H);
    transpose_split_f16<<<(H * R + 255) / 256, 256, 0, stream>>>(W2, W2thi, W2tlo, H, R);
    split_flat_f16<<<(256 * R + 255) / 256, 256, 0, stream>>>(CB, CBhi, CBlo, 256 * R);
    transpose_bf16<<<(H * R + 255) / 256, 256, 0, stream>>>(W3, W3t, R, H);
    transpose_bf16<<<(H * NA * H + 255) / 256, 256, 0, stream>>>(W4, W4t, NA * H, H);
    transpose_bf16<<<(S * H + 255) / 256, 256, 0, stream>>>(W5, W5t, H, S);

    for (int r0 = 0; r0 < Mtot; r0 += rpc) {
        const int M6 = rpc / NA;
        // h0: reg-staged split (A = fp32 X, in-register split)
        gemm_split5<256, true><<<dim3(H / 64, rpc / 128), 256, 0, stream>>>(
            X + (size_t)r0 * D_in, W0hi, W0lo, b0, h0hi, h0lo, rpc, H);
        // h1: DMA-staged split (m97 structure, swizzled linear LDS)
        gemm_split7<512><<<dim3(H / 64, rpc / 128), 256, 0, stream>>>(
            h0hi, h0lo, W1hi, W1lo, b1, h1hi, h1lo, rpc, H);
        // z_e: split-fp16 MFMA, fp32 accum -> output zone 1
        gemm_ze_mfma<<<rpc / 128, 256, 0, stream>>>(
            h1hi, h1lo, W2thi, W2tlo, b2, ze + (size_t)r0 * R, rpc);
        // VQ (fp32 filter + candidate-only fp64 re-check)
        vq_mfma<<<rpc / 128, 512, 0, stream>>>(
            ze + (size_t)r0 * R, CB, CBhi, CBlo,
            remb + (size_t)r0 * R, zqb);
        // decoder: bf16 MFMA, DMA-staged
        gemm_bt7<true, true><<<dim3(H / 128, rpc / 128), 256, 0, stream>>>(
            zqb, W3t, b3, rec1b, rpc, H, R);
        gemm_bt7<true, true><<<dim3(H / 128, M6 / 128), 256, 0, stream>>>(
            rec1b, W4t, b4, rec2b, M6, H, NA * H);
        gemm_bt7<false, false><<<dim3(S / 128, M6 / 128), 256, 0, stream>>>(
            rec2b, W5t, b5, recon + (size_t)(r0 / NA) * S, M6, S, H);
    }
}